// Round 1
// 1113.233 us; speedup vs baseline: 1.0735x; 1.0735x over previous
//
#include <hip/hip_runtime.h>
#include <cmath>
#include <cstdint>

// ---------------------------------------------------------------------------
// TransformerEncoderLayer (attention + MoE) on MI355X, fp32 acc.
// Round 9: the big GEMMs (shared SwiGLU/stage2, moe1, moe2) were VALU-bound
// (r8 profile: MfmaUtil 10.7%, VALUBusy 46.6%, HBM 16%) on their fp32 k-major
// B staging: 16 strided scalar loads + 16 cvts per K-step per thread.
// New: one-time transpose+convert pass -> n-major bf16 weight cache in
// workspace (rms folded into sh1/sh3), then a new GEMM family (gemmT/moeT)
// with 128x64 (or 64x128) tiles where every staging op is 1 bf16x8 load +
// 1 conflict-free ds_write_b128. 16 MFMA / 10 ds_read per wave-K-step.
// Tiered on ws_size: full (>=~176MB), shared-only (>=~60MB), old path else.
// ---------------------------------------------------------------------------

typedef __bf16 bf16;
typedef __bf16 bf16x8 __attribute__((ext_vector_type(8)));
typedef __bf16 bf16x4 __attribute__((ext_vector_type(4)));
typedef float  f32x4  __attribute__((ext_vector_type(4)));

static constexpr int Bb = 2, Ss = 1024, Dd = 512, NHh = 8, HDd = 64;
static constexpr int Tt = Bb * Ss;           // 2048 tokens
static constexpr int NSs = 8, F3f = 1536;
static constexpr int Ee = 32, F2f = 1024;
static constexpr int SLOTCAP = 10240;        // 8192 + worst-case pad (10208)
static constexpr int MAXTILE = 160;

// ---------------- helpers ----------------
__device__ inline float wavesum(float v) {
#pragma unroll
  for (int i = 1; i < 64; i <<= 1) v += __shfl_xor(v, i, 64);
  return v;
}
__device__ inline float blocksum(float v, float* sm) {
  v = wavesum(v);
  int wv = threadIdx.x >> 6;
  __syncthreads();
  if ((threadIdx.x & 63) == 0) sm[wv] = v;
  __syncthreads();
  return (sm[0] + sm[1]) + (sm[2] + sm[3]);
}
__device__ inline float silu_f(float x) { return x / (1.f + expf(-x)); }
__device__ inline float sigm_f(float x) { return 1.f / (1.f + expf(-x)); }

// Inline dtype classifier on d_in[0] (x ~ N(0,1)); 1 = fp32 buffer.
__device__ inline int is_f32(const unsigned short* __restrict__ xr) {
  int good = 0;
#pragma unroll
  for (int i = 0; i < 32; ++i) {
    unsigned e = (xr[2 * i] >> 7) & 0xFF;
    good += (e >= 110 && e <= 140);
  }
  return good < 16;
}

// ---------------------------------------------------------------------------
// Flexible MFMA GEMM (legacy path, kept for small projections + fallback).
// ---------------------------------------------------------------------------
template <typename TB, int WANT, int ACT, int DUAL, int OUTBF, int ACCUM,
          int RESID, int ASCALE>
__global__ __launch_bounds__(256) void gemm_k(
    const unsigned short* __restrict__ xdet,
    const bf16* __restrict__ A, long aBatch, int lda,
    const TB* __restrict__ ascale, long asBatch,
    const TB* __restrict__ B0, const TB* __restrict__ B1, long bBatch, int bK,
    const TB* __restrict__ bias, int biasBatch,
    void* __restrict__ Cv, long cBatch, int ldc,
    const TB* __restrict__ resid, int resLd,
    int N, int K, float scale) {
  if (is_f32(xdet) != WANT) return;
  __shared__ __align__(16) bf16 sA[64 * 40];
  __shared__ __align__(16) bf16 sB0[64 * 40];
  __shared__ __align__(16) bf16 sB1[64 * 40];

  const int tid = threadIdx.x;
  const int wave = tid >> 6, lane = tid & 63;
  const int fm = lane & 15, quad = lane >> 4;
  const int bm = blockIdx.x, bn = blockIdx.y, z = blockIdx.z;

  const bf16* Az = A + (long)z * aBatch;
  const TB* B0z = B0 + (long)z * bBatch;
  const TB* B1z = DUAL ? (B1 + (long)z * bBatch) : nullptr;
  const TB* asz = ASCALE ? (ascale + (long)z * asBatch) : nullptr;

  f32x4 acc0[4], acc1[4];
  const f32x4 vzero = {0.f, 0.f, 0.f, 0.f};
#pragma unroll
  for (int i = 0; i < 4; ++i) { acc0[i] = vzero; acc1[i] = vzero; }

  const int arow = tid >> 2, ak0 = (tid & 3) * 8;   // A staging (row-major)
  const int gn = bn * 64 + lane;                    // B staging (k-major)
  const int wch = wave * 8;                         // this wave's k-chunk

  for (int kb = 0; kb < K; kb += 32) {
    bf16x8 av = *(const bf16x8*)(Az + (long)(bm * 64 + arow) * lda + kb + ak0);
    if (ASCALE) {
#pragma unroll
      for (int j = 0; j < 8; ++j)
        av[j] = (bf16)((float)av[j] * (float)asz[kb + ak0 + j]);
    }
    *(bf16x8*)(sA + arow * 40 + ak0) = av;
    bf16x8 bv, cv;
    if (gn < N) {
      const TB* bp = B0z + (long)(kb + wch) * bK + gn;
#pragma unroll
      for (int j = 0; j < 8; ++j) bv[j] = (bf16)(float)bp[(long)j * bK];
      if (DUAL) {
        const TB* cp = B1z + (long)(kb + wch) * bK + gn;
#pragma unroll
        for (int j = 0; j < 8; ++j) cv[j] = (bf16)(float)cp[(long)j * bK];
      }
    } else {
#pragma unroll
      for (int j = 0; j < 8; ++j) { bv[j] = (bf16)0.f; if (DUAL) cv[j] = (bf16)0.f; }
    }
    *(bf16x8*)(sB0 + lane * 40 + wch) = bv;
    if (DUAL) *(bf16x8*)(sB1 + lane * 40 + wch) = cv;
    __syncthreads();
    bf16x8 af = *(const bf16x8*)(sA + (wave * 16 + fm) * 40 + quad * 8);
#pragma unroll
    for (int nt = 0; nt < 4; ++nt) {
      bf16x8 bfr = *(const bf16x8*)(sB0 + (nt * 16 + fm) * 40 + quad * 8);
      acc0[nt] = __builtin_amdgcn_mfma_f32_16x16x32_bf16(af, bfr, acc0[nt], 0, 0, 0);
      if (DUAL) {
        bf16x8 bg = *(const bf16x8*)(sB1 + (nt * 16 + fm) * 40 + quad * 8);
        acc1[nt] = __builtin_amdgcn_mfma_f32_16x16x32_bf16(af, bg, acc1[nt], 0, 0, 0);
      }
    }
    __syncthreads();
  }

#pragma unroll
  for (int nt = 0; nt < 4; ++nt) {
    int gcol = bn * 64 + nt * 16 + fm;
    if (gcol >= N) continue;
#pragma unroll
    for (int r = 0; r < 4; ++r) {
      int grow = bm * 64 + wave * 16 + quad * 4 + r;
      float v;
      if (DUAL) {
        v = silu_f(acc0[nt][r]) * acc1[nt][r];
      } else {
        v = acc0[nt][r] * scale;
        if (bias) v += (float)bias[z * biasBatch + gcol];
        if (ACT == 1) v = silu_f(v);
        else if (ACT == 2) v = sigm_f(v);
      }
      if (RESID) v += (float)resid[(long)grow * resLd + gcol];
      long ci = (long)z * cBatch + (long)grow * ldc + gcol;
      if (ACCUM) atomicAdd((float*)Cv + ci, v);
      else if (OUTBF) ((bf16*)Cv)[ci] = (bf16)v;
      else ((float*)Cv)[ci] = v;
    }
  }
}

// ---------------------------------------------------------------------------
// Weight transpose+convert: W [K][N] (fp32 or bf16) -> Wt [N][K] bf16,
// optional per-k scale fold (rmsnorm weight). 64x64 LDS tile transpose.
// ---------------------------------------------------------------------------
template <typename TI, int WANT, int SCALE>
__global__ __launch_bounds__(256) void tconv_k(
    const unsigned short* __restrict__ xdet,
    const TI* __restrict__ W, long wBatch,
    const TI* __restrict__ sc, long sBatch,
    bf16* __restrict__ Wt, long oBatch, int K, int N) {
  if (is_f32(xdet) != WANT) return;
  __shared__ float sT[64][65];
  const int tid = threadIdx.x;
  const int k0 = blockIdx.x * 64, n0 = blockIdx.y * 64, z = blockIdx.z;
  const TI* Wz = W + (long)z * wBatch;
  const int rr = tid >> 4, cc = (tid & 15) * 4;
#pragma unroll
  for (int it = 0; it < 4; ++it) {
    int row = it * 16 + rr;
    const TI* p = Wz + (long)(k0 + row) * N + n0 + cc;
    float v0, v1, v2, v3;
    if constexpr (sizeof(TI) == 4) {
      float4 v = *(const float4*)p;
      v0 = v.x; v1 = v.y; v2 = v.z; v3 = v.w;
    } else {
      bf16x4 v = *(const bf16x4*)p;
      v0 = (float)v[0]; v1 = (float)v[1]; v2 = (float)v[2]; v3 = (float)v[3];
    }
    if (SCALE) {
      float s = (float)sc[(long)z * sBatch + k0 + row];
      v0 *= s; v1 *= s; v2 *= s; v3 *= s;
    }
    sT[row][cc + 0] = v0; sT[row][cc + 1] = v1;
    sT[row][cc + 2] = v2; sT[row][cc + 3] = v3;
  }
  __syncthreads();
  bf16* Oz = Wt + (long)z * oBatch;
#pragma unroll
  for (int it = 0; it < 4; ++it) {
    int n = it * 16 + rr;
    bf16x4 ov;
#pragma unroll
    for (int j = 0; j < 4; ++j) ov[j] = (bf16)sT[cc + j][n];
    *(bf16x4*)(Oz + (long)(n0 + n) * K + k0 + cc) = ov;
  }
}

// ---------------------------------------------------------------------------
// Dense GEMM on n-major bf16 B (Wt). BM=128, BN=64, BK=32, 4 waves over M.
// All staging: 1 bf16x8 global load + 1 ds_write_b128 per tile-chunk.
// DUAL: SwiGLU epilogue silu(a0)*a1 -> bf16. ACCUM: atomicAdd fp32 * scale.
// ---------------------------------------------------------------------------
template <int DUAL, int ACCUM>
__global__ __launch_bounds__(256) void gemmT_k(
    const bf16* __restrict__ A, long aBatch, int lda,
    const bf16* __restrict__ B0t, const bf16* __restrict__ B1t, long bBatch,
    void* __restrict__ Cv, long cBatch, int ldc, int K, float scale) {
  __shared__ __align__(16) bf16 sA[128 * 40];
  __shared__ __align__(16) bf16 sB0[64 * 40];
  __shared__ __align__(16) bf16 sB1[DUAL ? 64 * 40 : 16];
  const int tid = threadIdx.x, wave = tid >> 6, lane = tid & 63;
  const int fm = lane & 15, quad = lane >> 4;
  const bf16* Az = A + (long)blockIdx.z * aBatch + (long)(blockIdx.x * 128) * lda;
  const bf16* B0z = B0t + (long)blockIdx.z * bBatch + (long)(blockIdx.y * 64) * K;
  const bf16* B1z = DUAL ? (B1t + (long)blockIdx.z * bBatch + (long)(blockIdx.y * 64) * K) : nullptr;
  f32x4 acc0[2][4], acc1[2][4];
  const f32x4 vz = {0.f, 0.f, 0.f, 0.f};
#pragma unroll
  for (int m = 0; m < 2; ++m)
#pragma unroll
    for (int n = 0; n < 4; ++n) { acc0[m][n] = vz; acc1[m][n] = vz; }
  const int srow = tid >> 2, sk0 = (tid & 3) * 8;
  for (int kb = 0; kb < K; kb += 32) {
    *(bf16x8*)(sA + srow * 40 + sk0) =
        *(const bf16x8*)(Az + (long)srow * lda + kb + sk0);
    *(bf16x8*)(sA + (srow + 64) * 40 + sk0) =
        *(const bf16x8*)(Az + (long)(srow + 64) * lda + kb + sk0);
    *(bf16x8*)(sB0 + srow * 40 + sk0) =
        *(const bf16x8*)(B0z + (long)srow * K + kb + sk0);
    if (DUAL)
      *(bf16x8*)(sB1 + srow * 40 + sk0) =
          *(const bf16x8*)(B1z + (long)srow * K + kb + sk0);
    __syncthreads();
    bf16x8 af0 = *(const bf16x8*)(sA + (wave * 32 + fm) * 40 + quad * 8);
    bf16x8 af1 = *(const bf16x8*)(sA + (wave * 32 + 16 + fm) * 40 + quad * 8);
#pragma unroll
    for (int nt = 0; nt < 4; ++nt) {
      bf16x8 b0 = *(const bf16x8*)(sB0 + (nt * 16 + fm) * 40 + quad * 8);
      acc0[0][nt] = __builtin_amdgcn_mfma_f32_16x16x32_bf16(af0, b0, acc0[0][nt], 0, 0, 0);
      acc0[1][nt] = __builtin_amdgcn_mfma_f32_16x16x32_bf16(af1, b0, acc0[1][nt], 0, 0, 0);
      if (DUAL) {
        bf16x8 b1 = *(const bf16x8*)(sB1 + (nt * 16 + fm) * 40 + quad * 8);
        acc1[0][nt] = __builtin_amdgcn_mfma_f32_16x16x32_bf16(af0, b1, acc1[0][nt], 0, 0, 0);
        acc1[1][nt] = __builtin_amdgcn_mfma_f32_16x16x32_bf16(af1, b1, acc1[1][nt], 0, 0, 0);
      }
    }
    __syncthreads();
  }
#pragma unroll
  for (int mt = 0; mt < 2; ++mt)
#pragma unroll
    for (int nt = 0; nt < 4; ++nt) {
      int col = blockIdx.y * 64 + nt * 16 + fm;
#pragma unroll
      for (int r = 0; r < 4; ++r) {
        int row = blockIdx.x * 128 + wave * 32 + mt * 16 + quad * 4 + r;
        long ci = (long)blockIdx.z * cBatch + (long)row * ldc + col;
        if (DUAL) {
          ((bf16*)Cv)[ci] = (bf16)(silu_f(acc0[mt][nt][r]) * acc1[mt][nt][r]);
        } else {
          float v = acc0[mt][nt][r] * scale;
          if (ACCUM) atomicAdd((float*)Cv + ci, v);
          else ((bf16*)Cv)[ci] = (bf16)v;
        }
      }
    }
}

// ---------------------------------------------------------------------------
// Routed expert stage 1 on transposed bf16 weights: gathered dual-SwiGLU.
// BM=64 (slot tile), BN=128, waves 2x2. hid layout [slot][F2f].
// ---------------------------------------------------------------------------
__global__ __launch_bounds__(256) void moeT1_k(
    const int* __restrict__ tileExp, const int* __restrict__ tileStart,
    const int* __restrict__ slotTok, const bf16* __restrict__ xfb,
    const bf16* __restrict__ W1t, const bf16* __restrict__ W3t,
    bf16* __restrict__ hid) {
  int e = tileExp[blockIdx.x];
  if (e < 0) return;
  int slot0 = tileStart[blockIdx.x];
  __shared__ int sTok[64];
  __shared__ __align__(16) bf16 sA[64 * 40];
  __shared__ __align__(16) bf16 sB0[128 * 40];
  __shared__ __align__(16) bf16 sB1[128 * 40];
  const int tid = threadIdx.x, wave = tid >> 6, lane = tid & 63;
  const int fm = lane & 15, quad = lane >> 4;
  const int wr = wave >> 1, wc = wave & 1;
  if (tid < 64) sTok[tid] = slotTok[slot0 + tid];
  __syncthreads();
  const bf16* B0 = W1t + (long)e * (F2f * 512) + (long)(blockIdx.y * 128) * 512;
  const bf16* B1 = W3t + (long)e * (F2f * 512) + (long)(blockIdx.y * 128) * 512;
  f32x4 acc0[2][4], acc1[2][4];
  const f32x4 vz = {0.f, 0.f, 0.f, 0.f};
#pragma unroll
  for (int m = 0; m < 2; ++m)
#pragma unroll
    for (int n = 0; n < 4; ++n) { acc0[m][n] = vz; acc1[m][n] = vz; }
  const int srow = tid >> 2, sk0 = (tid & 3) * 8;
  const long atok = (long)sTok[srow] * 512;
  for (int kb = 0; kb < 512; kb += 32) {
    *(bf16x8*)(sA + srow * 40 + sk0) = *(const bf16x8*)(xfb + atok + kb + sk0);
    *(bf16x8*)(sB0 + srow * 40 + sk0) =
        *(const bf16x8*)(B0 + (long)srow * 512 + kb + sk0);
    *(bf16x8*)(sB0 + (srow + 64) * 40 + sk0) =
        *(const bf16x8*)(B0 + (long)(srow + 64) * 512 + kb + sk0);
    *(bf16x8*)(sB1 + srow * 40 + sk0) =
        *(const bf16x8*)(B1 + (long)srow * 512 + kb + sk0);
    *(bf16x8*)(sB1 + (srow + 64) * 40 + sk0) =
        *(const bf16x8*)(B1 + (long)(srow + 64) * 512 + kb + sk0);
    __syncthreads();
    bf16x8 af0 = *(const bf16x8*)(sA + (wr * 32 + fm) * 40 + quad * 8);
    bf16x8 af1 = *(const bf16x8*)(sA + (wr * 32 + 16 + fm) * 40 + quad * 8);
#pragma unroll
    for (int nt = 0; nt < 4; ++nt) {
      bf16x8 b0 = *(const bf16x8*)(sB0 + (wc * 64 + nt * 16 + fm) * 40 + quad * 8);
      acc0[0][nt] = __builtin_amdgcn_mfma_f32_16x16x32_bf16(af0, b0, acc0[0][nt], 0, 0, 0);
      acc0[1][nt] = __builtin_amdgcn_mfma_f32_16x16x32_bf16(af1, b0, acc0[1][nt], 0, 0, 0);
      bf16x8 b1 = *(const bf16x8*)(sB1 + (wc * 64 + nt * 16 + fm) * 40 + quad * 8);
      acc1[0][nt] = __builtin_amdgcn_mfma_f32_16x16x32_bf16(af0, b1, acc1[0][nt], 0, 0, 0);
      acc1[1][nt] = __builtin_amdgcn_mfma_f32_16x16x32_bf16(af1, b1, acc1[1][nt], 0, 0, 0);
    }
    __syncthreads();
  }
#pragma unroll
  for (int mt = 0; mt < 2; ++mt)
#pragma unroll
    for (int nt = 0; nt < 4; ++nt) {
      int col = blockIdx.y * 128 + wc * 64 + nt * 16 + fm;
#pragma unroll
      for (int r = 0; r < 4; ++r) {
        int row = wr * 32 + mt * 16 + quad * 4 + r;
        hid[(long)(slot0 + row) * F2f + col] =
            (bf16)(silu_f(acc0[mt][nt][r]) * acc1[mt][nt][r]);
      }
    }
}

// ---------------------------------------------------------------------------
// Routed expert stage 2 on transposed bf16 W2: hid @ W2t, weighted scatter.
// BM=64 (slot tile), BN=128, waves 2x2, K=F2f.
// ---------------------------------------------------------------------------
__global__ __launch_bounds__(256) void moeT2_k(
    const int* __restrict__ tileExp, const int* __restrict__ tileStart,
    const int* __restrict__ slotTok, const float* __restrict__ slotW,
    const bf16* __restrict__ hid, const bf16* __restrict__ W2t,
    float* __restrict__ acc) {
  int e = tileExp[blockIdx.x];
  if (e < 0) return;
  int slot0 = tileStart[blockIdx.x];
  __shared__ int sTok[64];
  __shared__ float sW[64];
  __shared__ __align__(16) bf16 sA[64 * 40];
  __shared__ __align__(16) bf16 sB[128 * 40];
  const int tid = threadIdx.x, wave = tid >> 6, lane = tid & 63;
  const int fm = lane & 15, quad = lane >> 4;
  const int wr = wave >> 1, wc = wave & 1;
  if (tid < 64) { sTok[tid] = slotTok[slot0 + tid]; sW[tid] = slotW[slot0 + tid]; }
  __syncthreads();
  const bf16* B = W2t + (long)e * (512 * F2f) + (long)(blockIdx.y * 128) * F2f;
  f32x4 acc0[2][4];
  const f32x4 vz = {0.f, 0.f, 0.f, 0.f};
#pragma unroll
  for (int m = 0; m < 2; ++m)
#pragma unroll
    for (int n = 0; n < 4; ++n) acc0[m][n] = vz;
  const int srow = tid >> 2, sk0 = (tid & 3) * 8;
  for (int kb = 0; kb < F2f; kb += 32) {
    *(bf16x8*)(sA + srow * 40 + sk0) =
        *(const bf16x8*)(hid + (long)(slot0 + srow) * F2f + kb + sk0);
    *(bf16x8*)(sB + srow * 40 + sk0) =
        *(const bf16x8*)(B + (long)srow * F2f + kb + sk0);
    *(bf16x8*)(sB + (srow + 64) * 40 + sk0) =
        *(const bf16x8*)(B + (long)(srow + 64) * F2f + kb + sk0);
    __syncthreads();
    bf16x8 af0 = *(const bf16x8*)(sA + (wr * 32 + fm) * 40 + quad * 8);
    bf16x8 af1 = *(const bf16x8*)(sA + (wr * 32 + 16 + fm) * 40 + quad * 8);
#pragma unroll
    for (int nt = 0; nt < 4; ++nt) {
      bf16x8 b0 = *(const bf16x8*)(sB + (wc * 64 + nt * 16 + fm) * 40 + quad * 8);
      acc0[0][nt] = __builtin_amdgcn_mfma_f32_16x16x32_bf16(af0, b0, acc0[0][nt], 0, 0, 0);
      acc0[1][nt] = __builtin_amdgcn_mfma_f32_16x16x32_bf16(af1, b0, acc0[1][nt], 0, 0, 0);
    }
    __syncthreads();
  }
#pragma unroll
  for (int mt = 0; mt < 2; ++mt)
#pragma unroll
    for (int nt = 0; nt < 4; ++nt) {
      int col = blockIdx.y * 128 + wc * 64 + nt * 16 + fm;
#pragma unroll
      for (int r = 0; r < 4; ++r) {
        int row = wr * 32 + mt * 16 + quad * 4 + r;
        atomicAdd(acc + (long)sTok[row] * 512 + col, acc0[mt][nt][r] * sW[row]);
      }
    }
}

// ---------------------------------------------------------------------------
// Sparse routed expert stage 1 (legacy fallback path).
// ---------------------------------------------------------------------------
template <typename TB, int WANT>
__global__ __launch_bounds__(256) void moe1_k(
    const unsigned short* __restrict__ xdet,
    const int* __restrict__ tileExp, const int* __restrict__ tileStart,
    const int* __restrict__ slotTok,
    const bf16* __restrict__ xfb,
    const TB* __restrict__ W1, const TB* __restrict__ W3,
    bf16* __restrict__ hid, int Ps, int colOff, int Np) {
  if (is_f32(xdet) != WANT) return;
  int e = tileExp[blockIdx.x];
  if (e < 0) return;
  int slot0 = tileStart[blockIdx.x];
  __shared__ int sTok[64];
  __shared__ __align__(16) bf16 sA[64 * 40];
  __shared__ __align__(16) bf16 sB0[64 * 40];
  __shared__ __align__(16) bf16 sB1[64 * 40];
  const int tid = threadIdx.x;
  const int wave = tid >> 6, lane = tid & 63;
  const int fm = lane & 15, quad = lane >> 4;
  if (tid < 64) sTok[tid] = slotTok[slot0 + tid];
  __syncthreads();
  const TB* B0 = W1 + (long)e * 512 * F2f + colOff;
  const TB* B1 = W3 + (long)e * 512 * F2f + colOff;
  const int bn = blockIdx.y;
  f32x4 acc0[4], acc1[4];
  const f32x4 vz = {0.f, 0.f, 0.f, 0.f};
#pragma unroll
  for (int i = 0; i < 4; ++i) { acc0[i] = vz; acc1[i] = vz; }
  const int arow = tid >> 2, ak0 = (tid & 3) * 8;
  const int gn = bn * 64 + lane;
  const int wch = wave * 8;
  for (int kb = 0; kb < 512; kb += 32) {
    int tok = sTok[arow];
    *(bf16x8*)(sA + arow * 40 + ak0) =
        *(const bf16x8*)(xfb + (long)tok * 512 + kb + ak0);
    bf16x8 bv, cv;
    if (gn < Np) {
      const TB* bp = B0 + (long)(kb + wch) * F2f + gn;
      const TB* cp = B1 + (long)(kb + wch) * F2f + gn;
#pragma unroll
      for (int j = 0; j < 8; ++j) {
        bv[j] = (bf16)(float)bp[(long)j * F2f];
        cv[j] = (bf16)(float)cp[(long)j * F2f];
      }
    } else {
#pragma unroll
      for (int j = 0; j < 8; ++j) { bv[j] = (bf16)0.f; cv[j] = (bf16)0.f; }
    }
    *(bf16x8*)(sB0 + lane * 40 + wch) = bv;
    *(bf16x8*)(sB1 + lane * 40 + wch) = cv;
    __syncthreads();
    bf16x8 af = *(const bf16x8*)(sA + (wave * 16 + fm) * 40 + quad * 8);
#pragma unroll
    for (int nt = 0; nt < 4; ++nt) {
      bf16x8 bfr = *(const bf16x8*)(sB0 + (nt * 16 + fm) * 40 + quad * 8);
      acc0[nt] = __builtin_amdgcn_mfma_f32_16x16x32_bf16(af, bfr, acc0[nt], 0, 0, 0);
      bf16x8 bg = *(const bf16x8*)(sB1 + (nt * 16 + fm) * 40 + quad * 8);
      acc1[nt] = __builtin_amdgcn_mfma_f32_16x16x32_bf16(af, bg, acc1[nt], 0, 0, 0);
    }
    __syncthreads();
  }
#pragma unroll
  for (int nt = 0; nt < 4; ++nt) {
    int gcol = bn * 64 + nt * 16 + fm;
    if (gcol >= Np) continue;
#pragma unroll
    for (int r = 0; r < 4; ++r) {
      int row = wave * 16 + quad * 4 + r;
      hid[(long)(slot0 + row) * Ps + gcol] =
          (bf16)(silu_f(acc0[nt][r]) * acc1[nt][r]);
    }
  }
}

// ---------------------------------------------------------------------------
// Sparse routed expert stage 2 (legacy fallback path).
// ---------------------------------------------------------------------------
template <typename TB, int WANT>
__global__ __launch_bounds__(256) void moe2_k(
    const unsigned short* __restrict__ xdet,
    const int* __restrict__ tileExp, const int* __restrict__ tileStart,
    const int* __restrict__ slotTok, const float* __restrict__ slotW,
    const bf16* __restrict__ hid, int Ps, int colOff, int Kp,
    const TB* __restrict__ W2, float* __restrict__ acc) {
  if (is_f32(xdet) != WANT) return;
  int e = tileExp[blockIdx.x];
  if (e < 0) return;
  int slot0 = tileStart[blockIdx.x];
  __shared__ int sTok[64];
  __shared__ float sW[64];
  __shared__ __align__(16) bf16 sA[64 * 40];
  __shared__ __align__(16) bf16 sB0[64 * 40];
  const int tid = threadIdx.x;
  const int wave = tid >> 6, lane = tid & 63;
  const int fm = lane & 15, quad = lane >> 4;
  if (tid < 64) { sTok[tid] = slotTok[slot0 + tid]; sW[tid] = slotW[slot0 + tid]; }
  __syncthreads();
  const TB* B0 = W2 + (long)e * F2f * 512 + (long)colOff * 512;
  const int bn = blockIdx.y;
  f32x4 acc0[4];
  const f32x4 vz = {0.f, 0.f, 0.f, 0.f};
#pragma unroll
  for (int i = 0; i < 4; ++i) acc0[i] = vz;
  const int arow = tid >> 2, ak0 = (tid & 3) * 8;
  const int gn = bn * 64 + lane;
  const int wch = wave * 8;
  for (int kb = 0; kb < Kp; kb += 32) {
    *(bf16x8*)(sA + arow * 40 + ak0) =
        *(const bf16x8*)(hid + (long)(slot0 + arow) * Ps + kb + ak0);
    const TB* bp = B0 + (long)(kb + wch) * 512 + gn;
    bf16x8 bv;
#pragma unroll
    for (int j = 0; j < 8; ++j) bv[j] = (bf16)(float)bp[(long)j * 512];
    *(bf16x8*)(sB0 + lane * 40 + wch) = bv;
    __syncthreads();
    bf16x8 af = *(const bf16x8*)(sA + (wave * 16 + fm) * 40 + quad * 8);
#pragma unroll
    for (int nt = 0; nt < 4; ++nt) {
      bf16x8 bfr = *(const bf16x8*)(sB0 + (nt * 16 + fm) * 40 + quad * 8);
      acc0[nt] = __builtin_amdgcn_mfma_f32_16x16x32_bf16(af, bfr, acc0[nt], 0, 0, 0);
    }
    __syncthreads();
  }
#pragma unroll
  for (int nt = 0; nt < 4; ++nt) {
    int gcol = bn * 64 + nt * 16 + fm;
#pragma unroll
    for (int r = 0; r < 4; ++r) {
      int row = wave * 16 + quad * 4 + r;
      int t = sTok[row];
      float w = sW[row];
      atomicAdd(acc + (long)t * 512 + gcol, acc0[nt][r] * w);
    }
  }
}

// ---------------------------------------------------------------------------
// Fused flash attention. V staged k-major (conflict-free b128 writes).
// ---------------------------------------------------------------------------
__global__ __launch_bounds__(256) void attn_k(const bf16* __restrict__ Q,
                                              const bf16* __restrict__ K,
                                              const bf16* __restrict__ V,
                                              bf16* __restrict__ O) {
  __shared__ __align__(16) bf16 sK[64 * 72];
  __shared__ __align__(16) bf16 sVt[64 * 72];
  __shared__ __align__(16) bf16 sP[4 * 16 * 72];
  const int tid = threadIdx.x, wave = tid >> 6, lane = tid & 63;
  const int fm = lane & 15, quad = lane >> 4;
  const long base = (long)blockIdx.y * Ss * 64;
  const int qrow0 = blockIdx.x * 64 + wave * 16;

  bf16x8 qf[2];
#pragma unroll
  for (int c = 0; c < 2; ++c)
    qf[c] = *(const bf16x8*)(Q + base + (long)(qrow0 + fm) * 64 + c * 32 + quad * 8);

  f32x4 oacc[4];
  const f32x4 vz = {0.f, 0.f, 0.f, 0.f};
#pragma unroll
  for (int i = 0; i < 4; ++i) oacc[i] = vz;
  float m_run[4], l_run[4];
#pragma unroll
  for (int r = 0; r < 4; ++r) { m_run[r] = -1e30f; l_run[r] = 0.f; }

  const int skey = tid >> 2, sd0 = (tid & 3) * 16;
  bf16* sPw = sP + wave * 16 * 72;

  for (int kt = 0; kt < 16; ++kt) {
    __syncthreads();
    const bf16* Kt = K + base + (long)(kt * 64) * 64;
    *(bf16x8*)(sK + skey * 72 + sd0)     = *(const bf16x8*)(Kt + (long)skey * 64 + sd0);
    *(bf16x8*)(sK + skey * 72 + sd0 + 8) = *(const bf16x8*)(Kt + (long)skey * 64 + sd0 + 8);
    const bf16* Vt = V + base + (long)(kt * 64) * 64;
    {
      bf16x8 v0, v1;
#pragma unroll
      for (int j = 0; j < 8; ++j) v0[j] = Vt[(long)(wave * 16 + j) * 64 + lane];
#pragma unroll
      for (int j = 0; j < 8; ++j) v1[j] = Vt[(long)(wave * 16 + 8 + j) * 64 + lane];
      *(bf16x8*)(sVt + lane * 72 + wave * 16) = v0;
      *(bf16x8*)(sVt + lane * 72 + wave * 16 + 8) = v1;
    }
    __syncthreads();
    f32x4 sacc[4];
#pragma unroll
    for (int nt = 0; nt < 4; ++nt) sacc[nt] = vz;
#pragma unroll
    for (int c = 0; c < 2; ++c) {
#pragma unroll
      for (int nt = 0; nt < 4; ++nt) {
        bf16x8 kf = *(const bf16x8*)(sK + (nt * 16 + fm) * 72 + c * 32 + quad * 8);
        sacc[nt] = __builtin_amdgcn_mfma_f32_16x16x32_bf16(qf[c], kf, sacc[nt], 0, 0, 0);
      }
    }
#pragma unroll
    for (int nt = 0; nt < 4; ++nt)
#pragma unroll
      for (int r = 0; r < 4; ++r) sacc[nt][r] *= 0.125f;
    float mt[4];
#pragma unroll
    for (int r = 0; r < 4; ++r) {
      float mx = -1e30f;
#pragma unroll
      for (int nt = 0; nt < 4; ++nt) mx = fmaxf(mx, sacc[nt][r]);
      mt[r] = mx;
    }
#pragma unroll
    for (int i = 1; i < 16; i <<= 1) {
#pragma unroll
      for (int r = 0; r < 4; ++r) mt[r] = fmaxf(mt[r], __shfl_xor(mt[r], i, 64));
    }
    float p[4][4], al[4], rs[4];
#pragma unroll
    for (int r = 0; r < 4; ++r) {
      float m_new = fmaxf(m_run[r], mt[r]);
      al[r] = expf(m_run[r] - m_new);
      m_run[r] = m_new;
      float s = 0.f;
#pragma unroll
      for (int nt = 0; nt < 4; ++nt) {
        float e = expf(sacc[nt][r] - m_new);
        p[nt][r] = e; s += e;
      }
      rs[r] = s;
    }
#pragma unroll
    for (int i = 1; i < 16; i <<= 1) {
#pragma unroll
      for (int r = 0; r < 4; ++r) rs[r] += __shfl_xor(rs[r], i, 64);
    }
#pragma unroll
    for (int r = 0; r < 4; ++r) l_run[r] = l_run[r] * al[r] + rs[r];
#pragma unroll
    for (int nt = 0; nt < 4; ++nt)
#pragma unroll
      for (int r = 0; r < 4; ++r) oacc[nt][r] *= al[r];
#pragma unroll
    for (int nt = 0; nt < 4; ++nt)
#pragma unroll
      for (int r = 0; r < 4; ++r)
        sPw[(quad * 4 + r) * 72 + nt * 16 + fm] = (bf16)p[nt][r];
    __syncthreads();
#pragma unroll
    for (int c = 0; c < 2; ++c) {
      bf16x8 pa = *(const bf16x8*)(sPw + fm * 72 + c * 32 + quad * 8);
#pragma unroll
      for (int nt = 0; nt < 4; ++nt) {
        bf16x8 vf = *(const bf16x8*)(sVt + (nt * 16 + fm) * 72 + c * 32 + quad * 8);
        oacc[nt] = __builtin_amdgcn_mfma_f32_16x16x32_bf16(pa, vf, oacc[nt], 0, 0, 0);
      }
    }
  }
#pragma unroll
  for (int nt = 0; nt < 4; ++nt) {
    int col = nt * 16 + fm;
#pragma unroll
    for (int r = 0; r < 4; ++r) {
      int row = qrow0 + quad * 4 + r;
      O[base + (long)row * 64 + col] = (bf16)(oacc[nt][r] / l_run[r]);
    }
  }
}

// ---------------- LayerNorm (D=512) -> bf16 ---------------------------------
template <typename TX, typename TW, int WANT>
__global__ __launch_bounds__(256) void ln_k(const unsigned short* __restrict__ xdet,
                                            const TX* __restrict__ xi,
                                            const TW* __restrict__ w,
                                            const TW* __restrict__ b,
                                            bf16* __restrict__ obf, float eps) {
  if (is_f32(xdet) != WANT) return;
  __shared__ float sm[4];
  long base = (long)blockIdx.x * 512;
  int tid = threadIdx.x;
  float x0 = (float)xi[base + tid], x1 = (float)xi[base + 256 + tid];
  float mean = blocksum(x0 + x1, sm) * (1.f / 512.f);
  float d0 = x0 - mean, d1 = x1 - mean;
  float var = blocksum(d0 * d0 + d1 * d1, sm) * (1.f / 512.f);
  float r = rsqrtf(var + eps);
  obf[base + tid] = (bf16)(d0 * r * (float)w[tid] + (float)b[tid]);
  obf[base + 256 + tid] = (bf16)(d1 * r * (float)w[256 + tid] + (float)b[256 + tid]);
}

// ---------------- RMSNorm (bf16 in, eps 1e-6) -> bf16 -----------------------
__global__ __launch_bounds__(256) void rms_k(const bf16* __restrict__ xi,
                                             bf16* __restrict__ ob) {
  __shared__ float sm[4];
  long base = (long)blockIdx.x * 512;
  int tid = threadIdx.x;
  float x0 = (float)xi[base + tid], x1 = (float)xi[base + 256 + tid];
  float ms = blocksum(x0 * x0 + x1 * x1, sm) * (1.f / 512.f);
  float r = rsqrtf(ms + 1e-6f);
  ob[base + tid] = (bf16)(x0 * r);
  ob[base + 256 + tid] = (bf16)(x1 * r);
}

// ---- q/k l2norm (in place) + v = v*alpha+beta (in place) -------------------
__global__ __launch_bounds__(256) void postproj_k(
    bf16* __restrict__ q, bf16* __restrict__ k, bf16* __restrict__ v,
    const bf16* __restrict__ al, const bf16* __restrict__ be) {
  int wv = threadIdx.x >> 6, lane = threadIdx.x & 63;
  long i = ((long)blockIdx.x * 4 + wv) * 64 + lane;
  float qv = (float)q[i];
  float nq = sqrtf(wavesum(qv * qv));
  q[i] = (bf16)(qv / fmaxf(nq, 1e-12f));
  float kv = (float)k[i];
  float nk = sqrtf(wavesum(kv * kv));
  k[i] = (bf16)(kv / fmaxf(nk, 1e-12f));
  v[i] = (bf16)((float)v[i] * (float)al[i] + (float)be[i]);
}

// ---- o = rms(o)*arms_w*shortcut, in place ----------------------------------
template <typename T, int WANT>
__global__ __launch_bounds__(256) void orms_k(const unsigned short* __restrict__ xdet,
                                              bf16* __restrict__ o,
                                              const T* __restrict__ arms,
                                              const bf16* __restrict__ sc) {
  if (is_f32(xdet) != WANT) return;
  int wv = threadIdx.x >> 6, lane = threadIdx.x & 63;
  long r = (long)blockIdx.x * 4 + wv;
  long i = r * 64 + lane;
  int h = (int)(r >> 11);
  float ov = (float)o[i];
  float ms = wavesum(ov * ov) * (1.f / 64.f);
  float s = rsqrtf(ms + 1e-6f);
  o[i] = (bf16)(ov * s * (float)arms[h * 64 + lane] * (float)sc[i]);
}

// ---------------- router: fp32 LN inside, logits, top-4 ---------------------
template <typename T, int WANT>
__global__ __launch_bounds__(256) void router_k(const unsigned short* __restrict__ xdet,
                                                const float* __restrict__ x2,
                                                const T* __restrict__ lnw,
                                                const T* __restrict__ lnb,
                                                const T* __restrict__ rdw,
                                                const T* __restrict__ ruw,
                                                int* __restrict__ eidx,
                                                float* __restrict__ ew,
                                                int* __restrict__ counts) {
  if (is_f32(xdet) != WANT) return;
  __shared__ float sx[4][512];
  __shared__ float st[4][64];
  __shared__ float sl[4][32];
  int wv = threadIdx.x >> 6, lane = threadIdx.x & 63;
  long t = (long)blockIdx.x * 4 + wv;
  float v[8];
  float s1 = 0.f;
#pragma unroll
  for (int j = 0; j < 8; ++j) { v[j] = x2[t * 512 + lane * 8 + j]; s1 += v[j]; }
  float mean = wavesum(s1) * (1.f / 512.f);
  float s2 = 0.f;
#pragma unroll
  for (int j = 0; j < 8; ++j) { float d = v[j] - mean; s2 += d * d; }
  float rv = rsqrtf(wavesum(s2) * (1.f / 512.f) + 1e-5f);
#pragma unroll
  for (int j = 0; j < 8; ++j)
    sx[wv][lane * 8 + j] = (v[j] - mean) * rv * (float)lnw[lane * 8 + j] + (float)lnb[lane * 8 + j];
  __syncthreads();
  float acc = 0.f;
  for (int d = 0; d < 512; ++d) acc += sx[wv][d] * (float)rdw[d * 64 + lane];
  st[wv][lane] = acc;
  __syncthreads();
  if (lane < 32) {
    float lg = 0.f;
    for (int r = 0; r < 64; ++r) lg += st[wv][r] * (float)ruw[r * 32 + lane];
    sl[wv][lane] = lg;
  }
  __syncthreads();
  if (lane == 0) {
    float vv[32];
#pragma unroll
    for (int e = 0; e < 32; ++e) vv[e] = sl[wv][e];
    int idx[4]; float tv[4];
#pragma unroll
    for (int k = 0; k < 4; ++k) {
      float best = -1e30f; int bi = 0;
      for (int e = 0; e < 32; ++e)
        if (vv[e] > best) { best = vv[e]; bi = e; }
      tv[k] = best; idx[k] = bi; vv[bi] = -1e30f;
    }
    float m = tv[0], s = 0.f, w[4];
#pragma unroll
    for (int k = 0; k < 4; ++k) { w[k] = expf(tv[k] - m); s += w[k]; }
    float inv = 1.f / s;
#pragma unroll
    for (int k = 0; k < 4; ++k) {
      eidx[t * 4 + k] = idx[k];
      ew[t * 4 + k] = w[k] * inv;
      atomicAdd(&counts[idx[k]], 1);
    }
  }
}

// ---------------- binning kernels -------------------------------------------
__global__ void offsets_k(const int* __restrict__ counts, int* __restrict__ segOff,
                          int* __restrict__ tileExp, int* __restrict__ tileStart) {
  if (threadIdx.x != 0) return;
  int off = 0, ti = 0;
  for (int e = 0; e < Ee; ++e) {
    segOff[e] = off;
    int pc = (counts[e] + 63) & ~63;
    for (int i = 0; i < pc / 64; ++i) { tileExp[ti] = e; tileStart[ti] = off + i * 64; ++ti; }
    off += pc;
  }
  for (; ti < 192; ++ti) tileExp[ti] = -1;
}
__global__ void scatter_k(const int* __restrict__ eidx, const float* __restrict__ ew,
                          const int* __restrict__ segOff, int* __restrict__ cursor,
                          int* __restrict__ slotTok, float* __restrict__ slotW) {
  int t = blockIdx.x * 256 + threadIdx.x;
#pragma unroll
  for (int k = 0; k < 4; ++k) {
    int e = eidx[t * 4 + k];
    int pos = atomicAdd(&cursor[e], 1);
    int s = segOff[e] + pos;
    slotTok[s] = t;
    slotW[s] = ew[t * 4 + k];
  }
}
__global__ void pad_k(const int* __restrict__ counts, const int* __restrict__ segOff,
                      int* __restrict__ slotTok, float* __restrict__ slotW) {
  int e = blockIdx.x;
  int c = counts[e], pc = (c + 63) & ~63;
  for (int i = c + threadIdx.x; i < pc; i += 64) {
    int s = segOff[e] + i;
    slotTok[s] = 0;
    slotW[s] = 0.f;
  }
}

// ---------------- misc ----------------
__global__ void zero_k(float* __restrict__ p, long n) {
  long i = (long)blockIdx.x * blockDim.x + threadIdx.x;
  long st = (long)gridDim.x * blockDim.x;
  for (; i < n; i += st) p[i] = 0.f;
}
template <typename TW, typename TO, int WANT>
__global__ __launch_bounds__(256) void final_k(const unsigned short* __restrict__ xdet,
                                               const float* __restrict__ x2,
                                               const TW* __restrict__ lnw,
                                               const TW* __restrict__ lnb,
                                               const float* __restrict__ acc,
                                               TO* __restrict__ out) {
  if (is_f32(xdet) != WANT) return;
  __shared__ float sm[4];
  long base = (long)blockIdx.x * 512;
  int tid = threadIdx.x;
  float x0 = x2[base + tid], x1 = x2[base + 256 + tid];
  float mean = blocksum(x0 + x1, sm) * (1.f / 512.f);
  float d0 = x0 - mean, d1 = x1 - mean;
  float var = blocksum(d0 * d0 + d1 * d1, sm) * (1.f / 512.f);
  float r = rsqrtf(var + 1e-5f);
  float f0 = d0 * r * (float)lnw[tid] + (float)lnb[tid];
  float f1 = d1 * r * (float)lnw[256 + tid] + (float)lnb[256 + tid];
  out[base + tid] = (TO)(x0 + f0 + acc[base + tid]);
  out[base + 256 + tid] = (TO)(x1 + f1 + acc[base + 256 + tid]);
}
template <typename TO, int WANT>
__global__ void loss_k(const unsigned short* __restrict__ xdet,
                       const int* __restrict__ counts, TO* __restrict__ out) {
  if (is_f32(xdet) != WANT) return;
  int lane = threadIdx.x;
  float c = lane < 32 ? (float)counts[lane] : 0.f;
  float mean = wavesum(c) * (1.f / 32.f);
  float d = lane < 32 ? (c - mean) * (c - mean) : 0.f;
  float var = wavesum(d) * (1.f / 31.f);
  if (lane == 0) out[(long)Tt * 512] = (TO)var;
}

// ---------------- host-side dual-dispatch helper for gemm_k -----------------
template <int ACT, int DUAL, int OUTBF, int ACCUM, int RESID, int ASCALE>
static inline void G(dim3 grid, hipStream_t st, const unsigned short* xdet,
                     const bf16* A, long aB, int lda,
                     const void* ascale, long asOff, long asB,
                     const void* B0, long b0Off, const void* B1, long b1Off,
                     long bB, int bK,
                     const void* bias, int biasB,
                     void* C, long cB, int ldc,
                     const void* resid, int resLd,
                     int N, int K, float scale) {
  gemm_k<float, 1, ACT, DUAL, OUTBF, ACCUM, RESID, ASCALE><<<grid, 256, 0, st>>>(
      xdet, A, aB, lda,
      ascale ? (const float*)ascale + asOff : nullptr, asB,
      (const float*)B0 + b0Off, B1 ? (const float*)B1 + b1Off : nullptr, bB, bK,
      bias ? (const float*)bias : nullptr, biasB, C, cB, ldc,
      resid ? (const float*)resid : nullptr, resLd, N, K, scale);
  gemm_k<bf16, 0, ACT, DUAL, OUTBF, ACCUM, RESID, ASCALE><<<grid, 256, 0, st>>>(
      xdet, A, aB, lda,
      ascale ? (const bf16*)ascale + asOff : nullptr, asB,
      (const bf16*)B0 + b0Off, B1 ? (const bf16*)B1 + b1Off : nullptr, bB, bK,
      bias ? (const bf16*)bias : nullptr, biasB, C, cB, ldc,
      resid ? (const bf16*)resid : nullptr, resLd, N, K, scale);
}

// ---------------- host-side dual-dispatch helper for tconv_k ----------------
template <int SC>
static inline void CVT(hipStream_t st, const unsigned short* xdet, const void* W,
                       const void* sc, bf16* Wt, int K, int N, int batch,
                       long wB, long sB, long oB) {
  dim3 g(K / 64, N / 64, batch);
  tconv_k<float, 1, SC><<<g, 256, 0, st>>>(xdet, (const float*)W, wB,
                                           (const float*)sc, sB, Wt, oB, K, N);
  tconv_k<bf16, 0, SC><<<g, 256, 0, st>>>(xdet, (const bf16*)W, wB,
                                          (const bf16*)sc, sB, Wt, oB, K, N);
}

// ---------------------------------------------------------------------------
extern "C" void kernel_launch(void* const* d_in, const int* in_sizes, int n_in,
                              void* d_out, int out_size, void* d_ws, size_t ws_size,
                              hipStream_t stream) {
  (void)in_sizes; (void)n_in; (void)out_size;
  const void* x    = d_in[0];
  const void* ln1w = d_in[1];
  const void* ln1b = d_in[2];
  const void* ln2w = d_in[3];
  const void* ln2b = d_in[4];
  const void* q_w  = d_in[5];
  const void* q_b  = d_in[6];
  const void* k_w  = d_in[7];
  const void* k_b  = d_in[8];
  const void* v_w  = d_in[9];
  const void* v_b  = d_in[10];
  const void* aw1  = d_in[11];
  const void* ab1  = d_in[12];
  const void* aw2  = d_in[13];
  const void* ab2  = d_in[14];
  const void* bw   = d_in[15];
  const void* bbv  = d_in[16];
  const void* scw1 = d_in[17];
  const void* scb1 = d_in[18];
  const void* scw2 = d_in[19];
  const void* scb2 = d_in[20];
  const void* arms = d_in[21];
  const void* l1w  = d_in[22];
  const void* l1b  = d_in[23];
  const void* outw = d_in[24];
  const void* outb = d_in[25];
  const void* shrms= d_in[26];
  const void* shw1 = d_in[27];
  const void* shw2 = d_in[28];
  const void* shw3 = d_in[29];
  const void* rw1  = d_in[30];
  const void* rw2  = d_in[31];
  const void* rw3  = d_in[32];
  const void* rdw  = d_in[33];
  const void* ruw  = d_in[34];
  const unsigned short* xdet = (const unsigned short*)x;

  // ---- workspace map. Base 16 MiB unchanged; then bf16 weight cache + hid.
  constexpr size_t MB = 1u << 20;
  char* base = (char*)d_ws;
  bf16* xn    = (bf16*)(base + 0 * MB);
  bf16* qh    = (bf16*)(base + 2 * MB);
  bf16* kh    = (bf16*)(base + 4 * MB);
  bf16* vh    = (bf16*)(base + 6 * MB);
  bf16* beta  = (bf16*)(base + 8 * MB);
  bf16* ah    = (bf16*)(base + 10 * MB);
  bf16* alpha = (bf16*)(base + 12 * MB);
  bf16* sch   = (bf16*)(base + 8 * MB);
  bf16* shct  = (bf16*)(base + 14 * MB);
  bf16* oatt  = (bf16*)(base + 8 * MB);
  bf16* conc  = (bf16*)(base + 2 * MB);
  float* x2   = (float*)(base + 4 * MB);
  bf16* xfb   = (bf16*)(base + 0 * MB);
  bf16* rbb   = (bf16*)(base + 2 * MB);
  float* acc  = (float*)(base + 12 * MB);
  int*   hcnt = (int*)(base + 8 * MB);
  int*   hcur = hcnt + 32;
  int*   hseg = hcnt + 64;
  int*   hte  = hcnt + 96;
  int*   hts  = hcnt + 288;
  int*   heidx= hcnt + 512;
  float* hew  = (float*)(hcnt + 512 + 8192);
  int*   hstok= hcnt + 512 + 16384;
  float* hsw  = (float*)(hcnt + 512 + 16384 + 10240);

  // ---- tier decision: transposed-bf16 weight cache sizes ----
  size_t rem = ws_size > (size_t)16 * MB ? ws_size - (size_t)16 * MB : 0;
  const size_t SH1B  = (size_t)NSs * F3f * Dd * 2;   // 12.58 MB each (x3)
  const size_t R1B   = (size_t)Ee * F2f * Dd * 2;    // 33.55 MB each (x3)
  const size_t HIDRT = (size_t)SLOTCAP * F2f * 2;    // 20.97 MB
  const size_t HID1  = (size_t)Tt * F3f * 2;         // 6.29 MB per shared exp
  const bool cvtRt = rem >= 3 * SH1B + 3 * R1B + HIDRT;
  const bool cvtSh = cvtRt || rem >= 3 * SH1B + HID1;
  char* cur = base + (size_t)16 * MB;
  bf16 *sh1t = nullptr, *sh3t = nullptr, *sh2t = nullptr;
  bf16 *r1t = nullptr, *r3t = nullptr, *r2t = nullptr;
  if (cvtSh) {
    sh1t = (bf16*)cur; cur += SH1B;
    sh3t = (bf16*)cur; cur += SH1B;
    sh2t = (bf16*)cur; cur += SH1B;
  }
  if (cvtRt) {
    r1t = (bf16*)cur; cur += R1B;
    r3t = (bf16*)cur; cur += R1B;
    r2t = (bf16*)cur; cur += R1B;
  }
  bf16* hid; long hidElems;
  if (ws_size >= 20 * MB) {
    hid = (bf16*)cur;
    hidElems = (long)((base + ws_size) - cur) / 2;
  } else {
    hid = (bf16*)(base + 8 * MB + 256 * 1024);
    hidElems = (long)(4 * MB - 256 * 1024) / 2;
  }

  // ---- attention sublayer ----
  ln_k<float, float, 1><<<Tt, 256, 0, stream>>>(xdet, (const float*)x, (const float*)ln1w, (const float*)ln1b, xn, 1e-5f);
  ln_k<bf16, bf16, 0><<<Tt, 256, 0, stream>>>(xdet, (const bf16*)x, (const bf16*)ln1w, (const bf16*)ln1b, xn, 1e-5f);

  G<1,0,1,0,0,0>(dim3(32,1,8), stream, xdet, xn,0,512, nullptr,0,0, q_w,0,nullptr,0,(long)512*64,64, q_b,64, qh,(long)Tt*64,64, nullptr,0, 64,512,1.f);
  G<1,0,1,0,0,0>(dim3(32,1,8), stream, xdet, xn,0,512, nullptr,0,0, k_w,0,nullptr,0,(long)512*64,64, k_b,64, kh,(long)Tt*64,64, nullptr,0, 64,512,1.f);
  G<1,0,1,0,0,0>(dim3(32,1,8), stream, xdet, xn,0,512, nullptr,0,0, v_w,0,nullptr,0,(long)512*64,64, v_b,64, vh,(long)Tt*64,64, nullptr,0, 64,512,1.f);
  G<2,0,1,0,0,0>(dim3(32,1,8), stream, xdet, xn,0,512, nullptr,0,0, bw,0,nullptr,0,(long)512*64,64, bbv,64, beta,(long)Tt*64,64, nullptr,0, 64,512,1.f);
  G<0,0,1,0,0,0>(dim3(32,1,8), stream, xdet, xn,0,512, nullptr,0,0, aw1,0,nullptr,0,(long)512*32,32, ab1,32, ah,(long)Tt*32,32, nullptr,0, 32,512,1.f);
  G<2,0,1,0,0,0>(dim3(32,1,8), stream, xdet, ah,(long)Tt*32,32, nullptr,0,0, aw2,0,nullptr,0,(long)32*64,64, ab2,64, alpha,(long)Tt*64,64, nullptr,0, 64,32,1.f);

  postproj_k<<<NHh * Tt / 4, 256, 0, stream>>>(qh, kh, vh, alpha, beta);

  G<0,0,1,0,0,0>(dim3(32,1,8), stream, xdet, xn,0,512, nullptr,0,0, scw1,0,nullptr,0,(long)512*32,32, scb1,32, sch,(long)Tt*32,32, nullptr,0, 32,512,1.f);
  G<2,0,1,0,0,0>(dim3(32,1,8), stream, xdet, sch,(long)Tt*32,32, nullptr,0,0, scw2,0,nullptr,0,(long)32*64,64, scb2,64, shct,(long)Tt*64,64, nullptr,0, 64,32,1.f);

  attn_k<<<dim3(16, 16), 256, 0, stream>>>(qh, kh, vh, oatt);

  orms_k<float, 1><<<NHh * Tt / 4, 256, 0, stream>>>(xdet, oatt, (const float*)arms, shct);
  orms_k<bf16, 0><<<NHh * Tt / 4, 256, 0, stream>>>(xdet, oatt, (const bf16*)arms, shct);

  G<0,0,1,0,0,0>(dim3(32,1,8), stream, xdet, oatt,(long)Tt*64,64, nullptr,0,0, l1w,0,nullptr,0,(long)64*64,64, l1b,64, conc,64,512, nullptr,0, 64,64,1.f);
  G<0,0,0,0,1,0>(dim3(32,8,1), stream, xdet, conc,0,512, nullptr,0,0, outw,0,nullptr,0,0,512, outb,0, x2,0,512, x,512, 512,512,1.f);

  // ---- MoE sublayer ----
  ln_k<float, float, 1><<<Tt, 256, 0, stream>>>(xdet, x2, (const float*)ln2w, (const float*)ln2b, xfb, 1e-5f);
  ln_k<float, bf16, 0><<<Tt, 256, 0, stream>>>(xdet, x2, (const bf16*)ln2w, (const bf16*)ln2b, xfb, 1e-5f);
  rms_k<<<Tt, 256, 0, stream>>>(xfb, rbb);
  zero_k<<<256, 256, 0, stream>>>(acc, (long)Tt * 512);
  zero_k<<<1, 64, 0, stream>>>((float*)hcnt, 64);
  router_k<float, 1><<<Tt / 4, 256, 0, stream>>>(xdet, x2, (const float*)ln2w, (const float*)ln2b, (const float*)rdw, (const float*)ruw, heidx, hew, hcnt);
  router_k<bf16, 0><<<Tt / 4, 256, 0, stream>>>(xdet, x2, (const bf16*)ln2w, (const bf16*)ln2b, (const bf16*)rdw, (const bf16*)ruw, heidx, hew, hcnt);
  offsets_k<<<1, 64, 0, stream>>>(hcnt, hseg, hte, hts);
  scatter_k<<<Tt / 256, 256, 0, stream>>>(heidx, hew, hseg, hcur, hstok, hsw);
  pad_k<<<Ee, 64, 0, stream>>>(hcnt, hseg, hstok, hsw);

  // ---- weight conversion: fp32/bf16 [K][N] -> bf16 [N][K] (rms folded) ----
  if (cvtSh) {
    CVT<1>(stream, xdet, shw1, shrms, sh1t, 512, F3f, NSs, (long)512*F3f, 512, (long)F3f*512);
    CVT<1>(stream, xdet, shw3, shrms, sh3t, 512, F3f, NSs, (long)512*F3f, 512, (long)F3f*512);
    CVT<0>(stream, xdet, shw2, nullptr, sh2t, F3f, 512, NSs, (long)F3f*512, 0, (long)512*F3f);
  }
  if (cvtRt) {
    CVT<0>(stream, xdet, rw1, nullptr, r1t, 512, F2f, Ee, (long)512*F2f, 0, (long)F2f*512);
    CVT<0>(stream, xdet, rw3, nullptr, r3t, 512, F2f, Ee, (long)512*F2f, 0, (long)F2f*512);
    CVT<0>(stream, xdet, rw2, nullptr, r2t, F2f, 512, Ee, (long)F2f*512, 0, (long)512*F2f);
  }

  // ---- shared experts ----
  if (cvtSh) {
    int zB = (int)((hidElems * 2) / (long)HID1);
    if (zB > NSs) zB = NSs;
    if (zB < 1) zB = 1;
    for (int e0 = 0; e0 < NSs; e0 += zB) {
      int zc = NSs - e0 < zB ? NSs - e0 : zB;
      gemmT_k<1, 0><<<dim3(Tt / 128, F3f / 64, zc), 256, 0, stream>>>(
          rbb, 0, 512, sh1t + (long)e0 * F3f * 512, sh3t + (long)e0 * F3f * 512,
          (long)F3f * 512, hid, (long)Tt * F3f, F3f, 512, 1.f);
      gemmT_k<0, 1><<<dim3(Tt / 128, 512 / 64, zc), 256, 0, stream>>>(
          hid, (long)Tt * F3f, F3f, sh2t + (long)e0 * 512 * F3f, nullptr,
          (long)512 * F3f, acc, 0, 512, F3f, 0.125f);
    }
  } else {
    int PsS, zBsh;
    if (hidElems >= (long)Tt * F3f) {
      PsS = F3f;
      zBsh = (int)(hidElems / ((long)Tt * F3f)); if (zBsh > NSs) zBsh = NSs;
    } else {
      PsS = (int)((hidElems / Tt / 32) * 32); if (PsS > F3f) PsS = F3f;
      zBsh = 1;
    }
    for (int n0e = 0; n0e < NSs; n0e += zBsh) {
      int zc = NSs - n0e < zBsh ? NSs - n0e : zBsh;
      for (int off = 0; off < F3f; off += PsS) {
        int Np = F3f - off < PsS ? F3f - off : PsS;
        G<0,1,1,0,0,1>(dim3(32,(Np+63)/64,zc), stream, xdet, rbb,0,512,
                       shrms,(long)n0e*512,512,
                       shw1,(long)n0e*512*F3f + off, shw3,(long)n0e*512*F3f + off,
                       (long)512*F3f, F3f,
                       nullptr,0, hid,(long)Tt*PsS,PsS, nullptr,0, Np,512,1.f);
        G<0,0,0,1,0,0>(dim3(32,8,zc), stream, xdet, hid,(long)Tt*PsS,PsS, nullptr,0,0,
                       shw2,(long)n0e*F3f*512 + (long)off*512, nullptr,0,
                       (long)F3f*512, 512,
                       nullptr,0, acc,0,512, nullptr,0, 512,Np,0.125f);
      }
    }
  }

  // ---- routed experts ----
  if (cvtRt) {
    moeT1_k<<<dim3(MAXTILE, F2f / 128), 256, 0, stream>>>(hte, hts, hstok, xfb, r1t, r3t, hid);
    moeT2_k<<<dim3(MAXTILE, 512 / 128), 256, 0, stream>>>(hte, hts, hstok, hsw, hid, r2t, acc);
  } else {
    int PsR = (int)((hidElems / SLOTCAP / 32) * 32);
    if (PsR > F2f) PsR = F2f;
    if (PsR < 32) PsR = 32;
    for (int off = 0; off < F2f; off += PsR) {
      int Np = F2f - off < PsR ? F2f - off : PsR;
      dim3 g1(MAXTILE, (Np + 63) / 64);
      moe1_k<float, 1><<<g1, 256, 0, stream>>>(xdet, hte, hts, hstok, xfb, (const float*)rw1, (const float*)rw3, hid, PsR, off, Np);
      moe1_k<bf16, 0><<<g1, 256, 0, stream>>>(xdet, hte, hts, hstok, xfb, (const bf16*)rw1, (const bf16*)rw3, hid, PsR, off, Np);
      dim3 g2(MAXTILE, 8);
      moe2_k<float, 1><<<g2, 256, 0, stream>>>(xdet, hte, hts, hstok, hsw, hid, PsR, off, Np, (const float*)rw2, acc);
      moe2_k<bf16, 0><<<g2, 256, 0, stream>>>(xdet, hte, hts, hstok, hsw, hid, PsR, off, Np, (const bf16*)rw2, acc);
    }
  }

  final_k<float, float, 1><<<Tt, 256, 0, stream>>>(xdet, x2, (const float*)ln2w, (const float*)ln2b, acc, (float*)d_out);
  final_k<bf16, bf16, 0><<<Tt, 256, 0, stream>>>(xdet, x2, (const bf16*)ln2w, (const bf16*)ln2b, acc, (bf16*)d_out);
  loss_k<float, 1><<<1, 64, 0, stream>>>(xdet, hcnt, (float*)d_out);
  loss_k<bf16, 0><<<1, 64, 0, stream>>>(xdet, hcnt, (bf16*)d_out);
}

// Round 2
// 999.299 us; speedup vs baseline: 1.1959x; 1.1140x over previous
//
#include <hip/hip_runtime.h>
#include <cmath>
#include <cstdint>

// ---------------------------------------------------------------------------
// TransformerEncoderLayer (attention + MoE) on MI355X, fp32 acc.
// Round 10: moeT2 was pure latency-stall (MfmaUtil 2.5%, VALU 1.7%, HBM 9%,
// occ 13%): per-K-step global->LDS->barrier chain exposed full load latency,
// plus 5.2M+8.4M fp32 atomics in the MoE epilogues.
//  (a) register prefetch in gemmT/moeT1/moeT2: next K-chunk's global loads
//      issue between barrier and MFMA, hiding latency under compute.
//  (b) atomic-free combine: scatter_k records slot per (token,k); moeT2
//      stores w*out to eoRt[slot][512]; shared stage2 stores per-expert to
//      eoSh[e][T][512] (*1/8); final_k gathers+sums. acc/zero_k dropped in
//      the full tier. Tiered on ws_size with fallback to atomic paths.
// ---------------------------------------------------------------------------

typedef __bf16 bf16;
typedef __bf16 bf16x8 __attribute__((ext_vector_type(8)));
typedef __bf16 bf16x4 __attribute__((ext_vector_type(4)));
typedef float  f32x4  __attribute__((ext_vector_type(4)));

static constexpr int Bb = 2, Ss = 1024, Dd = 512, NHh = 8, HDd = 64;
static constexpr int Tt = Bb * Ss;           // 2048 tokens
static constexpr int NSs = 8, F3f = 1536;
static constexpr int Ee = 32, F2f = 1024;
static constexpr int SLOTCAP = 10240;        // 8192 + worst-case pad (10208)
static constexpr int MAXTILE = 160;

// ---------------- helpers ----------------
__device__ inline float wavesum(float v) {
#pragma unroll
  for (int i = 1; i < 64; i <<= 1) v += __shfl_xor(v, i, 64);
  return v;
}
__device__ inline float blocksum(float v, float* sm) {
  v = wavesum(v);
  int wv = threadIdx.x >> 6;
  __syncthreads();
  if ((threadIdx.x & 63) == 0) sm[wv] = v;
  __syncthreads();
  return (sm[0] + sm[1]) + (sm[2] + sm[3]);
}
__device__ inline float silu_f(float x) { return x / (1.f + expf(-x)); }
__device__ inline float sigm_f(float x) { return 1.f / (1.f + expf(-x)); }

// Inline dtype classifier on d_in[0] (x ~ N(0,1)); 1 = fp32 buffer.
__device__ inline int is_f32(const unsigned short* __restrict__ xr) {
  int good = 0;
#pragma unroll
  for (int i = 0; i < 32; ++i) {
    unsigned e = (xr[2 * i] >> 7) & 0xFF;
    good += (e >= 110 && e <= 140);
  }
  return good < 16;
}

// ---------------------------------------------------------------------------
// Flexible MFMA GEMM (legacy path, kept for small projections + fallback).
// ---------------------------------------------------------------------------
template <typename TB, int WANT, int ACT, int DUAL, int OUTBF, int ACCUM,
          int RESID, int ASCALE>
__global__ __launch_bounds__(256) void gemm_k(
    const unsigned short* __restrict__ xdet,
    const bf16* __restrict__ A, long aBatch, int lda,
    const TB* __restrict__ ascale, long asBatch,
    const TB* __restrict__ B0, const TB* __restrict__ B1, long bBatch, int bK,
    const TB* __restrict__ bias, int biasBatch,
    void* __restrict__ Cv, long cBatch, int ldc,
    const TB* __restrict__ resid, int resLd,
    int N, int K, float scale) {
  if (is_f32(xdet) != WANT) return;
  __shared__ __align__(16) bf16 sA[64 * 40];
  __shared__ __align__(16) bf16 sB0[64 * 40];
  __shared__ __align__(16) bf16 sB1[64 * 40];

  const int tid = threadIdx.x;
  const int wave = tid >> 6, lane = tid & 63;
  const int fm = lane & 15, quad = lane >> 4;
  const int bm = blockIdx.x, bn = blockIdx.y, z = blockIdx.z;

  const bf16* Az = A + (long)z * aBatch;
  const TB* B0z = B0 + (long)z * bBatch;
  const TB* B1z = DUAL ? (B1 + (long)z * bBatch) : nullptr;
  const TB* asz = ASCALE ? (ascale + (long)z * asBatch) : nullptr;

  f32x4 acc0[4], acc1[4];
  const f32x4 vzero = {0.f, 0.f, 0.f, 0.f};
#pragma unroll
  for (int i = 0; i < 4; ++i) { acc0[i] = vzero; acc1[i] = vzero; }

  const int arow = tid >> 2, ak0 = (tid & 3) * 8;   // A staging (row-major)
  const int gn = bn * 64 + lane;                    // B staging (k-major)
  const int wch = wave * 8;                         // this wave's k-chunk

  for (int kb = 0; kb < K; kb += 32) {
    bf16x8 av = *(const bf16x8*)(Az + (long)(bm * 64 + arow) * lda + kb + ak0);
    if (ASCALE) {
#pragma unroll
      for (int j = 0; j < 8; ++j)
        av[j] = (bf16)((float)av[j] * (float)asz[kb + ak0 + j]);
    }
    *(bf16x8*)(sA + arow * 40 + ak0) = av;
    bf16x8 bv, cv;
    if (gn < N) {
      const TB* bp = B0z + (long)(kb + wch) * bK + gn;
#pragma unroll
      for (int j = 0; j < 8; ++j) bv[j] = (bf16)(float)bp[(long)j * bK];
      if (DUAL) {
        const TB* cp = B1z + (long)(kb + wch) * bK + gn;
#pragma unroll
        for (int j = 0; j < 8; ++j) cv[j] = (bf16)(float)cp[(long)j * bK];
      }
    } else {
#pragma unroll
      for (int j = 0; j < 8; ++j) { bv[j] = (bf16)0.f; if (DUAL) cv[j] = (bf16)0.f; }
    }
    *(bf16x8*)(sB0 + lane * 40 + wch) = bv;
    if (DUAL) *(bf16x8*)(sB1 + lane * 40 + wch) = cv;
    __syncthreads();
    bf16x8 af = *(const bf16x8*)(sA + (wave * 16 + fm) * 40 + quad * 8);
#pragma unroll
    for (int nt = 0; nt < 4; ++nt) {
      bf16x8 bfr = *(const bf16x8*)(sB0 + (nt * 16 + fm) * 40 + quad * 8);
      acc0[nt] = __builtin_amdgcn_mfma_f32_16x16x32_bf16(af, bfr, acc0[nt], 0, 0, 0);
      if (DUAL) {
        bf16x8 bg = *(const bf16x8*)(sB1 + (nt * 16 + fm) * 40 + quad * 8);
        acc1[nt] = __builtin_amdgcn_mfma_f32_16x16x32_bf16(af, bg, acc1[nt], 0, 0, 0);
      }
    }
    __syncthreads();
  }

#pragma unroll
  for (int nt = 0; nt < 4; ++nt) {
    int gcol = bn * 64 + nt * 16 + fm;
    if (gcol >= N) continue;
#pragma unroll
    for (int r = 0; r < 4; ++r) {
      int grow = bm * 64 + wave * 16 + quad * 4 + r;
      float v;
      if (DUAL) {
        v = silu_f(acc0[nt][r]) * acc1[nt][r];
      } else {
        v = acc0[nt][r] * scale;
        if (bias) v += (float)bias[z * biasBatch + gcol];
        if (ACT == 1) v = silu_f(v);
        else if (ACT == 2) v = sigm_f(v);
      }
      if (RESID) v += (float)resid[(long)grow * resLd + gcol];
      long ci = (long)z * cBatch + (long)grow * ldc + gcol;
      if (ACCUM) atomicAdd((float*)Cv + ci, v);
      else if (OUTBF) ((bf16*)Cv)[ci] = (bf16)v;
      else ((float*)Cv)[ci] = v;
    }
  }
}

// ---------------------------------------------------------------------------
// Weight transpose+convert: W [K][N] (fp32 or bf16) -> Wt [N][K] bf16,
// optional per-k scale fold (rmsnorm weight). 64x64 LDS tile transpose.
// ---------------------------------------------------------------------------
template <typename TI, int WANT, int SCALE>
__global__ __launch_bounds__(256) void tconv_k(
    const unsigned short* __restrict__ xdet,
    const TI* __restrict__ W, long wBatch,
    const TI* __restrict__ sc, long sBatch,
    bf16* __restrict__ Wt, long oBatch, int K, int N) {
  if (is_f32(xdet) != WANT) return;
  __shared__ float sT[64][65];
  const int tid = threadIdx.x;
  const int k0 = blockIdx.x * 64, n0 = blockIdx.y * 64, z = blockIdx.z;
  const TI* Wz = W + (long)z * wBatch;
  const int rr = tid >> 4, cc = (tid & 15) * 4;
#pragma unroll
  for (int it = 0; it < 4; ++it) {
    int row = it * 16 + rr;
    const TI* p = Wz + (long)(k0 + row) * N + n0 + cc;
    float v0, v1, v2, v3;
    if constexpr (sizeof(TI) == 4) {
      float4 v = *(const float4*)p;
      v0 = v.x; v1 = v.y; v2 = v.z; v3 = v.w;
    } else {
      bf16x4 v = *(const bf16x4*)p;
      v0 = (float)v[0]; v1 = (float)v[1]; v2 = (float)v[2]; v3 = (float)v[3];
    }
    if (SCALE) {
      float s = (float)sc[(long)z * sBatch + k0 + row];
      v0 *= s; v1 *= s; v2 *= s; v3 *= s;
    }
    sT[row][cc + 0] = v0; sT[row][cc + 1] = v1;
    sT[row][cc + 2] = v2; sT[row][cc + 3] = v3;
  }
  __syncthreads();
  bf16* Oz = Wt + (long)z * oBatch;
#pragma unroll
  for (int it = 0; it < 4; ++it) {
    int n = it * 16 + rr;
    bf16x4 ov;
#pragma unroll
    for (int j = 0; j < 4; ++j) ov[j] = (bf16)sT[cc + j][n];
    *(bf16x4*)(Oz + (long)(n0 + n) * K + k0 + cc) = ov;
  }
}

// ---------------------------------------------------------------------------
// Dense GEMM on n-major bf16 B (Wt). BM=128, BN=64, BK=32, 4 waves over M.
// Register-prefetched staging (next K-chunk loads issued under MFMA).
// ACCUM: 0 = bf16 store, 1 = atomicAdd fp32*scale, 2 = plain fp32 store*scale.
// ---------------------------------------------------------------------------
template <int DUAL, int ACCUM>
__global__ __launch_bounds__(256) void gemmT_k(
    const bf16* __restrict__ A, long aBatch, int lda,
    const bf16* __restrict__ B0t, const bf16* __restrict__ B1t, long bBatch,
    void* __restrict__ Cv, long cBatch, int ldc, int K, float scale) {
  __shared__ __align__(16) bf16 sA[128 * 40];
  __shared__ __align__(16) bf16 sB0[64 * 40];
  __shared__ __align__(16) bf16 sB1[DUAL ? 64 * 40 : 16];
  const int tid = threadIdx.x, wave = tid >> 6, lane = tid & 63;
  const int fm = lane & 15, quad = lane >> 4;
  const bf16* Az = A + (long)blockIdx.z * aBatch + (long)(blockIdx.x * 128) * lda;
  const bf16* B0z = B0t + (long)blockIdx.z * bBatch + (long)(blockIdx.y * 64) * K;
  const bf16* B1z = DUAL ? (B1t + (long)blockIdx.z * bBatch + (long)(blockIdx.y * 64) * K) : nullptr;
  f32x4 acc0[2][4], acc1[2][4];
  const f32x4 vz = {0.f, 0.f, 0.f, 0.f};
#pragma unroll
  for (int m = 0; m < 2; ++m)
#pragma unroll
    for (int n = 0; n < 4; ++n) { acc0[m][n] = vz; acc1[m][n] = vz; }
  const int srow = tid >> 2, sk0 = (tid & 3) * 8;
  const bf16* Ap0 = Az + (long)srow * lda + sk0;
  const bf16* Ap1 = Az + (long)(srow + 64) * lda + sk0;
  const bf16* Bp0 = B0z + (long)srow * K + sk0;
  const bf16* Bp1 = DUAL ? (B1z + (long)srow * K + sk0) : Bp0;
  bf16x8 rA0 = *(const bf16x8*)(Ap0);
  bf16x8 rA1 = *(const bf16x8*)(Ap1);
  bf16x8 rB0 = *(const bf16x8*)(Bp0);
  bf16x8 rB1 = rB0;
  if (DUAL) rB1 = *(const bf16x8*)(Bp1);
  for (int kb = 0; kb < K; kb += 32) {
    *(bf16x8*)(sA + srow * 40 + sk0) = rA0;
    *(bf16x8*)(sA + (srow + 64) * 40 + sk0) = rA1;
    *(bf16x8*)(sB0 + srow * 40 + sk0) = rB0;
    if (DUAL) *(bf16x8*)(sB1 + srow * 40 + sk0) = rB1;
    __syncthreads();
    int kn = kb + 32 < K ? kb + 32 : kb;
    rA0 = *(const bf16x8*)(Ap0 + kn);
    rA1 = *(const bf16x8*)(Ap1 + kn);
    rB0 = *(const bf16x8*)(Bp0 + kn);
    if (DUAL) rB1 = *(const bf16x8*)(Bp1 + kn);
    bf16x8 af0 = *(const bf16x8*)(sA + (wave * 32 + fm) * 40 + quad * 8);
    bf16x8 af1 = *(const bf16x8*)(sA + (wave * 32 + 16 + fm) * 40 + quad * 8);
#pragma unroll
    for (int nt = 0; nt < 4; ++nt) {
      bf16x8 b0 = *(const bf16x8*)(sB0 + (nt * 16 + fm) * 40 + quad * 8);
      acc0[0][nt] = __builtin_amdgcn_mfma_f32_16x16x32_bf16(af0, b0, acc0[0][nt], 0, 0, 0);
      acc0[1][nt] = __builtin_amdgcn_mfma_f32_16x16x32_bf16(af1, b0, acc0[1][nt], 0, 0, 0);
      if (DUAL) {
        bf16x8 b1 = *(const bf16x8*)(sB1 + (nt * 16 + fm) * 40 + quad * 8);
        acc1[0][nt] = __builtin_amdgcn_mfma_f32_16x16x32_bf16(af0, b1, acc1[0][nt], 0, 0, 0);
        acc1[1][nt] = __builtin_amdgcn_mfma_f32_16x16x32_bf16(af1, b1, acc1[1][nt], 0, 0, 0);
      }
    }
    __syncthreads();
  }
#pragma unroll
  for (int mt = 0; mt < 2; ++mt)
#pragma unroll
    for (int nt = 0; nt < 4; ++nt) {
      int col = blockIdx.y * 64 + nt * 16 + fm;
#pragma unroll
      for (int r = 0; r < 4; ++r) {
        int row = blockIdx.x * 128 + wave * 32 + mt * 16 + quad * 4 + r;
        long ci = (long)blockIdx.z * cBatch + (long)row * ldc + col;
        if (DUAL) {
          ((bf16*)Cv)[ci] = (bf16)(silu_f(acc0[mt][nt][r]) * acc1[mt][nt][r]);
        } else {
          float v = acc0[mt][nt][r] * scale;
          if (ACCUM == 1) atomicAdd((float*)Cv + ci, v);
          else if (ACCUM == 2) ((float*)Cv)[ci] = v;
          else ((bf16*)Cv)[ci] = (bf16)v;
        }
      }
    }
}

// ---------------------------------------------------------------------------
// Routed expert stage 1 on transposed bf16 weights: gathered dual-SwiGLU.
// BM=64 (slot tile), BN=128, waves 2x2, register-prefetched staging.
// ---------------------------------------------------------------------------
__global__ __launch_bounds__(256) void moeT1_k(
    const int* __restrict__ tileExp, const int* __restrict__ tileStart,
    const int* __restrict__ slotTok, const bf16* __restrict__ xfb,
    const bf16* __restrict__ W1t, const bf16* __restrict__ W3t,
    bf16* __restrict__ hid) {
  int e = tileExp[blockIdx.x];
  if (e < 0) return;
  int slot0 = tileStart[blockIdx.x];
  __shared__ int sTok[64];
  __shared__ __align__(16) bf16 sA[64 * 40];
  __shared__ __align__(16) bf16 sB0[128 * 40];
  __shared__ __align__(16) bf16 sB1[128 * 40];
  const int tid = threadIdx.x, wave = tid >> 6, lane = tid & 63;
  const int fm = lane & 15, quad = lane >> 4;
  const int wr = wave >> 1, wc = wave & 1;
  if (tid < 64) sTok[tid] = slotTok[slot0 + tid];
  __syncthreads();
  const bf16* B0 = W1t + (long)e * (F2f * 512) + (long)(blockIdx.y * 128) * 512;
  const bf16* B1 = W3t + (long)e * (F2f * 512) + (long)(blockIdx.y * 128) * 512;
  f32x4 acc0[2][4], acc1[2][4];
  const f32x4 vz = {0.f, 0.f, 0.f, 0.f};
#pragma unroll
  for (int m = 0; m < 2; ++m)
#pragma unroll
    for (int n = 0; n < 4; ++n) { acc0[m][n] = vz; acc1[m][n] = vz; }
  const int srow = tid >> 2, sk0 = (tid & 3) * 8;
  const bf16* Ap  = xfb + (long)sTok[srow] * 512 + sk0;
  const bf16* B0p = B0 + (long)srow * 512 + sk0;
  const bf16* B0q = B0 + (long)(srow + 64) * 512 + sk0;
  const bf16* B1p = B1 + (long)srow * 512 + sk0;
  const bf16* B1q = B1 + (long)(srow + 64) * 512 + sk0;
  bf16x8 rA  = *(const bf16x8*)(Ap);
  bf16x8 rB0 = *(const bf16x8*)(B0p);
  bf16x8 rB1 = *(const bf16x8*)(B0q);
  bf16x8 rB2 = *(const bf16x8*)(B1p);
  bf16x8 rB3 = *(const bf16x8*)(B1q);
  for (int kb = 0; kb < 512; kb += 32) {
    *(bf16x8*)(sA + srow * 40 + sk0) = rA;
    *(bf16x8*)(sB0 + srow * 40 + sk0) = rB0;
    *(bf16x8*)(sB0 + (srow + 64) * 40 + sk0) = rB1;
    *(bf16x8*)(sB1 + srow * 40 + sk0) = rB2;
    *(bf16x8*)(sB1 + (srow + 64) * 40 + sk0) = rB3;
    __syncthreads();
    int kn = kb + 32 < 512 ? kb + 32 : kb;
    rA  = *(const bf16x8*)(Ap + kn);
    rB0 = *(const bf16x8*)(B0p + kn);
    rB1 = *(const bf16x8*)(B0q + kn);
    rB2 = *(const bf16x8*)(B1p + kn);
    rB3 = *(const bf16x8*)(B1q + kn);
    bf16x8 af0 = *(const bf16x8*)(sA + (wr * 32 + fm) * 40 + quad * 8);
    bf16x8 af1 = *(const bf16x8*)(sA + (wr * 32 + 16 + fm) * 40 + quad * 8);
#pragma unroll
    for (int nt = 0; nt < 4; ++nt) {
      bf16x8 b0 = *(const bf16x8*)(sB0 + (wc * 64 + nt * 16 + fm) * 40 + quad * 8);
      acc0[0][nt] = __builtin_amdgcn_mfma_f32_16x16x32_bf16(af0, b0, acc0[0][nt], 0, 0, 0);
      acc0[1][nt] = __builtin_amdgcn_mfma_f32_16x16x32_bf16(af1, b0, acc0[1][nt], 0, 0, 0);
      bf16x8 b1 = *(const bf16x8*)(sB1 + (wc * 64 + nt * 16 + fm) * 40 + quad * 8);
      acc1[0][nt] = __builtin_amdgcn_mfma_f32_16x16x32_bf16(af0, b1, acc1[0][nt], 0, 0, 0);
      acc1[1][nt] = __builtin_amdgcn_mfma_f32_16x16x32_bf16(af1, b1, acc1[1][nt], 0, 0, 0);
    }
    __syncthreads();
  }
#pragma unroll
  for (int mt = 0; mt < 2; ++mt)
#pragma unroll
    for (int nt = 0; nt < 4; ++nt) {
      int col = blockIdx.y * 128 + wc * 64 + nt * 16 + fm;
#pragma unroll
      for (int r = 0; r < 4; ++r) {
        int row = wr * 32 + mt * 16 + quad * 4 + r;
        hid[(long)(slot0 + row) * F2f + col] =
            (bf16)(silu_f(acc0[mt][nt][r]) * acc1[mt][nt][r]);
      }
    }
}

// ---------------------------------------------------------------------------
// Routed expert stage 2: hid @ W2t. GATHER=1: plain store w*out -> eoRt.
// GATHER=0: atomicAdd into acc (fallback). Register-prefetched staging.
// ---------------------------------------------------------------------------
template <int GATHER>
__global__ __launch_bounds__(256) void moeT2_k(
    const int* __restrict__ tileExp, const int* __restrict__ tileStart,
    const int* __restrict__ slotTok, const float* __restrict__ slotW,
    const bf16* __restrict__ hid, const bf16* __restrict__ W2t,
    float* __restrict__ acc, float* __restrict__ eoRt) {
  int e = tileExp[blockIdx.x];
  if (e < 0) return;
  int slot0 = tileStart[blockIdx.x];
  __shared__ int sTok[64];
  __shared__ float sW[64];
  __shared__ __align__(16) bf16 sA[64 * 40];
  __shared__ __align__(16) bf16 sB[128 * 40];
  const int tid = threadIdx.x, wave = tid >> 6, lane = tid & 63;
  const int fm = lane & 15, quad = lane >> 4;
  const int wr = wave >> 1, wc = wave & 1;
  if (tid < 64) { sTok[tid] = slotTok[slot0 + tid]; sW[tid] = slotW[slot0 + tid]; }
  const bf16* B = W2t + (long)e * (512 * F2f) + (long)(blockIdx.y * 128) * F2f;
  f32x4 acc0[2][4];
  const f32x4 vz = {0.f, 0.f, 0.f, 0.f};
#pragma unroll
  for (int m = 0; m < 2; ++m)
#pragma unroll
    for (int n = 0; n < 4; ++n) acc0[m][n] = vz;
  const int srow = tid >> 2, sk0 = (tid & 3) * 8;
  const bf16* Ap  = hid + (long)(slot0 + srow) * F2f + sk0;
  const bf16* Bp0 = B + (long)srow * F2f + sk0;
  const bf16* Bp1 = B + (long)(srow + 64) * F2f + sk0;
  bf16x8 rA  = *(const bf16x8*)(Ap);
  bf16x8 rB0 = *(const bf16x8*)(Bp0);
  bf16x8 rB1 = *(const bf16x8*)(Bp1);
  for (int kb = 0; kb < F2f; kb += 32) {
    *(bf16x8*)(sA + srow * 40 + sk0) = rA;
    *(bf16x8*)(sB + srow * 40 + sk0) = rB0;
    *(bf16x8*)(sB + (srow + 64) * 40 + sk0) = rB1;
    __syncthreads();
    int kn = kb + 32 < F2f ? kb + 32 : kb;
    rA  = *(const bf16x8*)(Ap + kn);
    rB0 = *(const bf16x8*)(Bp0 + kn);
    rB1 = *(const bf16x8*)(Bp1 + kn);
    bf16x8 af0 = *(const bf16x8*)(sA + (wr * 32 + fm) * 40 + quad * 8);
    bf16x8 af1 = *(const bf16x8*)(sA + (wr * 32 + 16 + fm) * 40 + quad * 8);
#pragma unroll
    for (int nt = 0; nt < 4; ++nt) {
      bf16x8 b0 = *(const bf16x8*)(sB + (wc * 64 + nt * 16 + fm) * 40 + quad * 8);
      acc0[0][nt] = __builtin_amdgcn_mfma_f32_16x16x32_bf16(af0, b0, acc0[0][nt], 0, 0, 0);
      acc0[1][nt] = __builtin_amdgcn_mfma_f32_16x16x32_bf16(af1, b0, acc0[1][nt], 0, 0, 0);
    }
    __syncthreads();
  }
#pragma unroll
  for (int mt = 0; mt < 2; ++mt)
#pragma unroll
    for (int nt = 0; nt < 4; ++nt) {
      int col = blockIdx.y * 128 + wc * 64 + nt * 16 + fm;
#pragma unroll
      for (int r = 0; r < 4; ++r) {
        int row = wr * 32 + mt * 16 + quad * 4 + r;
        if (GATHER) {
          eoRt[(long)(slot0 + row) * 512 + col] = acc0[mt][nt][r] * sW[row];
        } else {
          atomicAdd(acc + (long)sTok[row] * 512 + col, acc0[mt][nt][r] * sW[row]);
        }
      }
    }
}

// ---------------------------------------------------------------------------
// Sparse routed expert stage 1 (legacy fallback path).
// ---------------------------------------------------------------------------
template <typename TB, int WANT>
__global__ __launch_bounds__(256) void moe1_k(
    const unsigned short* __restrict__ xdet,
    const int* __restrict__ tileExp, const int* __restrict__ tileStart,
    const int* __restrict__ slotTok,
    const bf16* __restrict__ xfb,
    const TB* __restrict__ W1, const TB* __restrict__ W3,
    bf16* __restrict__ hid, int Ps, int colOff, int Np) {
  if (is_f32(xdet) != WANT) return;
  int e = tileExp[blockIdx.x];
  if (e < 0) return;
  int slot0 = tileStart[blockIdx.x];
  __shared__ int sTok[64];
  __shared__ __align__(16) bf16 sA[64 * 40];
  __shared__ __align__(16) bf16 sB0[64 * 40];
  __shared__ __align__(16) bf16 sB1[64 * 40];
  const int tid = threadIdx.x;
  const int wave = tid >> 6, lane = tid & 63;
  const int fm = lane & 15, quad = lane >> 4;
  if (tid < 64) sTok[tid] = slotTok[slot0 + tid];
  __syncthreads();
  const TB* B0 = W1 + (long)e * 512 * F2f + colOff;
  const TB* B1 = W3 + (long)e * 512 * F2f + colOff;
  const int bn = blockIdx.y;
  f32x4 acc0[4], acc1[4];
  const f32x4 vz = {0.f, 0.f, 0.f, 0.f};
#pragma unroll
  for (int i = 0; i < 4; ++i) { acc0[i] = vz; acc1[i] = vz; }
  const int arow = tid >> 2, ak0 = (tid & 3) * 8;
  const int gn = bn * 64 + lane;
  const int wch = wave * 8;
  for (int kb = 0; kb < 512; kb += 32) {
    int tok = sTok[arow];
    *(bf16x8*)(sA + arow * 40 + ak0) =
        *(const bf16x8*)(xfb + (long)tok * 512 + kb + ak0);
    bf16x8 bv, cv;
    if (gn < Np) {
      const TB* bp = B0 + (long)(kb + wch) * F2f + gn;
      const TB* cp = B1 + (long)(kb + wch) * F2f + gn;
#pragma unroll
      for (int j = 0; j < 8; ++j) {
        bv[j] = (bf16)(float)bp[(long)j * F2f];
        cv[j] = (bf16)(float)cp[(long)j * F2f];
      }
    } else {
#pragma unroll
      for (int j = 0; j < 8; ++j) { bv[j] = (bf16)0.f; cv[j] = (bf16)0.f; }
    }
    *(bf16x8*)(sB0 + lane * 40 + wch) = bv;
    *(bf16x8*)(sB1 + lane * 40 + wch) = cv;
    __syncthreads();
    bf16x8 af = *(const bf16x8*)(sA + (wave * 16 + fm) * 40 + quad * 8);
#pragma unroll
    for (int nt = 0; nt < 4; ++nt) {
      bf16x8 bfr = *(const bf16x8*)(sB0 + (nt * 16 + fm) * 40 + quad * 8);
      acc0[nt] = __builtin_amdgcn_mfma_f32_16x16x32_bf16(af, bfr, acc0[nt], 0, 0, 0);
      bf16x8 bg = *(const bf16x8*)(sB1 + (nt * 16 + fm) * 40 + quad * 8);
      acc1[nt] = __builtin_amdgcn_mfma_f32_16x16x32_bf16(af, bg, acc1[nt], 0, 0, 0);
    }
    __syncthreads();
  }
#pragma unroll
  for (int nt = 0; nt < 4; ++nt) {
    int gcol = bn * 64 + nt * 16 + fm;
    if (gcol >= Np) continue;
#pragma unroll
    for (int r = 0; r < 4; ++r) {
      int row = wave * 16 + quad * 4 + r;
      hid[(long)(slot0 + row) * Ps + gcol] =
          (bf16)(silu_f(acc0[nt][r]) * acc1[nt][r]);
    }
  }
}

// ---------------------------------------------------------------------------
// Sparse routed expert stage 2 (legacy fallback path).
// ---------------------------------------------------------------------------
template <typename TB, int WANT>
__global__ __launch_bounds__(256) void moe2_k(
    const unsigned short* __restrict__ xdet,
    const int* __restrict__ tileExp, const int* __restrict__ tileStart,
    const int* __restrict__ slotTok, const float* __restrict__ slotW,
    const bf16* __restrict__ hid, int Ps, int colOff, int Kp,
    const TB* __restrict__ W2, float* __restrict__ acc) {
  if (is_f32(xdet) != WANT) return;
  int e = tileExp[blockIdx.x];
  if (e < 0) return;
  int slot0 = tileStart[blockIdx.x];
  __shared__ int sTok[64];
  __shared__ float sW[64];
  __shared__ __align__(16) bf16 sA[64 * 40];
  __shared__ __align__(16) bf16 sB0[64 * 40];
  const int tid = threadIdx.x;
  const int wave = tid >> 6, lane = tid & 63;
  const int fm = lane & 15, quad = lane >> 4;
  if (tid < 64) { sTok[tid] = slotTok[slot0 + tid]; sW[tid] = slotW[slot0 + tid]; }
  __syncthreads();
  const TB* B0 = W2 + (long)e * F2f * 512 + (long)colOff * 512;
  const int bn = blockIdx.y;
  f32x4 acc0[4];
  const f32x4 vz = {0.f, 0.f, 0.f, 0.f};
#pragma unroll
  for (int i = 0; i < 4; ++i) acc0[i] = vz;
  const int arow = tid >> 2, ak0 = (tid & 3) * 8;
  const int gn = bn * 64 + lane;
  const int wch = wave * 8;
  for (int kb = 0; kb < Kp; kb += 32) {
    *(bf16x8*)(sA + arow * 40 + ak0) =
        *(const bf16x8*)(hid + (long)(slot0 + arow) * Ps + kb + ak0);
    const TB* bp = B0 + (long)(kb + wch) * 512 + gn;
    bf16x8 bv;
#pragma unroll
    for (int j = 0; j < 8; ++j) bv[j] = (bf16)(float)bp[(long)j * 512];
    *(bf16x8*)(sB0 + lane * 40 + wch) = bv;
    __syncthreads();
    bf16x8 af = *(const bf16x8*)(sA + (wave * 16 + fm) * 40 + quad * 8);
#pragma unroll
    for (int nt = 0; nt < 4; ++nt) {
      bf16x8 bfr = *(const bf16x8*)(sB0 + (nt * 16 + fm) * 40 + quad * 8);
      acc0[nt] = __builtin_amdgcn_mfma_f32_16x16x32_bf16(af, bfr, acc0[nt], 0, 0, 0);
    }
    __syncthreads();
  }
#pragma unroll
  for (int nt = 0; nt < 4; ++nt) {
    int gcol = bn * 64 + nt * 16 + fm;
#pragma unroll
    for (int r = 0; r < 4; ++r) {
      int row = wave * 16 + quad * 4 + r;
      int t = sTok[row];
      float w = sW[row];
      atomicAdd(acc + (long)t * 512 + gcol, acc0[nt][r] * w);
    }
  }
}

// ---------------------------------------------------------------------------
// Fused flash attention. V staged k-major (conflict-free b128 writes).
// ---------------------------------------------------------------------------
__global__ __launch_bounds__(256) void attn_k(const bf16* __restrict__ Q,
                                              const bf16* __restrict__ K,
                                              const bf16* __restrict__ V,
                                              bf16* __restrict__ O) {
  __shared__ __align__(16) bf16 sK[64 * 72];
  __shared__ __align__(16) bf16 sVt[64 * 72];
  __shared__ __align__(16) bf16 sP[4 * 16 * 72];
  const int tid = threadIdx.x, wave = tid >> 6, lane = tid & 63;
  const int fm = lane & 15, quad = lane >> 4;
  const long base = (long)blockIdx.y * Ss * 64;
  const int qrow0 = blockIdx.x * 64 + wave * 16;

  bf16x8 qf[2];
#pragma unroll
  for (int c = 0; c < 2; ++c)
    qf[c] = *(const bf16x8*)(Q + base + (long)(qrow0 + fm) * 64 + c * 32 + quad * 8);

  f32x4 oacc[4];
  const f32x4 vz = {0.f, 0.f, 0.f, 0.f};
#pragma unroll
  for (int i = 0; i < 4; ++i) oacc[i] = vz;
  float m_run[4], l_run[4];
#pragma unroll
  for (int r = 0; r < 4; ++r) { m_run[r] = -1e30f; l_run[r] = 0.f; }

  const int skey = tid >> 2, sd0 = (tid & 3) * 16;
  bf16* sPw = sP + wave * 16 * 72;

  for (int kt = 0; kt < 16; ++kt) {
    __syncthreads();
    const bf16* Kt = K + base + (long)(kt * 64) * 64;
    *(bf16x8*)(sK + skey * 72 + sd0)     = *(const bf16x8*)(Kt + (long)skey * 64 + sd0);
    *(bf16x8*)(sK + skey * 72 + sd0 + 8) = *(const bf16x8*)(Kt + (long)skey * 64 + sd0 + 8);
    const bf16* Vt = V + base + (long)(kt * 64) * 64;
    {
      bf16x8 v0, v1;
#pragma unroll
      for (int j = 0; j < 8; ++j) v0[j] = Vt[(long)(wave * 16 + j) * 64 + lane];
#pragma unroll
      for (int j = 0; j < 8; ++j) v1[j] = Vt[(long)(wave * 16 + 8 + j) * 64 + lane];
      *(bf16x8*)(sVt + lane * 72 + wave * 16) = v0;
      *(bf16x8*)(sVt + lane * 72 + wave * 16 + 8) = v1;
    }
    __syncthreads();
    f32x4 sacc[4];
#pragma unroll
    for (int nt = 0; nt < 4; ++nt) sacc[nt] = vz;
#pragma unroll
    for (int c = 0; c < 2; ++c) {
#pragma unroll
      for (int nt = 0; nt < 4; ++nt) {
        bf16x8 kf = *(const bf16x8*)(sK + (nt * 16 + fm) * 72 + c * 32 + quad * 8);
        sacc[nt] = __builtin_amdgcn_mfma_f32_16x16x32_bf16(qf[c], kf, sacc[nt], 0, 0, 0);
      }
    }
#pragma unroll
    for (int nt = 0; nt < 4; ++nt)
#pragma unroll
      for (int r = 0; r < 4; ++r) sacc[nt][r] *= 0.125f;
    float mt[4];
#pragma unroll
    for (int r = 0; r < 4; ++r) {
      float mx = -1e30f;
#pragma unroll
      for (int nt = 0; nt < 4; ++nt) mx = fmaxf(mx, sacc[nt][r]);
      mt[r] = mx;
    }
#pragma unroll
    for (int i = 1; i < 16; i <<= 1) {
#pragma unroll
      for (int r = 0; r < 4; ++r) mt[r] = fmaxf(mt[r], __shfl_xor(mt[r], i, 64));
    }
    float p[4][4], al[4], rs[4];
#pragma unroll
    for (int r = 0; r < 4; ++r) {
      float m_new = fmaxf(m_run[r], mt[r]);
      al[r] = expf(m_run[r] - m_new);
      m_run[r] = m_new;
      float s = 0.f;
#pragma unroll
      for (int nt = 0; nt < 4; ++nt) {
        float e = expf(sacc[nt][r] - m_new);
        p[nt][r] = e; s += e;
      }
      rs[r] = s;
    }
#pragma unroll
    for (int i = 1; i < 16; i <<= 1) {
#pragma unroll
      for (int r = 0; r < 4; ++r) rs[r] += __shfl_xor(rs[r], i, 64);
    }
#pragma unroll
    for (int r = 0; r < 4; ++r) l_run[r] = l_run[r] * al[r] + rs[r];
#pragma unroll
    for (int nt = 0; nt < 4; ++nt)
#pragma unroll
      for (int r = 0; r < 4; ++r) oacc[nt][r] *= al[r];
#pragma unroll
    for (int nt = 0; nt < 4; ++nt)
#pragma unroll
      for (int r = 0; r < 4; ++r)
        sPw[(quad * 4 + r) * 72 + nt * 16 + fm] = (bf16)p[nt][r];
    __syncthreads();
#pragma unroll
    for (int c = 0; c < 2; ++c) {
      bf16x8 pa = *(const bf16x8*)(sPw + fm * 72 + c * 32 + quad * 8);
#pragma unroll
      for (int nt = 0; nt < 4; ++nt) {
        bf16x8 vf = *(const bf16x8*)(sVt + (nt * 16 + fm) * 72 + c * 32 + quad * 8);
        oacc[nt] = __builtin_amdgcn_mfma_f32_16x16x32_bf16(pa, vf, oacc[nt], 0, 0, 0);
      }
    }
  }
#pragma unroll
  for (int nt = 0; nt < 4; ++nt) {
    int col = nt * 16 + fm;
#pragma unroll
    for (int r = 0; r < 4; ++r) {
      int row = qrow0 + quad * 4 + r;
      O[base + (long)row * 64 + col] = (bf16)(oacc[nt][r] / l_run[r]);
    }
  }
}

// ---------------- LayerNorm (D=512) -> bf16 ---------------------------------
template <typename TX, typename TW, int WANT>
__global__ __launch_bounds__(256) void ln_k(const unsigned short* __restrict__ xdet,
                                            const TX* __restrict__ xi,
                                            const TW* __restrict__ w,
                                            const TW* __restrict__ b,
                                            bf16* __restrict__ obf, float eps) {
  if (is_f32(xdet) != WANT) return;
  __shared__ float sm[4];
  long base = (long)blockIdx.x * 512;
  int tid = threadIdx.x;
  float x0 = (float)xi[base + tid], x1 = (float)xi[base + 256 + tid];
  float mean = blocksum(x0 + x1, sm) * (1.f / 512.f);
  float d0 = x0 - mean, d1 = x1 - mean;
  float var = blocksum(d0 * d0 + d1 * d1, sm) * (1.f / 512.f);
  float r = rsqrtf(var + eps);
  obf[base + tid] = (bf16)(d0 * r * (float)w[tid] + (float)b[tid]);
  obf[base + 256 + tid] = (bf16)(d1 * r * (float)w[256 + tid] + (float)b[256 + tid]);
}

// ---------------- RMSNorm (bf16 in, eps 1e-6) -> bf16 -----------------------
__global__ __launch_bounds__(256) void rms_k(const bf16* __restrict__ xi,
                                             bf16* __restrict__ ob) {
  __shared__ float sm[4];
  long base = (long)blockIdx.x * 512;
  int tid = threadIdx.x;
  float x0 = (float)xi[base + tid], x1 = (float)xi[base + 256 + tid];
  float ms = blocksum(x0 * x0 + x1 * x1, sm) * (1.f / 512.f);
  float r = rsqrtf(ms + 1e-6f);
  ob[base + tid] = (bf16)(x0 * r);
  ob[base + 256 + tid] = (bf16)(x1 * r);
}

// ---- q/k l2norm (in place) + v = v*alpha+beta (in place) -------------------
__global__ __launch_bounds__(256) void postproj_k(
    bf16* __restrict__ q, bf16* __restrict__ k, bf16* __restrict__ v,
    const bf16* __restrict__ al, const bf16* __restrict__ be) {
  int wv = threadIdx.x >> 6, lane = threadIdx.x & 63;
  long i = ((long)blockIdx.x * 4 + wv) * 64 + lane;
  float qv = (float)q[i];
  float nq = sqrtf(wavesum(qv * qv));
  q[i] = (bf16)(qv / fmaxf(nq, 1e-12f));
  float kv = (float)k[i];
  float nk = sqrtf(wavesum(kv * kv));
  k[i] = (bf16)(kv / fmaxf(nk, 1e-12f));
  v[i] = (bf16)((float)v[i] * (float)al[i] + (float)be[i]);
}

// ---- o = rms(o)*arms_w*shortcut, in place ----------------------------------
template <typename T, int WANT>
__global__ __launch_bounds__(256) void orms_k(const unsigned short* __restrict__ xdet,
                                              bf16* __restrict__ o,
                                              const T* __restrict__ arms,
                                              const bf16* __restrict__ sc) {
  if (is_f32(xdet) != WANT) return;
  int wv = threadIdx.x >> 6, lane = threadIdx.x & 63;
  long r = (long)blockIdx.x * 4 + wv;
  long i = r * 64 + lane;
  int h = (int)(r >> 11);
  float ov = (float)o[i];
  float ms = wavesum(ov * ov) * (1.f / 64.f);
  float s = rsqrtf(ms + 1e-6f);
  o[i] = (bf16)(ov * s * (float)arms[h * 64 + lane] * (float)sc[i]);
}

// ---------------- router: fp32 LN inside, logits, top-4 ---------------------
template <typename T, int WANT>
__global__ __launch_bounds__(256) void router_k(const unsigned short* __restrict__ xdet,
                                                const float* __restrict__ x2,
                                                const T* __restrict__ lnw,
                                                const T* __restrict__ lnb,
                                                const T* __restrict__ rdw,
                                                const T* __restrict__ ruw,
                                                int* __restrict__ eidx,
                                                float* __restrict__ ew,
                                                int* __restrict__ counts) {
  if (is_f32(xdet) != WANT) return;
  __shared__ float sx[4][512];
  __shared__ float st[4][64];
  __shared__ float sl[4][32];
  int wv = threadIdx.x >> 6, lane = threadIdx.x & 63;
  long t = (long)blockIdx.x * 4 + wv;
  float v[8];
  float s1 = 0.f;
#pragma unroll
  for (int j = 0; j < 8; ++j) { v[j] = x2[t * 512 + lane * 8 + j]; s1 += v[j]; }
  float mean = wavesum(s1) * (1.f / 512.f);
  float s2 = 0.f;
#pragma unroll
  for (int j = 0; j < 8; ++j) { float d = v[j] - mean; s2 += d * d; }
  float rv = rsqrtf(wavesum(s2) * (1.f / 512.f) + 1e-5f);
#pragma unroll
  for (int j = 0; j < 8; ++j)
    sx[wv][lane * 8 + j] = (v[j] - mean) * rv * (float)lnw[lane * 8 + j] + (float)lnb[lane * 8 + j];
  __syncthreads();
  float acc = 0.f;
  for (int d = 0; d < 512; ++d) acc += sx[wv][d] * (float)rdw[d * 64 + lane];
  st[wv][lane] = acc;
  __syncthreads();
  if (lane < 32) {
    float lg = 0.f;
    for (int r = 0; r < 64; ++r) lg += st[wv][r] * (float)ruw[r * 32 + lane];
    sl[wv][lane] = lg;
  }
  __syncthreads();
  if (lane == 0) {
    float vv[32];
#pragma unroll
    for (int e = 0; e < 32; ++e) vv[e] = sl[wv][e];
    int idx[4]; float tv[4];
#pragma unroll
    for (int k = 0; k < 4; ++k) {
      float best = -1e30f; int bi = 0;
      for (int e = 0; e < 32; ++e)
        if (vv[e] > best) { best = vv[e]; bi = e; }
      tv[k] = best; idx[k] = bi; vv[bi] = -1e30f;
    }
    float m = tv[0], s = 0.f, w[4];
#pragma unroll
    for (int k = 0; k < 4; ++k) { w[k] = expf(tv[k] - m); s += w[k]; }
    float inv = 1.f / s;
#pragma unroll
    for (int k = 0; k < 4; ++k) {
      eidx[t * 4 + k] = idx[k];
      ew[t * 4 + k] = w[k] * inv;
      atomicAdd(&counts[idx[k]], 1);
    }
  }
}

// ---------------- binning kernels -------------------------------------------
__global__ void offsets_k(const int* __restrict__ counts, int* __restrict__ segOff,
                          int* __restrict__ tileExp, int* __restrict__ tileStart) {
  if (threadIdx.x != 0) return;
  int off = 0, ti = 0;
  for (int e = 0; e < Ee; ++e) {
    segOff[e] = off;
    int pc = (counts[e] + 63) & ~63;
    for (int i = 0; i < pc / 64; ++i) { tileExp[ti] = e; tileStart[ti] = off + i * 64; ++ti; }
    off += pc;
  }
  for (; ti < 192; ++ti) tileExp[ti] = -1;
}
__global__ void scatter_k(const int* __restrict__ eidx, const float* __restrict__ ew,
                          const int* __restrict__ segOff, int* __restrict__ cursor,
                          int* __restrict__ slotTok, float* __restrict__ slotW,
                          int* __restrict__ slotOf) {
  int t = blockIdx.x * 256 + threadIdx.x;
#pragma unroll
  for (int k = 0; k < 4; ++k) {
    int e = eidx[t * 4 + k];
    int pos = atomicAdd(&cursor[e], 1);
    int s = segOff[e] + pos;
    slotTok[s] = t;
    slotW[s] = ew[t * 4 + k];
    slotOf[t * 4 + k] = s;
  }
}
__global__ void pad_k(const int* __restrict__ counts, const int* __restrict__ segOff,
                      int* __restrict__ slotTok, float* __restrict__ slotW) {
  int e = blockIdx.x;
  int c = counts[e], pc = (c + 63) & ~63;
  for (int i = c + threadIdx.x; i < pc; i += 64) {
    int s = segOff[e] + i;
    slotTok[s] = 0;
    slotW[s] = 0.f;
  }
}

// ---------------- misc ----------------
__global__ void zero_k(float* __restrict__ p, long n) {
  long i = (long)blockIdx.x * blockDim.x + threadIdx.x;
  long st = (long)gridDim.x * blockDim.x;
  for (; i < n; i += st) p[i] = 0.f;
}
template <typename TW, typename TO, int WANT>
__global__ __launch_bounds__(256) void final_k(const unsigned short* __restrict__ xdet,
                                               const float* __restrict__ x2,
                                               const TW* __restrict__ lnw,
                                               const TW* __restrict__ lnb,
                                               const float* __restrict__ acc,
                                               const float* __restrict__ eoSh,
                                               const float* __restrict__ eoRt,
                                               const int* __restrict__ slotOf,
                                               TO* __restrict__ out) {
  if (is_f32(xdet) != WANT) return;
  __shared__ float sm[4];
  long base = (long)blockIdx.x * 512;
  int tid = threadIdx.x;
  float x0 = x2[base + tid], x1 = x2[base + 256 + tid];
  float mean = blocksum(x0 + x1, sm) * (1.f / 512.f);
  float d0 = x0 - mean, d1 = x1 - mean;
  float var = blocksum(d0 * d0 + d1 * d1, sm) * (1.f / 512.f);
  float r = rsqrtf(var + 1e-5f);
  float f0 = d0 * r * (float)lnw[tid] + (float)lnb[tid];
  float f1 = d1 * r * (float)lnw[256 + tid] + (float)lnb[256 + tid];
  float a0 = 0.f, a1 = 0.f;
  if (acc) { a0 = acc[base + tid]; a1 = acc[base + 256 + tid]; }
  if (eoSh) {
#pragma unroll
    for (int e2 = 0; e2 < NSs; ++e2) {
      a0 += eoSh[(long)e2 * Tt * 512 + base + tid];
      a1 += eoSh[(long)e2 * Tt * 512 + base + 256 + tid];
    }
  }
  if (eoRt) {
    long t = blockIdx.x;
#pragma unroll
    for (int k2 = 0; k2 < 4; ++k2) {
      long s = slotOf[t * 4 + k2];
      a0 += eoRt[s * 512 + tid];
      a1 += eoRt[s * 512 + 256 + tid];
    }
  }
  out[base + tid] = (TO)(x0 + f0 + a0);
  out[base + 256 + tid] = (TO)(x1 + f1 + a1);
}
template <typename TO, int WANT>
__global__ void loss_k(const unsigned short* __restrict__ xdet,
                       const int* __restrict__ counts, TO* __restrict__ out) {
  if (is_f32(xdet) != WANT) return;
  int lane = threadIdx.x;
  float c = lane < 32 ? (float)counts[lane] : 0.f;
  float mean = wavesum(c) * (1.f / 32.f);
  float d = lane < 32 ? (c - mean) * (c - mean) : 0.f;
  float var = wavesum(d) * (1.f / 31.f);
  if (lane == 0) out[(long)Tt * 512] = (TO)var;
}

// ---------------- host-side dual-dispatch helper for gemm_k -----------------
template <int ACT, int DUAL, int OUTBF, int ACCUM, int RESID, int ASCALE>
static inline void G(dim3 grid, hipStream_t st, const unsigned short* xdet,
                     const bf16* A, long aB, int lda,
                     const void* ascale, long asOff, long asB,
                     const void* B0, long b0Off, const void* B1, long b1Off,
                     long bB, int bK,
                     const void* bias, int biasB,
                     void* C, long cB, int ldc,
                     const void* resid, int resLd,
                     int N, int K, float scale) {
  gemm_k<float, 1, ACT, DUAL, OUTBF, ACCUM, RESID, ASCALE><<<grid, 256, 0, st>>>(
      xdet, A, aB, lda,
      ascale ? (const float*)ascale + asOff : nullptr, asB,
      (const float*)B0 + b0Off, B1 ? (const float*)B1 + b1Off : nullptr, bB, bK,
      bias ? (const float*)bias : nullptr, biasB, C, cB, ldc,
      resid ? (const float*)resid : nullptr, resLd, N, K, scale);
  gemm_k<bf16, 0, ACT, DUAL, OUTBF, ACCUM, RESID, ASCALE><<<grid, 256, 0, st>>>(
      xdet, A, aB, lda,
      ascale ? (const bf16*)ascale + asOff : nullptr, asB,
      (const bf16*)B0 + b0Off, B1 ? (const bf16*)B1 + b1Off : nullptr, bB, bK,
      bias ? (const bf16*)bias : nullptr, biasB, C, cB, ldc,
      resid ? (const bf16*)resid : nullptr, resLd, N, K, scale);
}

// ---------------- host-side dual-dispatch helper for tconv_k ----------------
template <int SC>
static inline void CVT(hipStream_t st, const unsigned short* xdet, const void* W,
                       const void* sc, bf16* Wt, int K, int N, int batch,
                       long wB, long sB, long oB) {
  dim3 g(K / 64, N / 64, batch);
  tconv_k<float, 1, SC><<<g, 256, 0, st>>>(xdet, (const float*)W, wB,
                                           (const float*)sc, sB, Wt, oB, K, N);
  tconv_k<bf16, 0, SC><<<g, 256, 0, st>>>(xdet, (const bf16*)W, wB,
                                          (const bf16*)sc, sB, Wt, oB, K, N);
}

// ---------------------------------------------------------------------------
extern "C" void kernel_launch(void* const* d_in, const int* in_sizes, int n_in,
                              void* d_out, int out_size, void* d_ws, size_t ws_size,
                              hipStream_t stream) {
  (void)in_sizes; (void)n_in; (void)out_size;
  const void* x    = d_in[0];
  const void* ln1w = d_in[1];
  const void* ln1b = d_in[2];
  const void* ln2w = d_in[3];
  const void* ln2b = d_in[4];
  const void* q_w  = d_in[5];
  const void* q_b  = d_in[6];
  const void* k_w  = d_in[7];
  const void* k_b  = d_in[8];
  const void* v_w  = d_in[9];
  const void* v_b  = d_in[10];
  const void* aw1  = d_in[11];
  const void* ab1  = d_in[12];
  const void* aw2  = d_in[13];
  const void* ab2  = d_in[14];
  const void* bw   = d_in[15];
  const void* bbv  = d_in[16];
  const void* scw1 = d_in[17];
  const void* scb1 = d_in[18];
  const void* scw2 = d_in[19];
  const void* scb2 = d_in[20];
  const void* arms = d_in[21];
  const void* l1w  = d_in[22];
  const void* l1b  = d_in[23];
  const void* outw = d_in[24];
  const void* outb = d_in[25];
  const void* shrms= d_in[26];
  const void* shw1 = d_in[27];
  const void* shw2 = d_in[28];
  const void* shw3 = d_in[29];
  const void* rw1  = d_in[30];
  const void* rw2  = d_in[31];
  const void* rw3  = d_in[32];
  const void* rdw  = d_in[33];
  const void* ruw  = d_in[34];
  const unsigned short* xdet = (const unsigned short*)x;

  // ---- workspace map. Base 16 MiB unchanged; then bf16 cache + eo + hid.
  constexpr size_t MB = 1u << 20;
  char* base = (char*)d_ws;
  bf16* xn    = (bf16*)(base + 0 * MB);
  bf16* qh    = (bf16*)(base + 2 * MB);
  bf16* kh    = (bf16*)(base + 4 * MB);
  bf16* vh    = (bf16*)(base + 6 * MB);
  bf16* beta  = (bf16*)(base + 8 * MB);
  bf16* ah    = (bf16*)(base + 10 * MB);
  bf16* alpha = (bf16*)(base + 12 * MB);
  bf16* sch   = (bf16*)(base + 8 * MB);
  bf16* shct  = (bf16*)(base + 14 * MB);
  bf16* oatt  = (bf16*)(base + 8 * MB);
  bf16* conc  = (bf16*)(base + 2 * MB);
  float* x2   = (float*)(base + 4 * MB);
  bf16* xfb   = (bf16*)(base + 0 * MB);
  bf16* rbb   = (bf16*)(base + 2 * MB);
  float* acc  = (float*)(base + 12 * MB);
  int*   hcnt = (int*)(base + 8 * MB);
  int*   hcur = hcnt + 32;
  int*   hseg = hcnt + 64;
  int*   hte  = hcnt + 96;
  int*   hts  = hcnt + 288;
  int*   heidx= hcnt + 512;
  float* hew  = (float*)(hcnt + 512 + 8192);
  int*   hstok= hcnt + 512 + 16384;
  float* hsw  = (float*)(hcnt + 512 + 16384 + 10240);
  int*   hslot= hcnt + 512 + 16384 + 20480;

  // ---- tier decision ----
  size_t rem = ws_size > (size_t)16 * MB ? ws_size - (size_t)16 * MB : 0;
  const size_t SH1B  = (size_t)NSs * F3f * Dd * 2;   // 12.58 MB each (x3)
  const size_t R1B   = (size_t)Ee * F2f * Dd * 2;    // 33.55 MB each (x3)
  const size_t HIDRT = (size_t)SLOTCAP * F2f * 2;    // 20.97 MB
  const size_t HID1  = (size_t)Tt * F3f * 2;         // 6.29 MB per shared exp
  const size_t EORT  = (size_t)SLOTCAP * 512 * 4;    // 20.97 MB
  const size_t EOSH  = (size_t)NSs * Tt * 512 * 4;   // 33.55 MB
  const bool cvtRt = rem >= 3 * SH1B + 3 * R1B + HIDRT;
  const bool cvtSh = cvtRt || rem >= 3 * SH1B + HID1;
  char* cur = base + (size_t)16 * MB;
  bf16 *sh1t = nullptr, *sh3t = nullptr, *sh2t = nullptr;
  bf16 *r1t = nullptr, *r3t = nullptr, *r2t = nullptr;
  size_t used = 0;
  if (cvtSh) {
    sh1t = (bf16*)cur; cur += SH1B;
    sh3t = (bf16*)cur; cur += SH1B;
    sh2t = (bf16*)cur; cur += SH1B;
    used += 3 * SH1B;
  }
  if (cvtRt) {
    r1t = (bf16*)cur; cur += R1B;
    r3t = (bf16*)cur; cur += R1B;
    r2t = (bf16*)cur; cur += R1B;
    used += 3 * R1B;
  }
  bool gather = false;
  float* eoRt = nullptr;
  float* eoSh = nullptr;
  if (cvtRt && rem - used >= EORT + HIDRT) {
    eoRt = (float*)cur; cur += EORT; used += EORT; gather = true;
  }
  if (gather && rem - used >= EOSH + HIDRT) {
    eoSh = (float*)cur; cur += EOSH; used += EOSH;
  }
  bf16* hid; long hidElems;
  if (ws_size >= 20 * MB) {
    hid = (bf16*)cur;
    hidElems = (long)((base + ws_size) - cur) / 2;
  } else {
    hid = (bf16*)(base + 8 * MB + 256 * 1024);
    hidElems = (long)(4 * MB - 256 * 1024) / 2;
  }
  const bool accUsed = (eoSh == nullptr) || !gather;

  // ---- attention sublayer ----
  ln_k<float, float, 1><<<Tt, 256, 0, stream>>>(xdet, (const float*)x, (const float*)ln1w, (const float*)ln1b, xn, 1e-5f);
  ln_k<bf16, bf16, 0><<<Tt, 256, 0, stream>>>(xdet, (const bf16*)x, (const bf16*)ln1w, (const bf16*)ln1b, xn, 1e-5f);

  G<1,0,1,0,0,0>(dim3(32,1,8), stream, xdet, xn,0,512, nullptr,0,0, q_w,0,nullptr,0,(long)512*64,64, q_b,64, qh,(long)Tt*64,64, nullptr,0, 64,512,1.f);
  G<1,0,1,0,0,0>(dim3(32,1,8), stream, xdet, xn,0,512, nullptr,0,0, k_w,0,nullptr,0,(long)512*64,64, k_b,64, kh,(long)Tt*64,64, nullptr,0, 64,512,1.f);
  G<1,0,1,0,0,0>(dim3(32,1,8), stream, xdet, xn,0,512, nullptr,0,0, v_w,0,nullptr,0,(long)512*64,64, v_b,64, vh,(long)Tt*64,64, nullptr,0, 64,512,1.f);
  G<2,0,1,0,0,0>(dim3(32,1,8), stream, xdet, xn,0,512, nullptr,0,0, bw,0,nullptr,0,(long)512*64,64, bbv,64, beta,(long)Tt*64,64, nullptr,0, 64,512,1.f);
  G<0,0,1,0,0,0>(dim3(32,1,8), stream, xdet, xn,0,512, nullptr,0,0, aw1,0,nullptr,0,(long)512*32,32, ab1,32, ah,(long)Tt*32,32, nullptr,0, 32,512,1.f);
  G<2,0,1,0,0,0>(dim3(32,1,8), stream, xdet, ah,(long)Tt*32,32, nullptr,0,0, aw2,0,nullptr,0,(long)32*64,64, ab2,64, alpha,(long)Tt*64,64, nullptr,0, 64,32,1.f);

  postproj_k<<<NHh * Tt / 4, 256, 0, stream>>>(qh, kh, vh, alpha, beta);

  G<0,0,1,0,0,0>(dim3(32,1,8), stream, xdet, xn,0,512, nullptr,0,0, scw1,0,nullptr,0,(long)512*32,32, scb1,32, sch,(long)Tt*32,32, nullptr,0, 32,512,1.f);
  G<2,0,1,0,0,0>(dim3(32,1,8), stream, xdet, sch,(long)Tt*32,32, nullptr,0,0, scw2,0,nullptr,0,(long)32*64,64, scb2,64, shct,(long)Tt*64,64, nullptr,0, 64,32,1.f);

  attn_k<<<dim3(16, 16), 256, 0, stream>>>(qh, kh, vh, oatt);

  orms_k<float, 1><<<NHh * Tt / 4, 256, 0, stream>>>(xdet, oatt, (const float*)arms, shct);
  orms_k<bf16, 0><<<NHh * Tt / 4, 256, 0, stream>>>(xdet, oatt, (const bf16*)arms, shct);

  G<0,0,1,0,0,0>(dim3(32,1,8), stream, xdet, oatt,(long)Tt*64,64, nullptr,0,0, l1w,0,nullptr,0,(long)64*64,64, l1b,64, conc,64,512, nullptr,0, 64,64,1.f);
  G<0,0,0,0,1,0>(dim3(32,8,1), stream, xdet, conc,0,512, nullptr,0,0, outw,0,nullptr,0,0,512, outb,0, x2,0,512, x,512, 512,512,1.f);

  // ---- MoE sublayer ----
  ln_k<float, float, 1><<<Tt, 256, 0, stream>>>(xdet, x2, (const float*)ln2w, (const float*)ln2b, xfb, 1e-5f);
  ln_k<float, bf16, 0><<<Tt, 256, 0, stream>>>(xdet, x2, (const bf16*)ln2w, (const bf16*)ln2b, xfb, 1e-5f);
  rms_k<<<Tt, 256, 0, stream>>>(xfb, rbb);
  if (accUsed) zero_k<<<256, 256, 0, stream>>>(acc, (long)Tt * 512);
  zero_k<<<1, 64, 0, stream>>>((float*)hcnt, 64);
  router_k<float, 1><<<Tt / 4, 256, 0, stream>>>(xdet, x2, (const float*)ln2w, (const float*)ln2b, (const float*)rdw, (const float*)ruw, heidx, hew, hcnt);
  router_k<bf16, 0><<<Tt / 4, 256, 0, stream>>>(xdet, x2, (const bf16*)ln2w, (const bf16*)ln2b, (const bf16*)rdw, (const bf16*)ruw, heidx, hew, hcnt);
  offsets_k<<<1, 64, 0, stream>>>(hcnt, hseg, hte, hts);
  scatter_k<<<Tt / 256, 256, 0, stream>>>(heidx, hew, hseg, hcur, hstok, hsw, hslot);
  pad_k<<<Ee, 64, 0, stream>>>(hcnt, hseg, hstok, hsw);

  // ---- weight conversion: fp32/bf16 [K][N] -> bf16 [N][K] (rms folded) ----
  if (cvtSh) {
    CVT<1>(stream, xdet, shw1, shrms, sh1t, 512, F3f, NSs, (long)512*F3f, 512, (long)F3f*512);
    CVT<1>(stream, xdet, shw3, shrms, sh3t, 512, F3f, NSs, (long)512*F3f, 512, (long)F3f*512);
    CVT<0>(stream, xdet, shw2, nullptr, sh2t, F3f, 512, NSs, (long)F3f*512, 0, (long)512*F3f);
  }
  if (cvtRt) {
    CVT<0>(stream, xdet, rw1, nullptr, r1t, 512, F2f, Ee, (long)512*F2f, 0, (long)F2f*512);
    CVT<0>(stream, xdet, rw3, nullptr, r3t, 512, F2f, Ee, (long)512*F2f, 0, (long)F2f*512);
    CVT<0>(stream, xdet, rw2, nullptr, r2t, F2f, 512, Ee, (long)F2f*512, 0, (long)512*F2f);
  }

  // ---- shared experts ----
  if (cvtSh) {
    int zB = (int)(((size_t)hidElems * 2) / HID1);
    if (zB > NSs) zB = NSs;
    if (zB < 1) zB = 1;
    for (int e0 = 0; e0 < NSs; e0 += zB) {
      int zc = NSs - e0 < zB ? NSs - e0 : zB;
      gemmT_k<1, 0><<<dim3(Tt / 128, F3f / 64, zc), 256, 0, stream>>>(
          rbb, 0, 512, sh1t + (long)e0 * F3f * 512, sh3t + (long)e0 * F3f * 512,
          (long)F3f * 512, hid, (long)Tt * F3f, F3f, 512, 1.f);
      if (eoSh) {
        gemmT_k<0, 2><<<dim3(Tt / 128, 512 / 64, zc), 256, 0, stream>>>(
            hid, (long)Tt * F3f, F3f, sh2t + (long)e0 * 512 * F3f, nullptr,
            (long)512 * F3f, eoSh + (long)e0 * Tt * 512, (long)Tt * 512, 512,
            F3f, 0.125f);
      } else {
        gemmT_k<0, 1><<<dim3(Tt / 128, 512 / 64, zc), 256, 0, stream>>>(
            hid, (long)Tt * F3f, F3f, sh2t + (long)e0 * 512 * F3f, nullptr,
            (long)512 * F3f, acc, 0, 512, F3f, 0.125f);
      }
    }
  } else {
    int PsS, zBsh;
    if (hidElems >= (long)Tt * F3f) {
      PsS = F3f;
      zBsh = (int)(hidElems / ((long)Tt * F3f)); if (zBsh > NSs) zBsh = NSs;
    } else {
      PsS = (int)((hidElems / Tt / 32) * 32); if (PsS > F3f) PsS = F3f;
      zBsh = 1;
    }
    for (int n0e = 0; n0e < NSs; n0e += zBsh) {
      int zc = NSs - n0e < zBsh ? NSs - n0e : zBsh;
      for (int off = 0; off < F3f; off += PsS) {
        int Np = F3f - off < PsS ? F3f - off : PsS;
        G<0,1,1,0,0,1>(dim3(32,(Np+63)/64,zc), stream, xdet, rbb,0,512,
                       shrms,(long)n0e*512,512,
                       shw1,(long)n0e*512*F3f + off, shw3,(long)n0e*512*F3f + off,
                       (long)512*F3f, F3f,
                       nullptr,0, hid,(long)Tt*PsS,PsS, nullptr,0, Np,512,1.f);
        G<0,0,0,1,0,0>(dim3(32,8,zc), stream, xdet, hid,(long)Tt*PsS,PsS, nullptr,0,0,
                       shw2,(long)n0e*F3f*512 + (long)off*512, nullptr,0,
                       (long)F3f*512, 512,
                       nullptr,0, acc,0,512, nullptr,0, 512,Np,0.125f);
      }
    }
  }

  // ---- routed experts ----
  if (cvtRt) {
    moeT1_k<<<dim3(MAXTILE, F2f / 128), 256, 0, stream>>>(hte, hts, hstok, xfb, r1t, r3t, hid);
    if (gather) {
      moeT2_k<1><<<dim3(MAXTILE, 512 / 128), 256, 0, stream>>>(hte, hts, hstok, hsw, hid, r2t, acc, eoRt);
    } else {
      moeT2_k<0><<<dim3(MAXTILE, 512 / 128), 256, 0, stream>>>(hte, hts, hstok, hsw, hid, r2t, acc, nullptr);
    }
  } else {
    int PsR = (int)((hidElems / SLOTCAP / 32) * 32);
    if (PsR > F2f) PsR = F2f;
    if (PsR < 32) PsR = 32;
    for (int off = 0; off < F2f; off += PsR) {
      int Np = F2f - off < PsR ? F2f - off : PsR;
      dim3 g1(MAXTILE, (Np + 63) / 64);
      moe1_k<float, 1><<<g1, 256, 0, stream>>>(xdet, hte, hts, hstok, xfb, (const float*)rw1, (const float*)rw3, hid, PsR, off, Np);
      moe1_k<bf16, 0><<<g1, 256, 0, stream>>>(xdet, hte, hts, hstok, xfb, (const bf16*)rw1, (const bf16*)rw3, hid, PsR, off, Np);
      dim3 g2(MAXTILE, 8);
      moe2_k<float, 1><<<g2, 256, 0, stream>>>(xdet, hte, hts, hstok, hsw, hid, PsR, off, Np, (const float*)rw2, acc);
      moe2_k<bf16, 0><<<g2, 256, 0, stream>>>(xdet, hte, hts, hstok, hsw, hid, PsR, off, Np, (const bf16*)rw2, acc);
    }
  }

  const float* accP = accUsed ? acc : nullptr;
  const float* eoRtP = gather ? eoRt : nullptr;
  final_k<float, float, 1><<<Tt, 256, 0, stream>>>(xdet, x2, (const float*)ln2w, (const float*)ln2b, accP, eoSh, eoRtP, hslot, (float*)d_out);
  final_k<bf16, bf16, 0><<<Tt, 256, 0, stream>>>(xdet, x2, (const bf16*)ln2w, (const bf16*)ln2b, accP, eoSh, eoRtP, hslot, (bf16*)d_out);
  loss_k<float, 1><<<1, 64, 0, stream>>>(xdet, hcnt, (float*)d_out);
  loss_k<bf16, 0><<<1, 64, 0, stream>>>(xdet, hcnt, (bf16*)d_out);
}

// Round 3
// 895.887 us; speedup vs baseline: 1.3340x; 1.1154x over previous
//
#include <hip/hip_runtime.h>
#include <cmath>
#include <cstdint>

// ---------------------------------------------------------------------------
// TransformerEncoderLayer (attention + MoE) on MI355X, fp32 acc.
// Round 11:
//  (a) gemmT/moeT1/moeT2 staging switched from reg-prefetch+ds_write to
//      __builtin_amdgcn_global_load_lds (width 16) into linear [rows][32]
//      LDS tiles (64B rows -> fragment reads at the 8-cycle b128 minimum,
//      no padding/swizzle needed). Kills ds_writes + address VALU.
//  (b) attention projections leave the legacy scalar-staging gemm_k:
//      atconv_k transposes q/k/v/bw + aw1/scw1 + out_w to n-major bf16 and
//      packs biases fp32; then ONE fused gemmT (N=2048, per-col silu/sigm,
//      head-major out) + one for aw1|scw1 + one for out_w (bias+resid,
//      resid = fp32 x copy written by the ln1 pass).
// Tiered on ws_size with graceful fallback to the legacy paths.
// ---------------------------------------------------------------------------

typedef __bf16 bf16;
typedef __bf16 bf16x8 __attribute__((ext_vector_type(8)));
typedef __bf16 bf16x4 __attribute__((ext_vector_type(4)));
typedef float  f32x4  __attribute__((ext_vector_type(4)));

static constexpr int Bb = 2, Ss = 1024, Dd = 512, NHh = 8, HDd = 64;
static constexpr int Tt = Bb * Ss;           // 2048 tokens
static constexpr int NSs = 8, F3f = 1536;
static constexpr int Ee = 32, F2f = 1024;
static constexpr int SLOTCAP = 10240;        // 8192 + worst-case pad (10208)
static constexpr int MAXTILE = 160;

// ---------------- helpers ----------------
__device__ inline float wavesum(float v) {
#pragma unroll
  for (int i = 1; i < 64; i <<= 1) v += __shfl_xor(v, i, 64);
  return v;
}
__device__ inline float blocksum(float v, float* sm) {
  v = wavesum(v);
  int wv = threadIdx.x >> 6;
  __syncthreads();
  if ((threadIdx.x & 63) == 0) sm[wv] = v;
  __syncthreads();
  return (sm[0] + sm[1]) + (sm[2] + sm[3]);
}
__device__ inline float silu_f(float x) { return x / (1.f + expf(-x)); }
__device__ inline float sigm_f(float x) { return 1.f / (1.f + expf(-x)); }

// async global->LDS, 16B per lane; lds base must be wave-uniform.
__device__ inline void gl16(const void* g, void* l) {
  __builtin_amdgcn_global_load_lds(
      (const __attribute__((address_space(1))) void*)g,
      (__attribute__((address_space(3))) void*)l, 16, 0, 0);
}

// Inline dtype classifier on d_in[0] (x ~ N(0,1)); 1 = fp32 buffer.
__device__ inline int is_f32(const unsigned short* __restrict__ xr) {
  int good = 0;
#pragma unroll
  for (int i = 0; i < 32; ++i) {
    unsigned e = (xr[2 * i] >> 7) & 0xFF;
    good += (e >= 110 && e <= 140);
  }
  return good < 16;
}

// ---------------------------------------------------------------------------
// Flexible MFMA GEMM (legacy path, kept for small-K projections + fallback).
// ---------------------------------------------------------------------------
template <typename TB, int WANT, int ACT, int DUAL, int OUTBF, int ACCUM,
          int RESID, int ASCALE>
__global__ __launch_bounds__(256) void gemm_k(
    const unsigned short* __restrict__ xdet,
    const bf16* __restrict__ A, long aBatch, int lda,
    const TB* __restrict__ ascale, long asBatch,
    const TB* __restrict__ B0, const TB* __restrict__ B1, long bBatch, int bK,
    const TB* __restrict__ bias, int biasBatch,
    void* __restrict__ Cv, long cBatch, int ldc,
    const TB* __restrict__ resid, int resLd,
    int N, int K, float scale) {
  if (is_f32(xdet) != WANT) return;
  __shared__ __align__(16) bf16 sA[64 * 40];
  __shared__ __align__(16) bf16 sB0[64 * 40];
  __shared__ __align__(16) bf16 sB1[64 * 40];

  const int tid = threadIdx.x;
  const int wave = tid >> 6, lane = tid & 63;
  const int fm = lane & 15, quad = lane >> 4;
  const int bm = blockIdx.x, bn = blockIdx.y, z = blockIdx.z;

  const bf16* Az = A + (long)z * aBatch;
  const TB* B0z = B0 + (long)z * bBatch;
  const TB* B1z = DUAL ? (B1 + (long)z * bBatch) : nullptr;
  const TB* asz = ASCALE ? (ascale + (long)z * asBatch) : nullptr;

  f32x4 acc0[4], acc1[4];
  const f32x4 vzero = {0.f, 0.f, 0.f, 0.f};
#pragma unroll
  for (int i = 0; i < 4; ++i) { acc0[i] = vzero; acc1[i] = vzero; }

  const int arow = tid >> 2, ak0 = (tid & 3) * 8;
  const int gn = bn * 64 + lane;
  const int wch = wave * 8;

  for (int kb = 0; kb < K; kb += 32) {
    bf16x8 av = *(const bf16x8*)(Az + (long)(bm * 64 + arow) * lda + kb + ak0);
    if (ASCALE) {
#pragma unroll
      for (int j = 0; j < 8; ++j)
        av[j] = (bf16)((float)av[j] * (float)asz[kb + ak0 + j]);
    }
    *(bf16x8*)(sA + arow * 40 + ak0) = av;
    bf16x8 bv, cv;
    if (gn < N) {
      const TB* bp = B0z + (long)(kb + wch) * bK + gn;
#pragma unroll
      for (int j = 0; j < 8; ++j) bv[j] = (bf16)(float)bp[(long)j * bK];
      if (DUAL) {
        const TB* cp = B1z + (long)(kb + wch) * bK + gn;
#pragma unroll
        for (int j = 0; j < 8; ++j) cv[j] = (bf16)(float)cp[(long)j * bK];
      }
    } else {
#pragma unroll
      for (int j = 0; j < 8; ++j) { bv[j] = (bf16)0.f; if (DUAL) cv[j] = (bf16)0.f; }
    }
    *(bf16x8*)(sB0 + lane * 40 + wch) = bv;
    if (DUAL) *(bf16x8*)(sB1 + lane * 40 + wch) = cv;
    __syncthreads();
    bf16x8 af = *(const bf16x8*)(sA + (wave * 16 + fm) * 40 + quad * 8);
#pragma unroll
    for (int nt = 0; nt < 4; ++nt) {
      bf16x8 bfr = *(const bf16x8*)(sB0 + (nt * 16 + fm) * 40 + quad * 8);
      acc0[nt] = __builtin_amdgcn_mfma_f32_16x16x32_bf16(af, bfr, acc0[nt], 0, 0, 0);
      if (DUAL) {
        bf16x8 bg = *(const bf16x8*)(sB1 + (nt * 16 + fm) * 40 + quad * 8);
        acc1[nt] = __builtin_amdgcn_mfma_f32_16x16x32_bf16(af, bg, acc1[nt], 0, 0, 0);
      }
    }
    __syncthreads();
  }

#pragma unroll
  for (int nt = 0; nt < 4; ++nt) {
    int gcol = bn * 64 + nt * 16 + fm;
    if (gcol >= N) continue;
#pragma unroll
    for (int r = 0; r < 4; ++r) {
      int grow = bm * 64 + wave * 16 + quad * 4 + r;
      float v;
      if (DUAL) {
        v = silu_f(acc0[nt][r]) * acc1[nt][r];
      } else {
        v = acc0[nt][r] * scale;
        if (bias) v += (float)bias[z * biasBatch + gcol];
        if (ACT == 1) v = silu_f(v);
        else if (ACT == 2) v = sigm_f(v);
      }
      if (RESID) v += (float)resid[(long)grow * resLd + gcol];
      long ci = (long)z * cBatch + (long)grow * ldc + gcol;
      if (ACCUM) atomicAdd((float*)Cv + ci, v);
      else if (OUTBF) ((bf16*)Cv)[ci] = (bf16)v;
      else ((float*)Cv)[ci] = v;
    }
  }
}

// ---------------------------------------------------------------------------
// MoE weight transpose+convert: W [K][N] -> Wt [N][K] bf16, optional per-k
// scale fold. 64x64 LDS tile transpose.
// ---------------------------------------------------------------------------
template <typename TI, int WANT, int SCALE>
__global__ __launch_bounds__(256) void tconv_k(
    const unsigned short* __restrict__ xdet,
    const TI* __restrict__ W, long wBatch,
    const TI* __restrict__ sc, long sBatch,
    bf16* __restrict__ Wt, long oBatch, int K, int N) {
  if (is_f32(xdet) != WANT) return;
  __shared__ float sT[64][65];
  const int tid = threadIdx.x;
  const int k0 = blockIdx.x * 64, n0 = blockIdx.y * 64, z = blockIdx.z;
  const TI* Wz = W + (long)z * wBatch;
  const int rr = tid >> 4, cc = (tid & 15) * 4;
#pragma unroll
  for (int it = 0; it < 4; ++it) {
    int row = it * 16 + rr;
    const TI* p = Wz + (long)(k0 + row) * N + n0 + cc;
    float v0, v1, v2, v3;
    if constexpr (sizeof(TI) == 4) {
      float4 v = *(const float4*)p;
      v0 = v.x; v1 = v.y; v2 = v.z; v3 = v.w;
    } else {
      bf16x4 v = *(const bf16x4*)p;
      v0 = (float)v[0]; v1 = (float)v[1]; v2 = (float)v[2]; v3 = (float)v[3];
    }
    if (SCALE) {
      float s = (float)sc[(long)z * sBatch + k0 + row];
      v0 *= s; v1 *= s; v2 *= s; v3 *= s;
    }
    sT[row][cc + 0] = v0; sT[row][cc + 1] = v1;
    sT[row][cc + 2] = v2; sT[row][cc + 3] = v3;
  }
  __syncthreads();
  bf16* Oz = Wt + (long)z * oBatch;
#pragma unroll
  for (int it = 0; it < 4; ++it) {
    int n = it * 16 + rr;
    bf16x4 ov;
#pragma unroll
    for (int j = 0; j < 4; ++j) ov[j] = (bf16)sT[cc + j][n];
    *(bf16x4*)(Oz + (long)(n0 + n) * K + k0 + cc) = ov;
  }
}

// ---------------------------------------------------------------------------
// Attention weight conversion, one dispatch:
//  blocks 0-255   q/k/v/bw [8,512,64]  -> wqkvbT [2048][512]
//  blocks 256-383 aw1/scw1 [8,512,32]  -> wascT  [512][512]
//  blocks 384-447 outw [512,512]       -> woutT  [512][512]
//  block  448     pack biases -> biasP fp32 [3072]
// ---------------------------------------------------------------------------
template <typename TI, int WANT>
__global__ __launch_bounds__(256) void atconv_k(
    const unsigned short* __restrict__ xdet,
    const TI* __restrict__ qw, const TI* __restrict__ kw,
    const TI* __restrict__ vw, const TI* __restrict__ bw,
    const TI* __restrict__ a1w, const TI* __restrict__ s1w,
    const TI* __restrict__ ow,
    const TI* __restrict__ qb, const TI* __restrict__ kb,
    const TI* __restrict__ vb, const TI* __restrict__ bb,
    const TI* __restrict__ a1b, const TI* __restrict__ s1b,
    const TI* __restrict__ ob,
    bf16* __restrict__ wqkvbT, bf16* __restrict__ wascT,
    bf16* __restrict__ woutT, float* __restrict__ biasP) {
  if (is_f32(xdet) != WANT) return;
  const int tid = threadIdx.x;
  const int b = blockIdx.x;
  if (b == 448) {
    for (int i = tid; i < 3072; i += 256) {
      float v;
      if (i < 512) v = (float)qb[i];
      else if (i < 1024) v = (float)kb[i - 512];
      else if (i < 1536) v = (float)vb[i - 1024];
      else if (i < 2048) v = (float)bb[i - 1536];
      else if (i < 2304) v = (float)a1b[i - 2048];
      else if (i < 2560) v = (float)s1b[i - 2304];
      else v = (float)ob[i - 2560];
      biasP[i] = v;
    }
    return;
  }
  __shared__ float sT[64][65];
  const TI* W; bf16* O; int ldw, N, k0, n0;
  if (b < 256) {
    int t = b >> 6, i = b & 63, h = i >> 3;
    k0 = (i & 7) * 64; n0 = 0; ldw = 64; N = 64;
    const TI* s = t == 0 ? qw : t == 1 ? kw : t == 2 ? vw : bw;
    W = s + (long)h * 512 * 64;
    O = wqkvbT + ((long)t * 512 + h * 64) * 512;
  } else if (b < 384) {
    int t = (b - 256) >> 6, i = (b - 256) & 63, h = i >> 3;
    k0 = (i & 7) * 64; n0 = 0; ldw = 32; N = 32;
    W = (t == 0 ? a1w : s1w) + (long)h * 512 * 32;
    O = wascT + ((long)t * 256 + h * 32) * 512;
  } else {
    int i = b - 384;
    k0 = (i >> 3) * 64; n0 = (i & 7) * 64; ldw = 512; N = 512;
    W = ow; O = woutT;
  }
  const int rr = tid >> 4, cc = (tid & 15) * 4;
#pragma unroll
  for (int it = 0; it < 4; ++it) {
    int row = it * 16 + rr;
    float v0 = 0.f, v1 = 0.f, v2 = 0.f, v3 = 0.f;
    if (n0 + cc < N) {
      const TI* p = W + (long)(k0 + row) * ldw + n0 + cc;
      v0 = (float)p[0]; v1 = (float)p[1]; v2 = (float)p[2]; v3 = (float)p[3];
    }
    sT[row][cc + 0] = v0; sT[row][cc + 1] = v1;
    sT[row][cc + 2] = v2; sT[row][cc + 3] = v3;
  }
  __syncthreads();
#pragma unroll
  for (int it = 0; it < 4; ++it) {
    int n = it * 16 + rr;
    if (n0 + n < N) {
      bf16x4 ov;
#pragma unroll
      for (int j = 0; j < 4; ++j) ov[j] = (bf16)sT[cc + j][n];
      *(bf16x4*)(O + (long)(n0 + n) * 512 + k0 + cc) = ov;
    }
  }
}

// ---------------------------------------------------------------------------
// Dense GEMM on n-major bf16 B. BM=128, BN=64, BK=32, 4 waves over M.
// Staging via global_load_lds into linear [rows][32] tiles.
// CMODE: 0 bf16 store (+bias/ACT); 1 atomicAdd fp32*scale; 2 fp32 store*scale;
//        3 fp32 store + bias + resid.
// ACT (CMODE 0): 0 none, 1 silu, 2 sigm, 3 col<1536?silu:sigm.
// HOUT: 0 normal C index; else head-major: ci=((col>>H)*Tt+row)<<H | col&mask.
// ---------------------------------------------------------------------------
template <int DUAL, int CMODE, int ACT, int HOUT>
__global__ __launch_bounds__(256) void gemmT_k(
    const bf16* __restrict__ A, long aBatch, int lda,
    const bf16* __restrict__ B0t, const bf16* __restrict__ B1t, long bBatch,
    const float* __restrict__ bias,
    void* __restrict__ Cv, long cBatch, int ldc,
    const float* __restrict__ resid,
    int K, float scale) {
  __shared__ __align__(16) bf16 sA[128 * 32];
  __shared__ __align__(16) bf16 sB0[64 * 32];
  __shared__ __align__(16) bf16 sB1[DUAL ? 64 * 32 : 16];
  const int tid = threadIdx.x, wave = tid >> 6, lane = tid & 63;
  const int fm = lane & 15, quad = lane >> 4;
  const bf16* Az = A + (long)blockIdx.z * aBatch + (long)(blockIdx.x * 128) * lda;
  const bf16* B0z = B0t + (long)blockIdx.z * bBatch + (long)(blockIdx.y * 64) * K;
  const bf16* B1z = DUAL ? (B1t + (long)blockIdx.z * bBatch + (long)(blockIdx.y * 64) * K) : nullptr;
  const int srow = lane >> 2, scol = (lane & 3) * 8;
  const bf16* gA0 = Az + (long)(wave * 32 + srow) * lda + scol;
  const bf16* gA1 = Az + (long)(wave * 32 + 16 + srow) * lda + scol;
  const bf16* gB0 = B0z + (long)(wave * 16 + srow) * K + scol;
  const bf16* gB1 = DUAL ? (B1z + (long)(wave * 16 + srow) * K + scol) : nullptr;
  bf16* lA0 = sA + (wave * 32) * 32;
  bf16* lA1 = sA + (wave * 32 + 16) * 32;
  bf16* lB0 = sB0 + (wave * 16) * 32;
  bf16* lB1 = DUAL ? (sB1 + (wave * 16) * 32) : nullptr;
  f32x4 acc0[2][4], acc1[2][4];
  const f32x4 vz = {0.f, 0.f, 0.f, 0.f};
#pragma unroll
  for (int m = 0; m < 2; ++m)
#pragma unroll
    for (int n = 0; n < 4; ++n) { acc0[m][n] = vz; acc1[m][n] = vz; }
  for (int kb = 0; kb < K; kb += 32) {
    gl16(gA0 + kb, lA0);
    gl16(gA1 + kb, lA1);
    gl16(gB0 + kb, lB0);
    if (DUAL) gl16(gB1 + kb, lB1);
    __syncthreads();
    bf16x8 af0 = *(const bf16x8*)(sA + (wave * 32 + fm) * 32 + quad * 8);
    bf16x8 af1 = *(const bf16x8*)(sA + (wave * 32 + 16 + fm) * 32 + quad * 8);
#pragma unroll
    for (int nt = 0; nt < 4; ++nt) {
      bf16x8 b0 = *(const bf16x8*)(sB0 + (nt * 16 + fm) * 32 + quad * 8);
      acc0[0][nt] = __builtin_amdgcn_mfma_f32_16x16x32_bf16(af0, b0, acc0[0][nt], 0, 0, 0);
      acc0[1][nt] = __builtin_amdgcn_mfma_f32_16x16x32_bf16(af1, b0, acc0[1][nt], 0, 0, 0);
      if (DUAL) {
        bf16x8 b1 = *(const bf16x8*)(sB1 + (nt * 16 + fm) * 32 + quad * 8);
        acc1[0][nt] = __builtin_amdgcn_mfma_f32_16x16x32_bf16(af0, b1, acc1[0][nt], 0, 0, 0);
        acc1[1][nt] = __builtin_amdgcn_mfma_f32_16x16x32_bf16(af1, b1, acc1[1][nt], 0, 0, 0);
      }
    }
    __syncthreads();
  }
#pragma unroll
  for (int mt = 0; mt < 2; ++mt)
#pragma unroll
    for (int nt = 0; nt < 4; ++nt) {
      int col = blockIdx.y * 64 + nt * 16 + fm;
#pragma unroll
      for (int r = 0; r < 4; ++r) {
        int row = blockIdx.x * 128 + wave * 32 + mt * 16 + quad * 4 + r;
        long ci;
        if (HOUT)
          ci = (((long)(col >> HOUT) * Tt + row) << HOUT) + (col & ((1 << HOUT) - 1));
        else
          ci = (long)blockIdx.z * cBatch + (long)row * ldc + col;
        if (DUAL) {
          ((bf16*)Cv)[ci] = (bf16)(silu_f(acc0[mt][nt][r]) * acc1[mt][nt][r]);
        } else {
          float v = acc0[mt][nt][r] * scale;
          if (bias) v += bias[col];
          if (ACT == 1) v = silu_f(v);
          else if (ACT == 2) v = sigm_f(v);
          else if (ACT == 3) v = (col < 1536) ? silu_f(v) : sigm_f(v);
          if (CMODE == 1) atomicAdd((float*)Cv + ci, v);
          else if (CMODE == 2) ((float*)Cv)[ci] = v;
          else if (CMODE == 3) ((float*)Cv)[ci] = v + resid[(long)row * ldc + col];
          else ((bf16*)Cv)[ci] = (bf16)v;
        }
      }
    }
}

// ---------------------------------------------------------------------------
// Routed expert stage 1: gathered dual-SwiGLU, global_load_lds staging.
// BM=64 (slots), BN=128, waves 2x2.
// ---------------------------------------------------------------------------
__global__ __launch_bounds__(256) void moeT1_k(
    const int* __restrict__ tileExp, const int* __restrict__ tileStart,
    const int* __restrict__ slotTok, const bf16* __restrict__ xfb,
    const bf16* __restrict__ W1t, const bf16* __restrict__ W3t,
    bf16* __restrict__ hid) {
  int e = tileExp[blockIdx.x];
  if (e < 0) return;
  int slot0 = tileStart[blockIdx.x];
  __shared__ int sTok[64];
  __shared__ __align__(16) bf16 sA[64 * 32];
  __shared__ __align__(16) bf16 sB0[128 * 32];
  __shared__ __align__(16) bf16 sB1[128 * 32];
  const int tid = threadIdx.x, wave = tid >> 6, lane = tid & 63;
  const int fm = lane & 15, quad = lane >> 4;
  const int wr = wave >> 1, wc = wave & 1;
  if (tid < 64) sTok[tid] = slotTok[slot0 + tid];
  __syncthreads();
  const int srow = lane >> 2, scol = (lane & 3) * 8;
  const int myTok = sTok[wave * 16 + srow];
  const bf16* gA = xfb + (long)myTok * 512 + scol;
  const bf16* B0 = W1t + (long)e * (F2f * 512) + (long)(blockIdx.y * 128) * 512;
  const bf16* B1 = W3t + (long)e * (F2f * 512) + (long)(blockIdx.y * 128) * 512;
  const bf16* gB00 = B0 + (long)(wave * 32 + srow) * 512 + scol;
  const bf16* gB01 = B0 + (long)(wave * 32 + 16 + srow) * 512 + scol;
  const bf16* gB10 = B1 + (long)(wave * 32 + srow) * 512 + scol;
  const bf16* gB11 = B1 + (long)(wave * 32 + 16 + srow) * 512 + scol;
  bf16* lA = sA + (wave * 16) * 32;
  bf16* lB00 = sB0 + (wave * 32) * 32;
  bf16* lB01 = sB0 + (wave * 32 + 16) * 32;
  bf16* lB10 = sB1 + (wave * 32) * 32;
  bf16* lB11 = sB1 + (wave * 32 + 16) * 32;
  f32x4 acc0[2][4], acc1[2][4];
  const f32x4 vz = {0.f, 0.f, 0.f, 0.f};
#pragma unroll
  for (int m = 0; m < 2; ++m)
#pragma unroll
    for (int n = 0; n < 4; ++n) { acc0[m][n] = vz; acc1[m][n] = vz; }
  for (int kb = 0; kb < 512; kb += 32) {
    gl16(gA + kb, lA);
    gl16(gB00 + kb, lB00);
    gl16(gB01 + kb, lB01);
    gl16(gB10 + kb, lB10);
    gl16(gB11 + kb, lB11);
    __syncthreads();
    bf16x8 af0 = *(const bf16x8*)(sA + (wr * 32 + fm) * 32 + quad * 8);
    bf16x8 af1 = *(const bf16x8*)(sA + (wr * 32 + 16 + fm) * 32 + quad * 8);
#pragma unroll
    for (int nt = 0; nt < 4; ++nt) {
      bf16x8 b0 = *(const bf16x8*)(sB0 + (wc * 64 + nt * 16 + fm) * 32 + quad * 8);
      acc0[0][nt] = __builtin_amdgcn_mfma_f32_16x16x32_bf16(af0, b0, acc0[0][nt], 0, 0, 0);
      acc0[1][nt] = __builtin_amdgcn_mfma_f32_16x16x32_bf16(af1, b0, acc0[1][nt], 0, 0, 0);
      bf16x8 b1 = *(const bf16x8*)(sB1 + (wc * 64 + nt * 16 + fm) * 32 + quad * 8);
      acc1[0][nt] = __builtin_amdgcn_mfma_f32_16x16x32_bf16(af0, b1, acc1[0][nt], 0, 0, 0);
      acc1[1][nt] = __builtin_amdgcn_mfma_f32_16x16x32_bf16(af1, b1, acc1[1][nt], 0, 0, 0);
    }
    __syncthreads();
  }
#pragma unroll
  for (int mt = 0; mt < 2; ++mt)
#pragma unroll
    for (int nt = 0; nt < 4; ++nt) {
      int col = blockIdx.y * 128 + wc * 64 + nt * 16 + fm;
#pragma unroll
      for (int r = 0; r < 4; ++r) {
        int row = wr * 32 + mt * 16 + quad * 4 + r;
        hid[(long)(slot0 + row) * F2f + col] =
            (bf16)(silu_f(acc0[mt][nt][r]) * acc1[mt][nt][r]);
      }
    }
}

// ---------------------------------------------------------------------------
// Routed expert stage 2: hid @ W2t, global_load_lds staging.
// GATHER=1: plain store w*out -> eoRt; else atomicAdd acc.
// ---------------------------------------------------------------------------
template <int GATHER>
__global__ __launch_bounds__(256) void moeT2_k(
    const int* __restrict__ tileExp, const int* __restrict__ tileStart,
    const int* __restrict__ slotTok, const float* __restrict__ slotW,
    const bf16* __restrict__ hid, const bf16* __restrict__ W2t,
    float* __restrict__ acc, float* __restrict__ eoRt) {
  int e = tileExp[blockIdx.x];
  if (e < 0) return;
  int slot0 = tileStart[blockIdx.x];
  __shared__ int sTok[64];
  __shared__ float sW[64];
  __shared__ __align__(16) bf16 sA[64 * 32];
  __shared__ __align__(16) bf16 sB[128 * 32];
  const int tid = threadIdx.x, wave = tid >> 6, lane = tid & 63;
  const int fm = lane & 15, quad = lane >> 4;
  const int wr = wave >> 1, wc = wave & 1;
  if (tid < 64) { sTok[tid] = slotTok[slot0 + tid]; sW[tid] = slotW[slot0 + tid]; }
  const int srow = lane >> 2, scol = (lane & 3) * 8;
  const bf16* gA = hid + (long)(slot0 + wave * 16 + srow) * F2f + scol;
  const bf16* B = W2t + (long)e * (512 * F2f) + (long)(blockIdx.y * 128) * F2f;
  const bf16* gB0 = B + (long)(wave * 32 + srow) * F2f + scol;
  const bf16* gB1 = B + (long)(wave * 32 + 16 + srow) * F2f + scol;
  bf16* lA = sA + (wave * 16) * 32;
  bf16* lB0 = sB + (wave * 32) * 32;
  bf16* lB1 = sB + (wave * 32 + 16) * 32;
  f32x4 acc0[2][4];
  const f32x4 vz = {0.f, 0.f, 0.f, 0.f};
#pragma unroll
  for (int m = 0; m < 2; ++m)
#pragma unroll
    for (int n = 0; n < 4; ++n) acc0[m][n] = vz;
  for (int kb = 0; kb < F2f; kb += 32) {
    gl16(gA + kb, lA);
    gl16(gB0 + kb, lB0);
    gl16(gB1 + kb, lB1);
    __syncthreads();
    bf16x8 af0 = *(const bf16x8*)(sA + (wr * 32 + fm) * 32 + quad * 8);
    bf16x8 af1 = *(const bf16x8*)(sA + (wr * 32 + 16 + fm) * 32 + quad * 8);
#pragma unroll
    for (int nt = 0; nt < 4; ++nt) {
      bf16x8 b0 = *(const bf16x8*)(sB + (wc * 64 + nt * 16 + fm) * 32 + quad * 8);
      acc0[0][nt] = __builtin_amdgcn_mfma_f32_16x16x32_bf16(af0, b0, acc0[0][nt], 0, 0, 0);
      acc0[1][nt] = __builtin_amdgcn_mfma_f32_16x16x32_bf16(af1, b0, acc0[1][nt], 0, 0, 0);
    }
    __syncthreads();
  }
#pragma unroll
  for (int mt = 0; mt < 2; ++mt)
#pragma unroll
    for (int nt = 0; nt < 4; ++nt) {
      int col = blockIdx.y * 128 + wc * 64 + nt * 16 + fm;
#pragma unroll
      for (int r = 0; r < 4; ++r) {
        int row = wr * 32 + mt * 16 + quad * 4 + r;
        if (GATHER) {
          eoRt[(long)(slot0 + row) * 512 + col] = acc0[mt][nt][r] * sW[row];
        } else {
          atomicAdd(acc + (long)sTok[row] * 512 + col, acc0[mt][nt][r] * sW[row]);
        }
      }
    }
}

// ---------------------------------------------------------------------------
// Sparse routed expert stage 1 (legacy fallback path).
// ---------------------------------------------------------------------------
template <typename TB, int WANT>
__global__ __launch_bounds__(256) void moe1_k(
    const unsigned short* __restrict__ xdet,
    const int* __restrict__ tileExp, const int* __restrict__ tileStart,
    const int* __restrict__ slotTok,
    const bf16* __restrict__ xfb,
    const TB* __restrict__ W1, const TB* __restrict__ W3,
    bf16* __restrict__ hid, int Ps, int colOff, int Np) {
  if (is_f32(xdet) != WANT) return;
  int e = tileExp[blockIdx.x];
  if (e < 0) return;
  int slot0 = tileStart[blockIdx.x];
  __shared__ int sTok[64];
  __shared__ __align__(16) bf16 sA[64 * 40];
  __shared__ __align__(16) bf16 sB0[64 * 40];
  __shared__ __align__(16) bf16 sB1[64 * 40];
  const int tid = threadIdx.x;
  const int wave = tid >> 6, lane = tid & 63;
  const int fm = lane & 15, quad = lane >> 4;
  if (tid < 64) sTok[tid] = slotTok[slot0 + tid];
  __syncthreads();
  const TB* B0 = W1 + (long)e * 512 * F2f + colOff;
  const TB* B1 = W3 + (long)e * 512 * F2f + colOff;
  const int bn = blockIdx.y;
  f32x4 acc0[4], acc1[4];
  const f32x4 vz = {0.f, 0.f, 0.f, 0.f};
#pragma unroll
  for (int i = 0; i < 4; ++i) { acc0[i] = vz; acc1[i] = vz; }
  const int arow = tid >> 2, ak0 = (tid & 3) * 8;
  const int gn = bn * 64 + lane;
  const int wch = wave * 8;
  for (int kb = 0; kb < 512; kb += 32) {
    int tok = sTok[arow];
    *(bf16x8*)(sA + arow * 40 + ak0) =
        *(const bf16x8*)(xfb + (long)tok * 512 + kb + ak0);
    bf16x8 bv, cv;
    if (gn < Np) {
      const TB* bp = B0 + (long)(kb + wch) * F2f + gn;
      const TB* cp = B1 + (long)(kb + wch) * F2f + gn;
#pragma unroll
      for (int j = 0; j < 8; ++j) {
        bv[j] = (bf16)(float)bp[(long)j * F2f];
        cv[j] = (bf16)(float)cp[(long)j * F2f];
      }
    } else {
#pragma unroll
      for (int j = 0; j < 8; ++j) { bv[j] = (bf16)0.f; cv[j] = (bf16)0.f; }
    }
    *(bf16x8*)(sB0 + lane * 40 + wch) = bv;
    *(bf16x8*)(sB1 + lane * 40 + wch) = cv;
    __syncthreads();
    bf16x8 af = *(const bf16x8*)(sA + (wave * 16 + fm) * 40 + quad * 8);
#pragma unroll
    for (int nt = 0; nt < 4; ++nt) {
      bf16x8 bfr = *(const bf16x8*)(sB0 + (nt * 16 + fm) * 40 + quad * 8);
      acc0[nt] = __builtin_amdgcn_mfma_f32_16x16x32_bf16(af, bfr, acc0[nt], 0, 0, 0);
      bf16x8 bg = *(const bf16x8*)(sB1 + (nt * 16 + fm) * 40 + quad * 8);
      acc1[nt] = __builtin_amdgcn_mfma_f32_16x16x32_bf16(af, bg, acc1[nt], 0, 0, 0);
    }
    __syncthreads();
  }
#pragma unroll
  for (int nt = 0; nt < 4; ++nt) {
    int gcol = bn * 64 + nt * 16 + fm;
    if (gcol >= Np) continue;
#pragma unroll
    for (int r = 0; r < 4; ++r) {
      int row = wave * 16 + quad * 4 + r;
      hid[(long)(slot0 + row) * Ps + gcol] =
          (bf16)(silu_f(acc0[nt][r]) * acc1[nt][r]);
    }
  }
}

// ---------------------------------------------------------------------------
// Sparse routed expert stage 2 (legacy fallback path).
// ---------------------------------------------------------------------------
template <typename TB, int WANT>
__global__ __launch_bounds__(256) void moe2_k(
    const unsigned short* __restrict__ xdet,
    const int* __restrict__ tileExp, const int* __restrict__ tileStart,
    const int* __restrict__ slotTok, const float* __restrict__ slotW,
    const bf16* __restrict__ hid, int Ps, int colOff, int Kp,
    const TB* __restrict__ W2, float* __restrict__ acc) {
  if (is_f32(xdet) != WANT) return;
  int e = tileExp[blockIdx.x];
  if (e < 0) return;
  int slot0 = tileStart[blockIdx.x];
  __shared__ int sTok[64];
  __shared__ float sW[64];
  __shared__ __align__(16) bf16 sA[64 * 40];
  __shared__ __align__(16) bf16 sB0[64 * 40];
  const int tid = threadIdx.x;
  const int wave = tid >> 6, lane = tid & 63;
  const int fm = lane & 15, quad = lane >> 4;
  if (tid < 64) { sTok[tid] = slotTok[slot0 + tid]; sW[tid] = slotW[slot0 + tid]; }
  __syncthreads();
  const TB* B0 = W2 + (long)e * F2f * 512 + (long)colOff * 512;
  const int bn = blockIdx.y;
  f32x4 acc0[4];
  const f32x4 vz = {0.f, 0.f, 0.f, 0.f};
#pragma unroll
  for (int i = 0; i < 4; ++i) acc0[i] = vz;
  const int arow = tid >> 2, ak0 = (tid & 3) * 8;
  const int gn = bn * 64 + lane;
  const int wch = wave * 8;
  for (int kb = 0; kb < Kp; kb += 32) {
    *(bf16x8*)(sA + arow * 40 + ak0) =
        *(const bf16x8*)(hid + (long)(slot0 + arow) * Ps + kb + ak0);
    const TB* bp = B0 + (long)(kb + wch) * 512 + gn;
    bf16x8 bv;
#pragma unroll
    for (int j = 0; j < 8; ++j) bv[j] = (bf16)(float)bp[(long)j * 512];
    *(bf16x8*)(sB0 + lane * 40 + wch) = bv;
    __syncthreads();
    bf16x8 af = *(const bf16x8*)(sA + (wave * 16 + fm) * 40 + quad * 8);
#pragma unroll
    for (int nt = 0; nt < 4; ++nt) {
      bf16x8 bfr = *(const bf16x8*)(sB0 + (nt * 16 + fm) * 40 + quad * 8);
      acc0[nt] = __builtin_amdgcn_mfma_f32_16x16x32_bf16(af, bfr, acc0[nt], 0, 0, 0);
    }
    __syncthreads();
  }
#pragma unroll
  for (int nt = 0; nt < 4; ++nt) {
    int gcol = bn * 64 + nt * 16 + fm;
#pragma unroll
    for (int r = 0; r < 4; ++r) {
      int row = wave * 16 + quad * 4 + r;
      int t = sTok[row];
      float w = sW[row];
      atomicAdd(acc + (long)t * 512 + gcol, acc0[nt][r] * w);
    }
  }
}

// ---------------------------------------------------------------------------
// Fused flash attention. V staged k-major (conflict-free b128 writes).
// ---------------------------------------------------------------------------
__global__ __launch_bounds__(256) void attn_k(const bf16* __restrict__ Q,
                                              const bf16* __restrict__ K,
                                              const bf16* __restrict__ V,
                                              bf16* __restrict__ O) {
  __shared__ __align__(16) bf16 sK[64 * 72];
  __shared__ __align__(16) bf16 sVt[64 * 72];
  __shared__ __align__(16) bf16 sP[4 * 16 * 72];
  const int tid = threadIdx.x, wave = tid >> 6, lane = tid & 63;
  const int fm = lane & 15, quad = lane >> 4;
  const long base = (long)blockIdx.y * Ss * 64;
  const int qrow0 = blockIdx.x * 64 + wave * 16;

  bf16x8 qf[2];
#pragma unroll
  for (int c = 0; c < 2; ++c)
    qf[c] = *(const bf16x8*)(Q + base + (long)(qrow0 + fm) * 64 + c * 32 + quad * 8);

  f32x4 oacc[4];
  const f32x4 vz = {0.f, 0.f, 0.f, 0.f};
#pragma unroll
  for (int i = 0; i < 4; ++i) oacc[i] = vz;
  float m_run[4], l_run[4];
#pragma unroll
  for (int r = 0; r < 4; ++r) { m_run[r] = -1e30f; l_run[r] = 0.f; }

  const int skey = tid >> 2, sd0 = (tid & 3) * 16;
  bf16* sPw = sP + wave * 16 * 72;

  for (int kt = 0; kt < 16; ++kt) {
    __syncthreads();
    const bf16* Kt = K + base + (long)(kt * 64) * 64;
    *(bf16x8*)(sK + skey * 72 + sd0)     = *(const bf16x8*)(Kt + (long)skey * 64 + sd0);
    *(bf16x8*)(sK + skey * 72 + sd0 + 8) = *(const bf16x8*)(Kt + (long)skey * 64 + sd0 + 8);
    const bf16* Vt = V + base + (long)(kt * 64) * 64;
    {
      bf16x8 v0, v1;
#pragma unroll
      for (int j = 0; j < 8; ++j) v0[j] = Vt[(long)(wave * 16 + j) * 64 + lane];
#pragma unroll
      for (int j = 0; j < 8; ++j) v1[j] = Vt[(long)(wave * 16 + 8 + j) * 64 + lane];
      *(bf16x8*)(sVt + lane * 72 + wave * 16) = v0;
      *(bf16x8*)(sVt + lane * 72 + wave * 16 + 8) = v1;
    }
    __syncthreads();
    f32x4 sacc[4];
#pragma unroll
    for (int nt = 0; nt < 4; ++nt) sacc[nt] = vz;
#pragma unroll
    for (int c = 0; c < 2; ++c) {
#pragma unroll
      for (int nt = 0; nt < 4; ++nt) {
        bf16x8 kf = *(const bf16x8*)(sK + (nt * 16 + fm) * 72 + c * 32 + quad * 8);
        sacc[nt] = __builtin_amdgcn_mfma_f32_16x16x32_bf16(qf[c], kf, sacc[nt], 0, 0, 0);
      }
    }
#pragma unroll
    for (int nt = 0; nt < 4; ++nt)
#pragma unroll
      for (int r = 0; r < 4; ++r) sacc[nt][r] *= 0.125f;
    float mt[4];
#pragma unroll
    for (int r = 0; r < 4; ++r) {
      float mx = -1e30f;
#pragma unroll
      for (int nt = 0; nt < 4; ++nt) mx = fmaxf(mx, sacc[nt][r]);
      mt[r] = mx;
    }
#pragma unroll
    for (int i = 1; i < 16; i <<= 1) {
#pragma unroll
      for (int r = 0; r < 4; ++r) mt[r] = fmaxf(mt[r], __shfl_xor(mt[r], i, 64));
    }
    float p[4][4], al[4], rs[4];
#pragma unroll
    for (int r = 0; r < 4; ++r) {
      float m_new = fmaxf(m_run[r], mt[r]);
      al[r] = expf(m_run[r] - m_new);
      m_run[r] = m_new;
      float s = 0.f;
#pragma unroll
      for (int nt = 0; nt < 4; ++nt) {
        float e = expf(sacc[nt][r] - m_new);
        p[nt][r] = e; s += e;
      }
      rs[r] = s;
    }
#pragma unroll
    for (int i = 1; i < 16; i <<= 1) {
#pragma unroll
      for (int r = 0; r < 4; ++r) rs[r] += __shfl_xor(rs[r], i, 64);
    }
#pragma unroll
    for (int r = 0; r < 4; ++r) l_run[r] = l_run[r] * al[r] + rs[r];
#pragma unroll
    for (int nt = 0; nt < 4; ++nt)
#pragma unroll
      for (int r = 0; r < 4; ++r) oacc[nt][r] *= al[r];
#pragma unroll
    for (int nt = 0; nt < 4; ++nt)
#pragma unroll
      for (int r = 0; r < 4; ++r)
        sPw[(quad * 4 + r) * 72 + nt * 16 + fm] = (bf16)p[nt][r];
    __syncthreads();
#pragma unroll
    for (int c = 0; c < 2; ++c) {
      bf16x8 pa = *(const bf16x8*)(sPw + fm * 72 + c * 32 + quad * 8);
#pragma unroll
      for (int nt = 0; nt < 4; ++nt) {
        bf16x8 vf = *(const bf16x8*)(sVt + (nt * 16 + fm) * 72 + c * 32 + quad * 8);
        oacc[nt] = __builtin_amdgcn_mfma_f32_16x16x32_bf16(pa, vf, oacc[nt], 0, 0, 0);
      }
    }
  }
#pragma unroll
  for (int nt = 0; nt < 4; ++nt) {
    int col = nt * 16 + fm;
#pragma unroll
    for (int r = 0; r < 4; ++r) {
      int row = qrow0 + quad * 4 + r;
      O[base + (long)row * 64 + col] = (bf16)(oacc[nt][r] / l_run[r]);
    }
  }
}

// ---------------- LayerNorm (D=512) -> bf16 (+ optional fp32 x copy) --------
template <typename TX, typename TW, int WANT>
__global__ __launch_bounds__(256) void ln_k(const unsigned short* __restrict__ xdet,
                                            const TX* __restrict__ xi,
                                            const TW* __restrict__ w,
                                            const TW* __restrict__ b,
                                            bf16* __restrict__ obf,
                                            float* __restrict__ xraw, float eps) {
  if (is_f32(xdet) != WANT) return;
  __shared__ float sm[4];
  long base = (long)blockIdx.x * 512;
  int tid = threadIdx.x;
  float x0 = (float)xi[base + tid], x1 = (float)xi[base + 256 + tid];
  if (xraw) { xraw[base + tid] = x0; xraw[base + 256 + tid] = x1; }
  float mean = blocksum(x0 + x1, sm) * (1.f / 512.f);
  float d0 = x0 - mean, d1 = x1 - mean;
  float var = blocksum(d0 * d0 + d1 * d1, sm) * (1.f / 512.f);
  float r = rsqrtf(var + eps);
  obf[base + tid] = (bf16)(d0 * r * (float)w[tid] + (float)b[tid]);
  obf[base + 256 + tid] = (bf16)(d1 * r * (float)w[256 + tid] + (float)b[256 + tid]);
}

// ---------------- RMSNorm (bf16 in, eps 1e-6) -> bf16 -----------------------
__global__ __launch_bounds__(256) void rms_k(const bf16* __restrict__ xi,
                                             bf16* __restrict__ ob) {
  __shared__ float sm[4];
  long base = (long)blockIdx.x * 512;
  int tid = threadIdx.x;
  float x0 = (float)xi[base + tid], x1 = (float)xi[base + 256 + tid];
  float ms = blocksum(x0 * x0 + x1 * x1, sm) * (1.f / 512.f);
  float r = rsqrtf(ms + 1e-6f);
  ob[base + tid] = (bf16)(x0 * r);
  ob[base + 256 + tid] = (bf16)(x1 * r);
}

// ---- q/k l2norm (in place) + v = v*alpha+beta (in place) -------------------
__global__ __launch_bounds__(256) void postproj_k(
    bf16* __restrict__ q, bf16* __restrict__ k, bf16* __restrict__ v,
    const bf16* __restrict__ al, const bf16* __restrict__ be) {
  int wv = threadIdx.x >> 6, lane = threadIdx.x & 63;
  long i = ((long)blockIdx.x * 4 + wv) * 64 + lane;
  float qv = (float)q[i];
  float nq = sqrtf(wavesum(qv * qv));
  q[i] = (bf16)(qv / fmaxf(nq, 1e-12f));
  float kv = (float)k[i];
  float nk = sqrtf(wavesum(kv * kv));
  k[i] = (bf16)(kv / fmaxf(nk, 1e-12f));
  v[i] = (bf16)((float)v[i] * (float)al[i] + (float)be[i]);
}

// ---- o = rms(o)*arms_w*shortcut, in place ----------------------------------
template <typename T, int WANT>
__global__ __launch_bounds__(256) void orms_k(const unsigned short* __restrict__ xdet,
                                              bf16* __restrict__ o,
                                              const T* __restrict__ arms,
                                              const bf16* __restrict__ sc) {
  if (is_f32(xdet) != WANT) return;
  int wv = threadIdx.x >> 6, lane = threadIdx.x & 63;
  long r = (long)blockIdx.x * 4 + wv;
  long i = r * 64 + lane;
  int h = (int)(r >> 11);
  float ov = (float)o[i];
  float ms = wavesum(ov * ov) * (1.f / 64.f);
  float s = rsqrtf(ms + 1e-6f);
  o[i] = (bf16)(ov * s * (float)arms[h * 64 + lane] * (float)sc[i]);
}

// ---------------- router: fp32 LN inside, logits, top-4 ---------------------
template <typename T, int WANT>
__global__ __launch_bounds__(256) void router_k(const unsigned short* __restrict__ xdet,
                                                const float* __restrict__ x2,
                                                const T* __restrict__ lnw,
                                                const T* __restrict__ lnb,
                                                const T* __restrict__ rdw,
                                                const T* __restrict__ ruw,
                                                int* __restrict__ eidx,
                                                float* __restrict__ ew,
                                                int* __restrict__ counts) {
  if (is_f32(xdet) != WANT) return;
  __shared__ float sx[4][512];
  __shared__ float st[4][64];
  __shared__ float sl[4][32];
  int wv = threadIdx.x >> 6, lane = threadIdx.x & 63;
  long t = (long)blockIdx.x * 4 + wv;
  float v[8];
  float s1 = 0.f;
#pragma unroll
  for (int j = 0; j < 8; ++j) { v[j] = x2[t * 512 + lane * 8 + j]; s1 += v[j]; }
  float mean = wavesum(s1) * (1.f / 512.f);
  float s2 = 0.f;
#pragma unroll
  for (int j = 0; j < 8; ++j) { float d = v[j] - mean; s2 += d * d; }
  float rv = rsqrtf(wavesum(s2) * (1.f / 512.f) + 1e-5f);
#pragma unroll
  for (int j = 0; j < 8; ++j)
    sx[wv][lane * 8 + j] = (v[j] - mean) * rv * (float)lnw[lane * 8 + j] + (float)lnb[lane * 8 + j];
  __syncthreads();
  float acc = 0.f;
  for (int d = 0; d < 512; ++d) acc += sx[wv][d] * (float)rdw[d * 64 + lane];
  st[wv][lane] = acc;
  __syncthreads();
  if (lane < 32) {
    float lg = 0.f;
    for (int r = 0; r < 64; ++r) lg += st[wv][r] * (float)ruw[r * 32 + lane];
    sl[wv][lane] = lg;
  }
  __syncthreads();
  if (lane == 0) {
    float vv[32];
#pragma unroll
    for (int e = 0; e < 32; ++e) vv[e] = sl[wv][e];
    int idx[4]; float tv[4];
#pragma unroll
    for (int k = 0; k < 4; ++k) {
      float best = -1e30f; int bi = 0;
      for (int e = 0; e < 32; ++e)
        if (vv[e] > best) { best = vv[e]; bi = e; }
      tv[k] = best; idx[k] = bi; vv[bi] = -1e30f;
    }
    float m = tv[0], s = 0.f, w[4];
#pragma unroll
    for (int k = 0; k < 4; ++k) { w[k] = expf(tv[k] - m); s += w[k]; }
    float inv = 1.f / s;
#pragma unroll
    for (int k = 0; k < 4; ++k) {
      eidx[t * 4 + k] = idx[k];
      ew[t * 4 + k] = w[k] * inv;
      atomicAdd(&counts[idx[k]], 1);
    }
  }
}

// ---------------- binning kernels -------------------------------------------
__global__ void offsets_k(const int* __restrict__ counts, int* __restrict__ segOff,
                          int* __restrict__ tileExp, int* __restrict__ tileStart) {
  if (threadIdx.x != 0) return;
  int off = 0, ti = 0;
  for (int e = 0; e < Ee; ++e) {
    segOff[e] = off;
    int pc = (counts[e] + 63) & ~63;
    for (int i = 0; i < pc / 64; ++i) { tileExp[ti] = e; tileStart[ti] = off + i * 64; ++ti; }
    off += pc;
  }
  for (; ti < 192; ++ti) tileExp[ti] = -1;
}
__global__ void scatter_k(const int* __restrict__ eidx, const float* __restrict__ ew,
                          const int* __restrict__ segOff, int* __restrict__ cursor,
                          int* __restrict__ slotTok, float* __restrict__ slotW,
                          int* __restrict__ slotOf) {
  int t = blockIdx.x * 256 + threadIdx.x;
#pragma unroll
  for (int k = 0; k < 4; ++k) {
    int e = eidx[t * 4 + k];
    int pos = atomicAdd(&cursor[e], 1);
    int s = segOff[e] + pos;
    slotTok[s] = t;
    slotW[s] = ew[t * 4 + k];
    slotOf[t * 4 + k] = s;
  }
}
__global__ void pad_k(const int* __restrict__ counts, const int* __restrict__ segOff,
                      int* __restrict__ slotTok, float* __restrict__ slotW) {
  int e = blockIdx.x;
  int c = counts[e], pc = (c + 63) & ~63;
  for (int i = c + threadIdx.x; i < pc; i += 64) {
    int s = segOff[e] + i;
    slotTok[s] = 0;
    slotW[s] = 0.f;
  }
}

// ---------------- misc ----------------
__global__ void zero_k(float* __restrict__ p, long n) {
  long i = (long)blockIdx.x * blockDim.x + threadIdx.x;
  long st = (long)gridDim.x * blockDim.x;
  for (; i < n; i += st) p[i] = 0.f;
}
template <typename TW, typename TO, int WANT>
__global__ __launch_bounds__(256) void final_k(const unsigned short* __restrict__ xdet,
                                               const float* __restrict__ x2,
                                               const TW* __restrict__ lnw,
                                               const TW* __restrict__ lnb,
                                               const float* __restrict__ acc,
                                               const float* __restrict__ eoSh,
                                               const float* __restrict__ eoRt,
                                               const int* __restrict__ slotOf,
                                               TO* __restrict__ out) {
  if (is_f32(xdet) != WANT) return;
  __shared__ float sm[4];
  long base = (long)blockIdx.x * 512;
  int tid = threadIdx.x;
  float x0 = x2[base + tid], x1 = x2[base + 256 + tid];
  float mean = blocksum(x0 + x1, sm) * (1.f / 512.f);
  float d0 = x0 - mean, d1 = x1 - mean;
  float var = blocksum(d0 * d0 + d1 * d1, sm) * (1.f / 512.f);
  float r = rsqrtf(var + 1e-5f);
  float f0 = d0 * r * (float)lnw[tid] + (float)lnb[tid];
  float f1 = d1 * r * (float)lnw[256 + tid] + (float)lnb[256 + tid];
  float a0 = 0.f, a1 = 0.f;
  if (acc) { a0 = acc[base + tid]; a1 = acc[base + 256 + tid]; }
  if (eoSh) {
#pragma unroll
    for (int e2 = 0; e2 < NSs; ++e2) {
      a0 += eoSh[(long)e2 * Tt * 512 + base + tid];
      a1 += eoSh[(long)e2 * Tt * 512 + base + 256 + tid];
    }
  }
  if (eoRt) {
    long t = blockIdx.x;
#pragma unroll
    for (int k2 = 0; k2 < 4; ++k2) {
      long s = slotOf[t * 4 + k2];
      a0 += eoRt[s * 512 + tid];
      a1 += eoRt[s * 512 + 256 + tid];
    }
  }
  out[base + tid] = (TO)(x0 + f0 + a0);
  out[base + 256 + tid] = (TO)(x1 + f1 + a1);
}
template <typename TO, int WANT>
__global__ void loss_k(const unsigned short* __restrict__ xdet,
                       const int* __restrict__ counts, TO* __restrict__ out) {
  if (is_f32(xdet) != WANT) return;
  int lane = threadIdx.x;
  float c = lane < 32 ? (float)counts[lane] : 0.f;
  float mean = wavesum(c) * (1.f / 32.f);
  float d = lane < 32 ? (c - mean) * (c - mean) : 0.f;
  float var = wavesum(d) * (1.f / 31.f);
  if (lane == 0) out[(long)Tt * 512] = (TO)var;
}

// ---------------- host-side dual-dispatch helper for gemm_k -----------------
template <int ACT, int DUAL, int OUTBF, int ACCUM, int RESID, int ASCALE>
static inline void G(dim3 grid, hipStream_t st, const unsigned short* xdet,
                     const bf16* A, long aB, int lda,
                     const void* ascale, long asOff, long asB,
                     const void* B0, long b0Off, const void* B1, long b1Off,
                     long bB, int bK,
                     const void* bias, int biasB,
                     void* C, long cB, int ldc,
                     const void* resid, int resLd,
                     int N, int K, float scale) {
  gemm_k<float, 1, ACT, DUAL, OUTBF, ACCUM, RESID, ASCALE><<<grid, 256, 0, st>>>(
      xdet, A, aB, lda,
      ascale ? (const float*)ascale + asOff : nullptr, asB,
      (const float*)B0 + b0Off, B1 ? (const float*)B1 + b1Off : nullptr, bB, bK,
      bias ? (const float*)bias : nullptr, biasB, C, cB, ldc,
      resid ? (const float*)resid : nullptr, resLd, N, K, scale);
  gemm_k<bf16, 0, ACT, DUAL, OUTBF, ACCUM, RESID, ASCALE><<<grid, 256, 0, st>>>(
      xdet, A, aB, lda,
      ascale ? (const bf16*)ascale + asOff : nullptr, asB,
      (const bf16*)B0 + b0Off, B1 ? (const bf16*)B1 + b1Off : nullptr, bB, bK,
      bias ? (const bf16*)bias : nullptr, biasB, C, cB, ldc,
      resid ? (const bf16*)resid : nullptr, resLd, N, K, scale);
}

// ---------------- host-side dual-dispatch helper for tconv_k ----------------
template <int SC>
static inline void CVT(hipStream_t st, const unsigned short* xdet, const void* W,
                       const void* sc, bf16* Wt, int K, int N, int batch,
                       long wB, long sB, long oB) {
  dim3 g(K / 64, N / 64, batch);
  tconv_k<float, 1, SC><<<g, 256, 0, st>>>(xdet, (const float*)W, wB,
                                           (const float*)sc, sB, Wt, oB, K, N);
  tconv_k<bf16, 0, SC><<<g, 256, 0, st>>>(xdet, (const bf16*)W, wB,
                                          (const bf16*)sc, sB, Wt, oB, K, N);
}

// ---------------------------------------------------------------------------
extern "C" void kernel_launch(void* const* d_in, const int* in_sizes, int n_in,
                              void* d_out, int out_size, void* d_ws, size_t ws_size,
                              hipStream_t stream) {
  (void)in_sizes; (void)n_in; (void)out_size;
  const void* x    = d_in[0];
  const void* ln1w = d_in[1];
  const void* ln1b = d_in[2];
  const void* ln2w = d_in[3];
  const void* ln2b = d_in[4];
  const void* q_w  = d_in[5];
  const void* q_b  = d_in[6];
  const void* k_w  = d_in[7];
  const void* k_b  = d_in[8];
  const void* v_w  = d_in[9];
  const void* v_b  = d_in[10];
  const void* aw1  = d_in[11];
  const void* ab1  = d_in[12];
  const void* aw2  = d_in[13];
  const void* ab2  = d_in[14];
  const void* bw   = d_in[15];
  const void* bbv  = d_in[16];
  const void* scw1 = d_in[17];
  const void* scb1 = d_in[18];
  const void* scw2 = d_in[19];
  const void* scb2 = d_in[20];
  const void* arms = d_in[21];
  const void* l1w  = d_in[22];
  const void* l1b  = d_in[23];
  const void* outw = d_in[24];
  const void* outb = d_in[25];
  const void* shrms= d_in[26];
  const void* shw1 = d_in[27];
  const void* shw2 = d_in[28];
  const void* shw3 = d_in[29];
  const void* rw1  = d_in[30];
  const void* rw2  = d_in[31];
  const void* rw3  = d_in[32];
  const void* rdw  = d_in[33];
  const void* ruw  = d_in[34];
  const unsigned short* xdet = (const unsigned short*)x;

  // ---- workspace map. Base 16 MiB; then bf16 caches + attn + eo + hid.
  constexpr size_t MB = 1u << 20;
  char* base = (char*)d_ws;
  bf16* xn    = (bf16*)(base + 0 * MB);
  bf16* qh    = (bf16*)(base + 2 * MB);   // qh,kh,vh,beta contiguous 2..10MB
  bf16* kh    = (bf16*)(base + 4 * MB);
  bf16* vh    = (bf16*)(base + 6 * MB);
  bf16* beta  = (bf16*)(base + 8 * MB);
  bf16* ah    = (bf16*)(base + 10 * MB);  // legacy ah region
  bf16* ah2   = (bf16*)(base + 10 * MB);  // fused: ah(8 heads) then sch(8)
  bf16* sch2  = (bf16*)(base + 10 * MB) + (long)Tt * 256;
  bf16* alpha = (bf16*)(base + 12 * MB);
  bf16* sch   = (bf16*)(base + 8 * MB);   // legacy sch region (after postproj)
  bf16* shct  = (bf16*)(base + 14 * MB);
  bf16* oatt  = (bf16*)(base + 8 * MB);
  bf16* conc  = (bf16*)(base + 2 * MB);
  float* x2   = (float*)(base + 4 * MB);
  bf16* xfb   = (bf16*)(base + 0 * MB);
  bf16* rbb   = (bf16*)(base + 2 * MB);
  float* acc  = (float*)(base + 12 * MB);
  int*   hcnt = (int*)(base + 8 * MB);
  int*   hcur = hcnt + 32;
  int*   hseg = hcnt + 64;
  int*   hte  = hcnt + 96;
  int*   hts  = hcnt + 288;
  int*   heidx= hcnt + 512;
  float* hew  = (float*)(hcnt + 512 + 8192);
  int*   hstok= hcnt + 512 + 16384;
  float* hsw  = (float*)(hcnt + 512 + 16384 + 10240);
  int*   hslot= hcnt + 512 + 16384 + 20480;

  // ---- tier decision ----
  size_t rem = ws_size > (size_t)16 * MB ? ws_size - (size_t)16 * MB : 0;
  const size_t SH1B  = (size_t)NSs * F3f * Dd * 2;   // 12.58 MB each (x3)
  const size_t R1B   = (size_t)Ee * F2f * Dd * 2;    // 33.55 MB each (x3)
  const size_t HIDRT = (size_t)SLOTCAP * F2f * 2;    // 20.97 MB
  const size_t HID1  = (size_t)Tt * F3f * 2;         // 6.29 MB per shared exp
  const size_t EORT  = (size_t)SLOTCAP * 512 * 4;    // 20.97 MB
  const size_t EOSH  = (size_t)NSs * Tt * 512 * 4;   // 33.55 MB
  const size_t WQKVB = (size_t)4 * 512 * 512 * 2;    // 1 MB
  const size_t WASC  = (size_t)512 * 512 * 2;        // 0.5 MB
  const size_t WOUT  = (size_t)512 * 512 * 2;        // 0.5 MB
  const size_t BIASB = 4096 * 4;
  const size_t XF32  = (size_t)Tt * 512 * 4;         // 4 MB
  const size_t ATTNB = WQKVB + WASC + WOUT + BIASB + XF32;
  const bool cvtRt = rem >= 3 * SH1B + 3 * R1B + HIDRT;
  const bool cvtSh = cvtRt || rem >= 3 * SH1B + HID1;
  char* cur = base + (size_t)16 * MB;
  bf16 *sh1t = nullptr, *sh3t = nullptr, *sh2t = nullptr;
  bf16 *r1t = nullptr, *r3t = nullptr, *r2t = nullptr;
  size_t used = 0;
  if (cvtSh) {
    sh1t = (bf16*)cur; cur += SH1B;
    sh3t = (bf16*)cur; cur += SH1B;
    sh2t = (bf16*)cur; cur += SH1B;
    used += 3 * SH1B;
  }
  if (cvtRt) {
    r1t = (bf16*)cur; cur += R1B;
    r3t = (bf16*)cur; cur += R1B;
    r2t = (bf16*)cur; cur += R1B;
    used += 3 * R1B;
  }
  const size_t minHid = cvtRt ? HIDRT : (cvtSh ? HID1 : 0);
  bool cvtAttn = cvtSh && (rem - used >= ATTNB + minHid);
  bf16 *wqkvbT = nullptr, *wascT = nullptr, *woutT = nullptr;
  float *biasP = nullptr, *xf32 = nullptr;
  if (cvtAttn) {
    wqkvbT = (bf16*)cur; cur += WQKVB;
    wascT  = (bf16*)cur; cur += WASC;
    woutT  = (bf16*)cur; cur += WOUT;
    biasP  = (float*)cur; cur += BIASB;
    xf32   = (float*)cur; cur += XF32;
    used += ATTNB;
  }
  bool gather = false;
  float* eoRt = nullptr;
  float* eoSh = nullptr;
  if (cvtRt && rem - used >= EORT + HIDRT) {
    eoRt = (float*)cur; cur += EORT; used += EORT; gather = true;
  }
  if (gather && rem - used >= EOSH + HIDRT) {
    eoSh = (float*)cur; cur += EOSH; used += EOSH;
  }
  bf16* hid; long hidElems;
  if (ws_size >= 20 * MB) {
    hid = (bf16*)cur;
    hidElems = (long)((base + ws_size) - cur) / 2;
  } else {
    hid = (bf16*)(base + 8 * MB + 256 * 1024);
    hidElems = (long)(4 * MB - 256 * 1024) / 2;
  }
  const bool accUsed = (eoSh == nullptr) || !gather;

  // ---- attention weight conversion (one dispatch pair) ----
  if (cvtAttn) {
    atconv_k<float, 1><<<449, 256, 0, stream>>>(
        xdet, (const float*)q_w, (const float*)k_w, (const float*)v_w, (const float*)bw,
        (const float*)aw1, (const float*)scw1, (const float*)outw,
        (const float*)q_b, (const float*)k_b, (const float*)v_b, (const float*)bbv,
        (const float*)ab1, (const float*)scb1, (const float*)outb,
        wqkvbT, wascT, woutT, biasP);
    atconv_k<bf16, 0><<<449, 256, 0, stream>>>(
        xdet, (const bf16*)q_w, (const bf16*)k_w, (const bf16*)v_w, (const bf16*)bw,
        (const bf16*)aw1, (const bf16*)scw1, (const bf16*)outw,
        (const bf16*)q_b, (const bf16*)k_b, (const bf16*)v_b, (const bf16*)bbv,
        (const bf16*)ab1, (const bf16*)scb1, (const bf16*)outb,
        wqkvbT, wascT, woutT, biasP);
  }

  // ---- attention sublayer ----
  ln_k<float, float, 1><<<Tt, 256, 0, stream>>>(xdet, (const float*)x, (const float*)ln1w, (const float*)ln1b, xn, cvtAttn ? xf32 : nullptr, 1e-5f);
  ln_k<bf16, bf16, 0><<<Tt, 256, 0, stream>>>(xdet, (const bf16*)x, (const bf16*)ln1w, (const bf16*)ln1b, xn, cvtAttn ? xf32 : nullptr, 1e-5f);

  if (cvtAttn) {
    // fused q|k|v|beta projection: N=2048, head-major out, silu/sigmoid
    gemmT_k<0, 0, 3, 6><<<dim3(16, 32, 1), 256, 0, stream>>>(
        xn, 0, 512, wqkvbT, nullptr, 0, biasP, qh, 0, 64, nullptr, 512, 1.f);
    // fused aw1|scw1: N=512, head-major (HD=32), no act
    gemmT_k<0, 0, 0, 5><<<dim3(16, 8, 1), 256, 0, stream>>>(
        xn, 0, 512, wascT, nullptr, 0, biasP + 2048, ah2, 0, 32, nullptr, 512, 1.f);
  } else {
    G<1,0,1,0,0,0>(dim3(32,1,8), stream, xdet, xn,0,512, nullptr,0,0, q_w,0,nullptr,0,(long)512*64,64, q_b,64, qh,(long)Tt*64,64, nullptr,0, 64,512,1.f);
    G<1,0,1,0,0,0>(dim3(32,1,8), stream, xdet, xn,0,512, nullptr,0,0, k_w,0,nullptr,0,(long)512*64,64, k_b,64, kh,(long)Tt*64,64, nullptr,0, 64,512,1.f);
    G<1,0,1,0,0,0>(dim3(32,1,8), stream, xdet, xn,0,512, nullptr,0,0, v_w,0,nullptr,0,(long)512*64,64, v_b,64, vh,(long)Tt*64,64, nullptr,0, 64,512,1.f);
    G<2,0,1,0,0,0>(dim3(32,1,8), stream, xdet, xn,0,512, nullptr,0,0, bw,0,nullptr,0,(long)512*64,64, bbv,64, beta,(long)Tt*64,64, nullptr,0, 64,512,1.f);
    G<0,0,1,0,0,0>(dim3(32,1,8), stream, xdet, xn,0,512, nullptr,0,0, aw1,0,nullptr,0,(long)512*32,32, ab1,32, ah,(long)Tt*32,32, nullptr,0, 32,512,1.f);
  }

  {
    const bf16* ahA = cvtAttn ? ah2 : ah;
    G<2,0,1,0,0,0>(dim3(32,1,8), stream, xdet, ahA,(long)Tt*32,32, nullptr,0,0, aw2,0,nullptr,0,(long)32*64,64, ab2,64, alpha,(long)Tt*64,64, nullptr,0, 64,32,1.f);
  }

  postproj_k<<<NHh * Tt / 4, 256, 0, stream>>>(qh, kh, vh, alpha, beta);

  if (!cvtAttn) {
    G<0,0,1,0,0,0>(dim3(32,1,8), stream, xdet, xn,0,512, nullptr,0,0, scw1,0,nullptr,0,(long)512*32,32, scb1,32, sch,(long)Tt*32,32, nullptr,0, 32,512,1.f);
  }
  {
    const bf16* schA = cvtAttn ? sch2 : sch;
    G<2,0,1,0,0,0>(dim3(32,1,8), stream, xdet, schA,(long)Tt*32,32, nullptr,0,0, scw2,0,nullptr,0,(long)32*64,64, scb2,64, shct,(long)Tt*64,64, nullptr,0, 64,32,1.f);
  }

  attn_k<<<dim3(16, 16), 256, 0, stream>>>(qh, kh, vh, oatt);

  orms_k<float, 1><<<NHh * Tt / 4, 256, 0, stream>>>(xdet, oatt, (const float*)arms, shct);
  orms_k<bf16, 0><<<NHh * Tt / 4, 256, 0, stream>>>(xdet, oatt, (const bf16*)arms, shct);

  G<0,0,1,0,0,0>(dim3(32,1,8), stream, xdet, oatt,(long)Tt*64,64, nullptr,0,0, l1w,0,nullptr,0,(long)64*64,64, l1b,64, conc,64,512, nullptr,0, 64,64,1.f);

  if (cvtAttn) {
    gemmT_k<0, 3, 0, 0><<<dim3(16, 8, 1), 256, 0, stream>>>(
        conc, 0, 512, woutT, nullptr, 0, biasP + 2560, x2, 0, 512, xf32, 512, 1.f);
  } else {
    G<0,0,0,0,1,0>(dim3(32,8,1), stream, xdet, conc,0,512, nullptr,0,0, outw,0,nullptr,0,0,512, outb,0, x2,0,512, x,512, 512,512,1.f);
  }

  // ---- MoE sublayer ----
  ln_k<float, float, 1><<<Tt, 256, 0, stream>>>(xdet, x2, (const float*)ln2w, (const float*)ln2b, xfb, nullptr, 1e-5f);
  ln_k<float, bf16, 0><<<Tt, 256, 0, stream>>>(xdet, x2, (const bf16*)ln2w, (const bf16*)ln2b, xfb, nullptr, 1e-5f);
  rms_k<<<Tt, 256, 0, stream>>>(xfb, rbb);
  if (accUsed) zero_k<<<256, 256, 0, stream>>>(acc, (long)Tt * 512);
  zero_k<<<1, 64, 0, stream>>>((float*)hcnt, 64);
  router_k<float, 1><<<Tt / 4, 256, 0, stream>>>(xdet, x2, (const float*)ln2w, (const float*)ln2b, (const float*)rdw, (const float*)ruw, heidx, hew, hcnt);
  router_k<bf16, 0><<<Tt / 4, 256, 0, stream>>>(xdet, x2, (const bf16*)ln2w, (const bf16*)ln2b, (const bf16*)rdw, (const bf16*)ruw, heidx, hew, hcnt);
  offsets_k<<<1, 64, 0, stream>>>(hcnt, hseg, hte, hts);
  scatter_k<<<Tt / 256, 256, 0, stream>>>(heidx, hew, hseg, hcur, hstok, hsw, hslot);
  pad_k<<<Ee, 64, 0, stream>>>(hcnt, hseg, hstok, hsw);

  // ---- MoE weight conversion: [K][N] -> bf16 [N][K] (rms folded) ----
  if (cvtSh) {
    CVT<1>(stream, xdet, shw1, shrms, sh1t, 512, F3f, NSs, (long)512*F3f, 512, (long)F3f*512);
    CVT<1>(stream, xdet, shw3, shrms, sh3t, 512, F3f, NSs, (long)512*F3f, 512, (long)F3f*512);
    CVT<0>(stream, xdet, shw2, nullptr, sh2t, F3f, 512, NSs, (long)F3f*512, 0, (long)512*F3f);
  }
  if (cvtRt) {
    CVT<0>(stream, xdet, rw1, nullptr, r1t, 512, F2f, Ee, (long)512*F2f, 0, (long)F2f*512);
    CVT<0>(stream, xdet, rw3, nullptr, r3t, 512, F2f, Ee, (long)512*F2f, 0, (long)F2f*512);
    CVT<0>(stream, xdet, rw2, nullptr, r2t, F2f, 512, Ee, (long)F2f*512, 0, (long)512*F2f);
  }

  // ---- shared experts ----
  if (cvtSh) {
    int zB = (int)(((size_t)hidElems * 2) / HID1);
    if (zB > NSs) zB = NSs;
    if (zB < 1) zB = 1;
    for (int e0 = 0; e0 < NSs; e0 += zB) {
      int zc = NSs - e0 < zB ? NSs - e0 : zB;
      gemmT_k<1, 0, 0, 0><<<dim3(Tt / 128, F3f / 64, zc), 256, 0, stream>>>(
          rbb, 0, 512, sh1t + (long)e0 * F3f * 512, sh3t + (long)e0 * F3f * 512,
          (long)F3f * 512, nullptr, hid, (long)Tt * F3f, F3f, nullptr, 512, 1.f);
      if (eoSh) {
        gemmT_k<0, 2, 0, 0><<<dim3(Tt / 128, 512 / 64, zc), 256, 0, stream>>>(
            hid, (long)Tt * F3f, F3f, sh2t + (long)e0 * 512 * F3f, nullptr,
            (long)512 * F3f, nullptr, eoSh + (long)e0 * Tt * 512, (long)Tt * 512,
            512, nullptr, F3f, 0.125f);
      } else {
        gemmT_k<0, 1, 0, 0><<<dim3(Tt / 128, 512 / 64, zc), 256, 0, stream>>>(
            hid, (long)Tt * F3f, F3f, sh2t + (long)e0 * 512 * F3f, nullptr,
            (long)512 * F3f, nullptr, acc, 0, 512, nullptr, F3f, 0.125f);
      }
    }
  } else {
    int PsS, zBsh;
    if (hidElems >= (long)Tt * F3f) {
      PsS = F3f;
      zBsh = (int)(hidElems / ((long)Tt * F3f)); if (zBsh > NSs) zBsh = NSs;
    } else {
      PsS = (int)((hidElems / Tt / 32) * 32); if (PsS > F3f) PsS = F3f;
      zBsh = 1;
    }
    for (int n0e = 0; n0e < NSs; n0e += zBsh) {
      int zc = NSs - n0e < zBsh ? NSs - n0e : zBsh;
      for (int off = 0; off < F3f; off += PsS) {
        int Np = F3f - off < PsS ? F3f - off : PsS;
        G<0,1,1,0,0,1>(dim3(32,(Np+63)/64,zc), stream, xdet, rbb,0,512,
                       shrms,(long)n0e*512,512,
                       shw1,(long)n0e*512*F3f + off, shw3,(long)n0e*512*F3f + off,
                       (long)512*F3f, F3f,
                       nullptr,0, hid,(long)Tt*PsS,PsS, nullptr,0, Np,512,1.f);
        G<0,0,0,1,0,0>(dim3(32,8,zc), stream, xdet, hid,(long)Tt*PsS,PsS, nullptr,0,0,
                       shw2,(long)n0e*F3f*512 + (long)off*512, nullptr,0,
                       (long)F3f*512, 512,
                       nullptr,0, acc,0,512, nullptr,0, 512,Np,0.125f);
      }
    }
  }

  // ---- routed experts ----
  if (cvtRt) {
    moeT1_k<<<dim3(MAXTILE, F2f / 128), 256, 0, stream>>>(hte, hts, hstok, xfb, r1t, r3t, hid);
    if (gather) {
      moeT2_k<1><<<dim3(MAXTILE, 512 / 128), 256, 0, stream>>>(hte, hts, hstok, hsw, hid, r2t, acc, eoRt);
    } else {
      moeT2_k<0><<<dim3(MAXTILE, 512 / 128), 256, 0, stream>>>(hte, hts, hstok, hsw, hid, r2t, acc, nullptr);
    }
  } else {
    int PsR = (int)((hidElems / SLOTCAP / 32) * 32);
    if (PsR > F2f) PsR = F2f;
    if (PsR < 32) PsR = 32;
    for (int off = 0; off < F2f; off += PsR) {
      int Np = F2f - off < PsR ? F2f - off : PsR;
      dim3 g1(MAXTILE, (Np + 63) / 64);
      moe1_k<float, 1><<<g1, 256, 0, stream>>>(xdet, hte, hts, hstok, xfb, (const float*)rw1, (const float*)rw3, hid, PsR, off, Np);
      moe1_k<bf16, 0><<<g1, 256, 0, stream>>>(xdet, hte, hts, hstok, xfb, (const bf16*)rw1, (const bf16*)rw3, hid, PsR, off, Np);
      dim3 g2(MAXTILE, 8);
      moe2_k<float, 1><<<g2, 256, 0, stream>>>(xdet, hte, hts, hstok, hsw, hid, PsR, off, Np, (const float*)rw2, acc);
      moe2_k<bf16, 0><<<g2, 256, 0, stream>>>(xdet, hte, hts, hstok, hsw, hid, PsR, off, Np, (const bf16*)rw2, acc);
    }
  }

  const float* accP = accUsed ? acc : nullptr;
  const float* eoRtP = gather ? eoRt : nullptr;
  final_k<float, float, 1><<<Tt, 256, 0, stream>>>(xdet, x2, (const float*)ln2w, (const float*)ln2b, accP, eoSh, eoRtP, hslot, (float*)d_out);
  final_k<bf16, bf16, 0><<<Tt, 256, 0, stream>>>(xdet, x2, (const bf16*)ln2w, (const bf16*)ln2b, accP, eoSh, eoRtP, hslot, (bf16*)d_out);
  loss_k<float, 1><<<1, 64, 0, stream>>>(xdet, hcnt, (float*)d_out);
  loss_k<bf16, 0><<<1, 64, 0, stream>>>(xdet, hcnt, (bf16*)d_out);
}